// Round 2
// baseline (3496.678 us; speedup 1.0000x reference)
//
#include <hip/hip_runtime.h>
#include <math.h>

#define CK_A (-0.75f)

__device__ __forceinline__ float cubicw(float t){
  float at = fabsf(t);
  float at2 = at*at, at3 = at2*at;
  if (at <= 1.f) return (CK_A+2.f)*at3 - (CK_A+3.f)*at2 + 1.f;
  if (at < 2.f)  return CK_A*at3 - 5.f*CK_A*at2 + 8.f*CK_A*at - 4.f*CK_A;
  return 0.f;
}

// ---------------- conv 3x3 SAME + bias + relu, register-blocked ----------------
// Each block: 16x16 spatial tile, COB output channels, stages CICH input-channel
// tiles per barrier. Weights are wave-uniform loads (scalarized by compiler).
template<int COB, int CICH>
__global__ __launch_bounds__(256) void conv3x3_b(
    const float* __restrict__ in, const float* __restrict__ w, const float* __restrict__ bias,
    float* __restrict__ out, int CI, int H, int W, long inBS, long outBS)
{
  int tilesX = (W + 15) >> 4;
  int tx0 = (blockIdx.x % tilesX) << 4;
  int ty0 = (blockIdx.x / tilesX) << 4;
  int cob = blockIdx.y * COB;
  int b = blockIdx.z;
  int lx = threadIdx.x & 15, ly = threadIdx.x >> 4;
  __shared__ float tile[CICH][18][20];
  float acc[COB];
  #pragma unroll
  for (int j=0;j<COB;j++) acc[j]=0.f;
  const float* inb = in + (long)b*inBS;
  int ox = tx0+lx, oy = ty0+ly;

  for (int c0=0; c0<CI; c0+=CICH){
    for (int idx = threadIdx.x; idx < CICH*324; idx += 256){
      int cl = idx/324, rem = idx - cl*324;
      int r = rem/18, c = rem - r*18;
      int gy = ty0 + r - 1, gx = tx0 + c - 1;
      const float* ic = inb + (long)(c0+cl)*H*W;
      tile[cl][r][c] = (gy>=0 && gy<H && gx>=0 && gx<W) ? ic[(long)gy*W+gx] : 0.f;
    }
    __syncthreads();
    #pragma unroll
    for (int cl=0; cl<CICH; cl++){
      float t00=tile[cl][ly+0][lx+0], t01=tile[cl][ly+0][lx+1], t02=tile[cl][ly+0][lx+2];
      float t10=tile[cl][ly+1][lx+0], t11=tile[cl][ly+1][lx+1], t12=tile[cl][ly+1][lx+2];
      float t20=tile[cl][ly+2][lx+0], t21=tile[cl][ly+2][lx+1], t22=tile[cl][ly+2][lx+2];
      #pragma unroll
      for (int j=0;j<COB;j++){
        const float* wp = w + ((long)(cob+j)*CI + (c0+cl))*9;
        float a = acc[j];
        a = fmaf(t00, wp[0], a); a = fmaf(t01, wp[1], a); a = fmaf(t02, wp[2], a);
        a = fmaf(t10, wp[3], a); a = fmaf(t11, wp[4], a); a = fmaf(t12, wp[5], a);
        a = fmaf(t20, wp[6], a); a = fmaf(t21, wp[7], a); a = fmaf(t22, wp[8], a);
        acc[j] = a;
      }
    }
    __syncthreads();
  }
  if (ox < W && oy < H){
    #pragma unroll
    for (int j=0;j<COB;j++){
      float r = acc[j] + bias[cob+j];
      out[(long)b*outBS + (long)(cob+j)*H*W + (long)oy*W + ox] = fmaxf(r, 0.f);
    }
  }
}

// ---------------- maxpool 2x2 stride 2 ----------------
__global__ void maxpool2(const float* __restrict__ in, float* __restrict__ out, long NC, int Hi, int Wi){
  int Ho = Hi>>1, Wo = Wi>>1;
  long total = NC * Ho * Wo;
  long idx = (long)blockIdx.x*256 + threadIdx.x;
  if (idx >= total) return;
  int x = (int)(idx % Wo); long t = idx / Wo; int y = (int)(t % Ho); long nc = t / Ho;
  const float* p = in + (nc*Hi + 2*y)*(long)Wi + 2*x;
  float v = fmaxf(fmaxf(p[0], p[1]), fmaxf(p[Wi], p[Wi+1]));
  out[idx] = v;
}

// ---------------- bicubic upsample (align_corners=True) ----------------
__global__ __launch_bounds__(256) void bicubic_up(
    const float* __restrict__ in, float* __restrict__ out,
    int Hin, int Win, int Hout, int Wout, long inBStride, long outBStride)
{
  int c = blockIdx.x, b = blockIdx.y;
  __shared__ float s[576];
  const float* ip = in + (long)b*inBStride + (long)c*Hin*Win;
  float* op = out + (long)b*outBStride + (long)c*Hout*Wout;
  int n = Hin*Win;
  for (int i = threadIdx.x; i < n; i += 256) s[i] = ip[i];
  __syncthreads();
  float scy = (float)((double)(Hin-1)/(double)(Hout-1));
  float scx = (float)((double)(Win-1)/(double)(Wout-1));
  int total = Hout*Wout;
  for (int idx = threadIdx.x; idx < total; idx += 256){
    int ox = idx % Wout, oy = idx / Wout;
    float py = oy * scy, px = ox * scx;
    float iy0f = floorf(py), ix0f = floorf(px);
    int iy0 = (int)iy0f, ix0 = (int)ix0f;
    float fy = py - iy0f, fx = px - ix0f;
    float wy[4], wx[4]; int xs[4], ys[4];
    #pragma unroll
    for (int t=0;t<4;t++){
      wy[t] = cubicw(fy - (float)(t-1));
      wx[t] = cubicw(fx - (float)(t-1));
      ys[t] = min(max(iy0 + t - 1, 0), Hin-1);
      xs[t] = min(max(ix0 + t - 1, 0), Win-1);
    }
    float acc = 0.f;
    #pragma unroll
    for (int i=0;i<4;i++){
      const float* row = &s[ys[i]*Win];
      float rs = wx[0]*row[xs[0]] + wx[1]*row[xs[1]] + wx[2]*row[xs[2]] + wx[3]*row[xs[3]];
      acc = fmaf(wy[i], rs, acc);
    }
    op[idx] = acc;
  }
}

// ---------------- normalizer ----------------
__global__ __launch_bounds__(256) void mean_k(const float* __restrict__ fR, const float* __restrict__ fT, float* __restrict__ mean){
  int c = blockIdx.x % 320, b = blockIdx.x / 320;
  const float* a = fR + ((long)b*320+c)*9216L;
  const float* t = fT + ((long)b*320+c)*2304L;
  float s = 0.f;
  for (int i=threadIdx.x;i<9216;i+=256) s += a[i];
  for (int i=threadIdx.x;i<2304;i+=256) s += t[i];
  __shared__ float sm[4];
  for (int o=32;o;o>>=1) s += __shfl_down(s,o);
  int lane = threadIdx.x & 63, wv = threadIdx.x >> 6;
  if (lane==0) sm[wv] = s;
  __syncthreads();
  if (threadIdx.x==0) mean[b*320+c] = (sm[0]+sm[1]+sm[2]+sm[3]) * (1.f/11520.f);
}

__global__ void norm_apply(float* __restrict__ f, const float* __restrict__ mean, long perChan, long total){
  long idx = (long)blockIdx.x*256 + threadIdx.x;
  if (idx >= total) return;
  long c = (idx / perChan) % 320;
  long b = idx / (perChan*320);
  float m = mean[b*320+c];
  f[idx] = (f[idx] - m) / (m + 1e-8f);
}

// ---------------- dist GEMM: D[m][n] = sum_k A[k][m]*B[k][n] ----------------
// A: [320][9216] (one batch), B: [320][2304], D: [9216][2304]
#define FMA4(ac, s, b) { ac.x=fmaf(s,b.x,ac.x); ac.y=fmaf(s,b.y,ac.y); ac.z=fmaf(s,b.z,ac.z); ac.w=fmaf(s,b.w,ac.w); }

__global__ __launch_bounds__(256) void gemm128(const float* __restrict__ A, const float* __restrict__ Bv, float* __restrict__ D){
  const int M=9216, N=2304, K=320;
  int n0 = blockIdx.x*128, m0 = blockIdx.y*128;
  const float* Ab = A + m0;
  const float* Bb = Bv + n0;
  __shared__ float As[8][128], Bs[8][128];
  int tid = threadIdx.x;
  int tn = tid & 15, tm = tid >> 4;
  float4 acc[8][2];
  #pragma unroll
  for (int i=0;i<8;i++){
    acc[i][0] = make_float4(0.f,0.f,0.f,0.f);
    acc[i][1] = make_float4(0.f,0.f,0.f,0.f);
  }
  int la = tid*4; int lk = la >> 7; int lm = la & 127;
  for (int k0=0;k0<K;k0+=8){
    *(float4*)&As[lk][lm] = *(const float4*)&Ab[(long)(k0+lk)*M + lm];
    *(float4*)&Bs[lk][lm] = *(const float4*)&Bb[(long)(k0+lk)*N + lm];
    __syncthreads();
    #pragma unroll
    for (int kk=0;kk<8;kk++){
      float4 A0 = *(float4*)&As[kk][tm*4];
      float4 A1 = *(float4*)&As[kk][64+tm*4];
      float4 B0 = *(float4*)&Bs[kk][tn*4];
      float4 B1 = *(float4*)&Bs[kk][64+tn*4];
      FMA4(acc[0][0], A0.x, B0); FMA4(acc[0][1], A0.x, B1);
      FMA4(acc[1][0], A0.y, B0); FMA4(acc[1][1], A0.y, B1);
      FMA4(acc[2][0], A0.z, B0); FMA4(acc[2][1], A0.z, B1);
      FMA4(acc[3][0], A0.w, B0); FMA4(acc[3][1], A0.w, B1);
      FMA4(acc[4][0], A1.x, B0); FMA4(acc[4][1], A1.x, B1);
      FMA4(acc[5][0], A1.y, B0); FMA4(acc[5][1], A1.y, B1);
      FMA4(acc[6][0], A1.z, B0); FMA4(acc[6][1], A1.z, B1);
      FMA4(acc[7][0], A1.w, B0); FMA4(acc[7][1], A1.w, B1);
    }
    __syncthreads();
  }
  float* Db = D + (long)m0*N + n0;
  #pragma unroll
  for (int i=0;i<8;i++){
    int mr = (i<4) ? (tm*4+i) : (64+tm*4+(i-4));
    *(float4*)&Db[(long)mr*N + tn*4] = acc[i][0];
    *(float4*)&Db[(long)mr*N + 64 + tn*4] = acc[i][1];
  }
}

// ---------------- row softmax stats (axis=-1, coef_tmp) ----------------
__global__ __launch_bounds__(256) void row_stats(const float* __restrict__ D, const float* __restrict__ coeft,
                                                 float* __restrict__ rmax, float* __restrict__ rsum){
  int m = blockIdx.x;
  const float* drow = D + (long)m*2304;
  float ct = *coeft;
  float v[9];
  float mx = -INFINITY;
  #pragma unroll
  for (int i=0;i<9;i++){ v[i] = ct * drow[threadIdx.x + i*256]; mx = fmaxf(mx, v[i]); }
  __shared__ float sm[4];
  for (int o=32;o;o>>=1) mx = fmaxf(mx, __shfl_down(mx,o));
  int lane = threadIdx.x & 63, wv = threadIdx.x>>6;
  if (lane==0) sm[wv]=mx;
  __syncthreads();
  mx = fmaxf(fmaxf(sm[0],sm[1]),fmaxf(sm[2],sm[3]));
  __syncthreads();
  float s=0.f;
  #pragma unroll
  for (int i=0;i<9;i++) s += expf(v[i]-mx);
  for (int o=32;o;o>>=1) s += __shfl_down(s,o);
  if (lane==0) sm[wv]=s;
  __syncthreads();
  if (threadIdx.x==0){ rmax[m]=mx; rsum[m]=sm[0]+sm[1]+sm[2]+sm[3]; }
}

// ---------------- column softmax stats (axis=-2, coef_ref) ----------------
__device__ __forceinline__ void merge_ms(float& m, float& s, float m2, float s2){
  float M = fmaxf(m, m2);
  s = s*expf(m - M) + s2*expf(m2 - M);
  m = M;
}

__global__ __launch_bounds__(256) void colstat_part(const float* __restrict__ D, const float* __restrict__ coefr,
                                                    float* __restrict__ pm, float* __restrict__ ps){
  int tx = threadIdx.x & 63, ty = threadIdx.x >> 6;
  int n = blockIdx.x*64 + tx;
  float cr = *coefr;
  float m = -INFINITY, s = 0.f;
  int r0 = blockIdx.y * 576;
  for (int r = r0 + ty; r < r0 + 576; r += 4){
    float v = cr * D[(long)r*2304 + n];
    if (v > m){ s = s*expf(m - v) + 1.f; m = v; }
    else s += expf(v - m);
  }
  __shared__ float smm[4][64], sms[4][64];
  smm[ty][tx]=m; sms[ty][tx]=s;
  __syncthreads();
  if (ty==0){
    #pragma unroll
    for (int k=1;k<4;k++) merge_ms(m, s, smm[k][tx], sms[k][tx]);
    pm[(long)blockIdx.y*2304 + n] = m;
    ps[(long)blockIdx.y*2304 + n] = s;
  }
}

__global__ void colstat_merge(const float* __restrict__ pm, const float* __restrict__ ps,
                              float* __restrict__ cm, float* __restrict__ cs){
  int idx = blockIdx.x*256 + threadIdx.x;
  if (idx >= 2304) return;
  float m=-INFINITY, s=0.f;
  for (int k=0;k<16;k++){
    merge_ms(m, s, pm[(long)k*2304+idx], ps[(long)k*2304+idx]);
  }
  cm[idx]=m; cs[idx]=s;
}

// ---------------- confidence + top-10 mean ----------------
__global__ __launch_bounds__(256) void conf_topk(const float* __restrict__ D,
    const float* __restrict__ coefr, const float* __restrict__ coeft,
    const float* __restrict__ rmax, const float* __restrict__ rsum,
    const float* __restrict__ cmax, const float* __restrict__ csum,
    float* __restrict__ outp){
  int m = blockIdx.x;
  const float* drow = D + (long)m*2304;
  float cr = *coefr, ct = *coeft;
  float rm = rmax[m], rs = rsum[m];
  float vals[9];
  #pragma unroll
  for (int i=0;i<9;i++){
    int n = threadIdx.x + i*256;
    float d = drow[n];
    float e = expf(0.5f*((cr+ct)*d - cmax[n] - rm));
    vals[i] = e / sqrtf(csum[n]*rs);
  }
  __shared__ float smv[4]; __shared__ int smi[4];
  float total = 0.f;
  for (int t=0;t<10;t++){
    float lv = -1.f; int li = 0;
    #pragma unroll
    for (int i=0;i<9;i++) if (vals[i] > lv){ lv = vals[i]; li = i; }
    float v = lv; int idx = li*256 + threadIdx.x;
    for (int o=32;o;o>>=1){
      float v2 = __shfl_down(v,o); int i2 = __shfl_down(idx,o);
      if (v2 > v || (v2 == v && i2 < idx)){ v=v2; idx=i2; }
    }
    int lane = threadIdx.x&63, wv = threadIdx.x>>6;
    if (lane==0){ smv[wv]=v; smi[wv]=idx; }
    __syncthreads();
    float bv = smv[0]; int bi = smi[0];
    #pragma unroll
    for (int k=1;k<4;k++){ float v2=smv[k]; int i2=smi[k]; if (v2>bv || (v2==bv && i2<bi)){bv=v2;bi=i2;} }
    total += bv;
    if ((bi & 255) == threadIdx.x) vals[bi>>8] = -2.f;
    __syncthreads();
  }
  if (threadIdx.x==0) outp[m] = total*0.1f;
}

// ---------------- host ----------------
extern "C" void kernel_launch(void* const* d_in, const int* in_sizes, int n_in,
                              void* d_out, int out_size, void* d_ws, size_t ws_size,
                              hipStream_t stream) {
  const float *W[8], *Bp[8], *xr, *xt, *cr, *ct;
  if (in_sizes[0] == 1728){
    for (int i=0;i<8;i++){ W[i]=(const float*)d_in[2*i]; Bp[i]=(const float*)d_in[2*i+1]; }
    xr=(const float*)d_in[16]; xt=(const float*)d_in[17];
    cr=(const float*)d_in[18]; ct=(const float*)d_in[19];
  } else {
    xr=(const float*)d_in[0]; xt=(const float*)d_in[1];
    cr=(const float*)d_in[2]; ct=(const float*)d_in[3];
    for (int i=0;i<8;i++){ W[i]=(const float*)d_in[4+2*i]; Bp[i]=(const float*)d_in[5+2*i]; }
  }

  float* ws = (float*)d_ws;
  long off = 0;
  auto alloc = [&](long nfl){ float* p = ws + off; off += (nfl + 63) & ~63L; return p; };
  float* featR = alloc(2L*320*9216);     // [2,320,96,96]
  float* featT = alloc(2L*320*2304);     // [2,320,48,48]
  float* meanb = alloc(640);
  float* rmax  = alloc(2L*9216);
  float* rsum  = alloc(2L*9216);
  float* pm    = alloc(16L*2304);
  float* ps    = alloc(16L*2304);
  float* cm    = alloc(2304);
  float* cs    = alloc(2304);
  float* scratch = alloc(9216L*2304);    // dist (per batch), aliases conv temps
  if ((size_t)(off*4) > ws_size) return; // insufficient scratch: bail cleanly

  // conv temporaries aliased inside scratch (dead before dist is written)
  float* tA = scratch;                   // [2,64,96,96]
  float* tB = tA + 2L*64*9216;           // [2,64,48,48]
  float* tC = tB + 2L*64*2304;           // [2,128,48,48]
  float* tD = tC + 2L*128*2304;          // [2,128,48,48]
  float* tE = tD + 2L*128*2304;          // [2,128,24,24]
  float* tF = tE + 2L*128*576;           // [2,256,24,24]
  float* tG = tF + 2L*256*576;           // [2,256,24,24]
  float* dist = scratch;

  auto convl = [&](const float* in, int i, float* out, int CI, int CO, int H, int Wd,
                   long inBS, long outBS, int cob){
    int tiles = ((Wd+15)/16)*((H+15)/16);
    dim3 g(tiles, CO/cob, 2);
    if (CI == 3)        conv3x3_b<8,3><<<g,256,0,stream>>>(in, W[i], Bp[i], out, CI, H, Wd, inBS, outBS);
    else if (cob == 16) conv3x3_b<16,8><<<g,256,0,stream>>>(in, W[i], Bp[i], out, CI, H, Wd, inBS, outBS);
    else if (cob == 8)  conv3x3_b<8,8><<<g,256,0,stream>>>(in, W[i], Bp[i], out, CI, H, Wd, inBS, outBS);
    else                conv3x3_b<4,8><<<g,256,0,stream>>>(in, W[i], Bp[i], out, CI, H, Wd, inBS, outBS);
  };
  auto pooll = [&](const float* in, float* out, long NC, int Hi, int Wi){
    long total = NC*(Hi/2)*(Wi/2);
    maxpool2<<<dim3((unsigned)((total+255)/256)), 256, 0, stream>>>(in, out, NC, Hi, Wi);
  };

  // ---- reference image path (96x96) ----
  convl(xr, 0, featR, 3, 64, 96, 96, 3L*9216, 320L*9216, 8);
  convl(featR, 1, tA, 64, 64, 96, 96, 320L*9216, 64L*9216, 16);
  pooll(tA, tB, 2L*64, 96, 96);
  convl(tB, 2, tC, 64, 128, 48, 48, 64L*2304, 128L*2304, 8);
  convl(tC, 3, tD, 128, 128, 48, 48, 128L*2304, 128L*2304, 8);
  pooll(tD, tE, 2L*128, 48, 48);
  convl(tE, 4, tF, 128, 256, 24, 24, 128L*576, 256L*576, 8);
  convl(tF, 5, tG, 256, 256, 24, 24, 256L*576, 256L*576, 8);
  convl(tG, 6, tF, 256, 256, 24, 24, 256L*576, 256L*576, 8);
  convl(tF, 7, tG, 256, 256, 24, 24, 256L*576, 256L*576, 8);
  bicubic_up<<<dim3(256,2), 256, 0, stream>>>(tG, featR + 64L*9216, 24,24,96,96, 256L*576, 320L*9216);

  // ---- template path (48x48) ----
  convl(xt, 0, featT, 3, 64, 48, 48, 3L*2304, 320L*2304, 8);
  convl(featT, 1, tA, 64, 64, 48, 48, 320L*2304, 64L*2304, 4);
  pooll(tA, tB, 2L*64, 48, 48);
  convl(tB, 2, tC, 64, 128, 24, 24, 64L*576, 128L*576, 4);
  convl(tC, 3, tD, 128, 128, 24, 24, 128L*576, 128L*576, 4);
  pooll(tD, tE, 2L*128, 24, 24);
  convl(tE, 4, tF, 128, 256, 12, 12, 128L*144, 256L*144, 4);
  convl(tF, 5, tG, 256, 256, 12, 12, 256L*144, 256L*144, 4);
  convl(tG, 6, tF, 256, 256, 12, 12, 256L*144, 256L*144, 4);
  convl(tF, 7, tG, 256, 256, 12, 12, 256L*144, 256L*144, 4);
  bicubic_up<<<dim3(256,2), 256, 0, stream>>>(tG, featT + 64L*2304, 12,12,48,48, 256L*144, 320L*2304);

  // ---- normalizer (std = mean bug preserved) ----
  mean_k<<<640, 256, 0, stream>>>(featR, featT, meanb);
  norm_apply<<<dim3((unsigned)((5898240L+255)/256)), 256, 0, stream>>>(featR, meanb, 9216L, 2L*320*9216);
  norm_apply<<<dim3((unsigned)((1474560L+255)/256)), 256, 0, stream>>>(featT, meanb, 2304L, 2L*320*2304);

  // ---- per-batch: dist GEMM, softmax stats, conf + top-10 ----
  for (int b=0; b<2; b++){
    const float* Ab = featR + (long)b*320*9216;
    const float* Bb = featT + (long)b*320*2304;
    gemm128<<<dim3(18,72), 256, 0, stream>>>(Ab, Bb, dist);
    row_stats<<<dim3(9216), 256, 0, stream>>>(dist, ct, rmax + (long)b*9216, rsum + (long)b*9216);
    colstat_part<<<dim3(36,16), 256, 0, stream>>>(dist, cr, pm, ps);
    colstat_merge<<<dim3(9), 256, 0, stream>>>(pm, ps, cm, cs);
    conf_topk<<<dim3(9216), 256, 0, stream>>>(dist, cr, ct,
        rmax + (long)b*9216, rsum + (long)b*9216, cm, cs, (float*)d_out + (long)b*9216);
  }
}

// Round 3
// 1879.326 us; speedup vs baseline: 1.8606x; 1.8606x over previous
//
#include <hip/hip_runtime.h>
#include <math.h>

#define CK_A (-0.75f)

__device__ __forceinline__ float cubicw(float t){
  float at = fabsf(t);
  float at2 = at*at, at3 = at2*at;
  if (at <= 1.f) return (CK_A+2.f)*at3 - (CK_A+3.f)*at2 + 1.f;
  if (at < 2.f)  return CK_A*at3 - 5.f*CK_A*at2 + 8.f*CK_A*at - 4.f*CK_A;
  return 0.f;
}

// ---------------- conv 3x3 SAME, register-blocked, CI-split, LDS weights ----
// blockIdx.x = spatial tile, blockIdx.y = CO/COB group, blockIdx.z = b*S + s.
// Each block reduces nci input channels [s*nci, (s+1)*nci). If bias!=nullptr
// (S==1) writes relu(acc+bias) to out; else writes raw partial to
// out + s*sStride for a later reduce pass.
template<int COB, int CICH>
__global__ __launch_bounds__(256) void conv3x3_v3(
    const float* __restrict__ in, const float* __restrict__ w, const float* __restrict__ bias,
    float* __restrict__ out, int CI, int nci, int S, int H, int W,
    long inBS, long outBS, long sStride)
{
  int tilesX = (W + 15) >> 4;
  int tx0 = (blockIdx.x % tilesX) << 4;
  int ty0 = (blockIdx.x / tilesX) << 4;
  int cob = blockIdx.y * COB;
  int s = blockIdx.z % S, b = blockIdx.z / S;
  int ci0 = s * nci;
  int lx = threadIdx.x & 15, ly = threadIdx.x >> 4;
  __shared__ float tile[CICH][18][20];
  __shared__ float wlds[CICH][COB][12];   // 9 used, padded for float4 reads
  float acc[COB];
  #pragma unroll
  for (int j=0;j<COB;j++) acc[j]=0.f;
  const float* inb = in + (long)b*inBS;
  int ox = tx0+lx, oy = ty0+ly;

  for (int c0=ci0; c0<ci0+nci; c0+=CICH){
    // stage input tile (CICH channels, 18x18 window)
    for (int idx = threadIdx.x; idx < CICH*324; idx += 256){
      int cl = idx/324, rem = idx - cl*324;
      int r = rem/18, c = rem - r*18;
      int gy = ty0 + r - 1, gx = tx0 + c - 1;
      const float* ic = inb + (long)(c0+cl)*H*W;
      tile[cl][r][c] = (gy>=0 && gy<H && gx>=0 && gx<W) ? ic[(long)gy*W+gx] : 0.f;
    }
    // stage weights for this chunk
    for (int idx = threadIdx.x; idx < CICH*COB*9; idx += 256){
      int cl = idx/(COB*9), rem = idx - cl*(COB*9);
      int j = rem/9, k = rem - j*9;
      wlds[cl][j][k] = w[((long)(cob+j)*CI + (c0+cl))*9 + k];
    }
    __syncthreads();
    #pragma unroll
    for (int cl=0; cl<CICH; cl++){
      float t00=tile[cl][ly+0][lx+0], t01=tile[cl][ly+0][lx+1], t02=tile[cl][ly+0][lx+2];
      float t10=tile[cl][ly+1][lx+0], t11=tile[cl][ly+1][lx+1], t12=tile[cl][ly+1][lx+2];
      float t20=tile[cl][ly+2][lx+0], t21=tile[cl][ly+2][lx+1], t22=tile[cl][ly+2][lx+2];
      #pragma unroll
      for (int j=0;j<COB;j++){
        float4 w0 = *(float4*)&wlds[cl][j][0];
        float4 w1 = *(float4*)&wlds[cl][j][4];
        float  w8 = wlds[cl][j][8];
        float a = acc[j];
        a = fmaf(t00, w0.x, a); a = fmaf(t01, w0.y, a); a = fmaf(t02, w0.z, a);
        a = fmaf(t10, w0.w, a); a = fmaf(t11, w1.x, a); a = fmaf(t12, w1.y, a);
        a = fmaf(t20, w1.z, a); a = fmaf(t21, w1.w, a); a = fmaf(t22, w8, a);
        acc[j] = a;
      }
    }
    __syncthreads();
  }
  if (ox < W && oy < H){
    float* outp = out + (long)s*sStride + (long)b*outBS;
    #pragma unroll
    for (int j=0;j<COB;j++){
      float v = acc[j];
      if (bias) v = fmaxf(v + bias[cob+j], 0.f);
      outp[(long)(cob+j)*H*W + (long)oy*W + ox] = v;
    }
  }
}

// ---------------- partial reduce + bias + relu ----------------
__global__ void reduce_bias_relu(const float* __restrict__ part, const float* __restrict__ bias,
                                 float* __restrict__ out, int S, long sStride,
                                 int CO, int HW, long outBS){
  long tot = 2L*CO*HW;
  long e = (long)blockIdx.x*256 + threadIdx.x;
  if (e >= tot) return;
  long b = e / ((long)CO*HW);
  long r = e - b*(long)CO*HW;
  float v = 0.f;
  for (int s=0;s<S;s++) v += part[(long)s*sStride + e];
  int co = (int)(r / HW);
  out[b*outBS + r] = fmaxf(v + bias[co], 0.f);
}

// ---------------- maxpool 2x2 stride 2 ----------------
__global__ void maxpool2(const float* __restrict__ in, float* __restrict__ out, long NC, int Hi, int Wi){
  int Ho = Hi>>1, Wo = Wi>>1;
  long total = NC * Ho * Wo;
  long idx = (long)blockIdx.x*256 + threadIdx.x;
  if (idx >= total) return;
  int x = (int)(idx % Wo); long t = idx / Wo; int y = (int)(t % Ho); long nc = t / Ho;
  const float* p = in + (nc*Hi + 2*y)*(long)Wi + 2*x;
  float v = fmaxf(fmaxf(p[0], p[1]), fmaxf(p[Wi], p[Wi+1]));
  out[idx] = v;
}

// ---------------- bicubic upsample (align_corners=True) ----------------
__global__ __launch_bounds__(256) void bicubic_up(
    const float* __restrict__ in, float* __restrict__ out,
    int Hin, int Win, int Hout, int Wout, long inBStride, long outBStride)
{
  int c = blockIdx.x, b = blockIdx.y;
  __shared__ float s[576];
  const float* ip = in + (long)b*inBStride + (long)c*Hin*Win;
  float* op = out + (long)b*outBStride + (long)c*Hout*Wout;
  int n = Hin*Win;
  for (int i = threadIdx.x; i < n; i += 256) s[i] = ip[i];
  __syncthreads();
  float scy = (float)((double)(Hin-1)/(double)(Hout-1));
  float scx = (float)((double)(Win-1)/(double)(Wout-1));
  int total = Hout*Wout;
  for (int idx = threadIdx.x; idx < total; idx += 256){
    int ox = idx % Wout, oy = idx / Wout;
    float py = oy * scy, px = ox * scx;
    float iy0f = floorf(py), ix0f = floorf(px);
    int iy0 = (int)iy0f, ix0 = (int)ix0f;
    float fy = py - iy0f, fx = px - ix0f;
    float wy[4], wx[4]; int xs[4], ys[4];
    #pragma unroll
    for (int t=0;t<4;t++){
      wy[t] = cubicw(fy - (float)(t-1));
      wx[t] = cubicw(fx - (float)(t-1));
      ys[t] = min(max(iy0 + t - 1, 0), Hin-1);
      xs[t] = min(max(ix0 + t - 1, 0), Win-1);
    }
    float acc = 0.f;
    #pragma unroll
    for (int i=0;i<4;i++){
      const float* row = &s[ys[i]*Win];
      float rs = wx[0]*row[xs[0]] + wx[1]*row[xs[1]] + wx[2]*row[xs[2]] + wx[3]*row[xs[3]];
      acc = fmaf(wy[i], rs, acc);
    }
    op[idx] = acc;
  }
}

// ---------------- normalizer ----------------
__global__ __launch_bounds__(256) void mean_k(const float* __restrict__ fR, const float* __restrict__ fT, float* __restrict__ mean){
  int c = blockIdx.x % 320, b = blockIdx.x / 320;
  const float* a = fR + ((long)b*320+c)*9216L;
  const float* t = fT + ((long)b*320+c)*2304L;
  float s = 0.f;
  for (int i=threadIdx.x;i<9216;i+=256) s += a[i];
  for (int i=threadIdx.x;i<2304;i+=256) s += t[i];
  __shared__ float sm[4];
  for (int o=32;o;o>>=1) s += __shfl_down(s,o);
  int lane = threadIdx.x & 63, wv = threadIdx.x >> 6;
  if (lane==0) sm[wv] = s;
  __syncthreads();
  if (threadIdx.x==0) mean[b*320+c] = (sm[0]+sm[1]+sm[2]+sm[3]) * (1.f/11520.f);
}

__global__ void norm_apply(float* __restrict__ f, const float* __restrict__ mean, long perChan, long total){
  long idx = (long)blockIdx.x*256 + threadIdx.x;
  if (idx >= total) return;
  long c = (idx / perChan) % 320;
  long b = idx / (perChan*320);
  float m = mean[b*320+c];
  f[idx] = (f[idx] - m) / (m + 1e-8f);
}

// ---------------- dist GEMM: D[m][n] = sum_k A[k][m]*B[k][n] ----------------
#define FMA4(ac, s, b) { ac.x=fmaf(s,b.x,ac.x); ac.y=fmaf(s,b.y,ac.y); ac.z=fmaf(s,b.z,ac.z); ac.w=fmaf(s,b.w,ac.w); }

__global__ __launch_bounds__(256) void gemm128(const float* __restrict__ A, const float* __restrict__ Bv, float* __restrict__ D){
  const int M=9216, N=2304, K=320;
  int n0 = blockIdx.x*128, m0 = blockIdx.y*128;
  const float* Ab = A + m0;
  const float* Bb = Bv + n0;
  __shared__ float As[8][128], Bs[8][128];
  int tid = threadIdx.x;
  int tn = tid & 15, tm = tid >> 4;
  float4 acc[8][2];
  #pragma unroll
  for (int i=0;i<8;i++){
    acc[i][0] = make_float4(0.f,0.f,0.f,0.f);
    acc[i][1] = make_float4(0.f,0.f,0.f,0.f);
  }
  int la = tid*4; int lk = la >> 7; int lm = la & 127;
  for (int k0=0;k0<K;k0+=8){
    *(float4*)&As[lk][lm] = *(const float4*)&Ab[(long)(k0+lk)*M + lm];
    *(float4*)&Bs[lk][lm] = *(const float4*)&Bb[(long)(k0+lk)*N + lm];
    __syncthreads();
    #pragma unroll
    for (int kk=0;kk<8;kk++){
      float4 A0 = *(float4*)&As[kk][tm*4];
      float4 A1 = *(float4*)&As[kk][64+tm*4];
      float4 B0 = *(float4*)&Bs[kk][tn*4];
      float4 B1 = *(float4*)&Bs[kk][64+tn*4];
      FMA4(acc[0][0], A0.x, B0); FMA4(acc[0][1], A0.x, B1);
      FMA4(acc[1][0], A0.y, B0); FMA4(acc[1][1], A0.y, B1);
      FMA4(acc[2][0], A0.z, B0); FMA4(acc[2][1], A0.z, B1);
      FMA4(acc[3][0], A0.w, B0); FMA4(acc[3][1], A0.w, B1);
      FMA4(acc[4][0], A1.x, B0); FMA4(acc[4][1], A1.x, B1);
      FMA4(acc[5][0], A1.y, B0); FMA4(acc[5][1], A1.y, B1);
      FMA4(acc[6][0], A1.z, B0); FMA4(acc[6][1], A1.z, B1);
      FMA4(acc[7][0], A1.w, B0); FMA4(acc[7][1], A1.w, B1);
    }
    __syncthreads();
  }
  float* Db = D + (long)m0*N + n0;
  #pragma unroll
  for (int i=0;i<8;i++){
    int mr = (i<4) ? (tm*4+i) : (64+tm*4+(i-4));
    *(float4*)&Db[(long)mr*N + tn*4] = acc[i][0];
    *(float4*)&Db[(long)mr*N + 64 + tn*4] = acc[i][1];
  }
}

// ---------------- row softmax stats (axis=-1, coef_tmp) ----------------
__global__ __launch_bounds__(256) void row_stats(const float* __restrict__ D, const float* __restrict__ coeft,
                                                 float* __restrict__ rmax, float* __restrict__ rsum){
  int m = blockIdx.x;
  const float* drow = D + (long)m*2304;
  float ct = *coeft;
  float v[9];
  float mx = -INFINITY;
  #pragma unroll
  for (int i=0;i<9;i++){ v[i] = ct * drow[threadIdx.x + i*256]; mx = fmaxf(mx, v[i]); }
  __shared__ float sm[4];
  for (int o=32;o;o>>=1) mx = fmaxf(mx, __shfl_down(mx,o));
  int lane = threadIdx.x & 63, wv = threadIdx.x>>6;
  if (lane==0) sm[wv]=mx;
  __syncthreads();
  mx = fmaxf(fmaxf(sm[0],sm[1]),fmaxf(sm[2],sm[3]));
  __syncthreads();
  float s=0.f;
  #pragma unroll
  for (int i=0;i<9;i++) s += expf(v[i]-mx);
  for (int o=32;o;o>>=1) s += __shfl_down(s,o);
  if (lane==0) sm[wv]=s;
  __syncthreads();
  if (threadIdx.x==0){ rmax[m]=mx; rsum[m]=sm[0]+sm[1]+sm[2]+sm[3]; }
}

// ---------------- column softmax stats (axis=-2, coef_ref) ----------------
__device__ __forceinline__ void merge_ms(float& m, float& s, float m2, float s2){
  float M = fmaxf(m, m2);
  s = s*expf(m - M) + s2*expf(m2 - M);
  m = M;
}

__global__ __launch_bounds__(256) void colstat_part(const float* __restrict__ D, const float* __restrict__ coefr,
                                                    float* __restrict__ pm, float* __restrict__ ps){
  int tx = threadIdx.x & 63, ty = threadIdx.x >> 6;
  int n = blockIdx.x*64 + tx;
  float cr = *coefr;
  float m = -INFINITY, s = 0.f;
  int r0 = blockIdx.y * 576;
  for (int r = r0 + ty; r < r0 + 576; r += 4){
    float v = cr * D[(long)r*2304 + n];
    if (v > m){ s = s*expf(m - v) + 1.f; m = v; }
    else s += expf(v - m);
  }
  __shared__ float smm[4][64], sms[4][64];
  smm[ty][tx]=m; sms[ty][tx]=s;
  __syncthreads();
  if (ty==0){
    #pragma unroll
    for (int k=1;k<4;k++) merge_ms(m, s, smm[k][tx], sms[k][tx]);
    pm[(long)blockIdx.y*2304 + n] = m;
    ps[(long)blockIdx.y*2304 + n] = s;
  }
}

__global__ void colstat_merge(const float* __restrict__ pm, const float* __restrict__ ps,
                              float* __restrict__ cm, float* __restrict__ cs){
  int idx = blockIdx.x*256 + threadIdx.x;
  if (idx >= 2304) return;
  float m=-INFINITY, s=0.f;
  for (int k=0;k<16;k++){
    merge_ms(m, s, pm[(long)k*2304+idx], ps[(long)k*2304+idx]);
  }
  cm[idx]=m; cs[idx]=s;
}

// ---------------- confidence + top-10 mean ----------------
__global__ __launch_bounds__(256) void conf_topk(const float* __restrict__ D,
    const float* __restrict__ coefr, const float* __restrict__ coeft,
    const float* __restrict__ rmax, const float* __restrict__ rsum,
    const float* __restrict__ cmax, const float* __restrict__ csum,
    float* __restrict__ outp){
  int m = blockIdx.x;
  const float* drow = D + (long)m*2304;
  float cr = *coefr, ct = *coeft;
  float rm = rmax[m], rs = rsum[m];
  float vals[9];
  #pragma unroll
  for (int i=0;i<9;i++){
    int n = threadIdx.x + i*256;
    float d = drow[n];
    float e = expf(0.5f*((cr+ct)*d - cmax[n] - rm));
    vals[i] = e / sqrtf(csum[n]*rs);
  }
  __shared__ float smv[4]; __shared__ int smi[4];
  float total = 0.f;
  for (int t=0;t<10;t++){
    float lv = -1.f; int li = 0;
    #pragma unroll
    for (int i=0;i<9;i++) if (vals[i] > lv){ lv = vals[i]; li = i; }
    float v = lv; int idx = li*256 + threadIdx.x;
    for (int o=32;o;o>>=1){
      float v2 = __shfl_down(v,o); int i2 = __shfl_down(idx,o);
      if (v2 > v || (v2 == v && i2 < idx)){ v=v2; idx=i2; }
    }
    int lane = threadIdx.x&63, wv = threadIdx.x>>6;
    if (lane==0){ smv[wv]=v; smi[wv]=idx; }
    __syncthreads();
    float bv = smv[0]; int bi = smi[0];
    #pragma unroll
    for (int k=1;k<4;k++){ float v2=smv[k]; int i2=smi[k]; if (v2>bv || (v2==bv && i2<bi)){bv=v2;bi=i2;} }
    total += bv;
    if ((bi & 255) == threadIdx.x) vals[bi>>8] = -2.f;
    __syncthreads();
  }
  if (threadIdx.x==0) outp[m] = total*0.1f;
}

// ---------------- host ----------------
extern "C" void kernel_launch(void* const* d_in, const int* in_sizes, int n_in,
                              void* d_out, int out_size, void* d_ws, size_t ws_size,
                              hipStream_t stream) {
  const float *W[8], *Bp[8], *xr, *xt, *cr, *ct;
  if (in_sizes[0] == 1728){
    for (int i=0;i<8;i++){ W[i]=(const float*)d_in[2*i]; Bp[i]=(const float*)d_in[2*i+1]; }
    xr=(const float*)d_in[16]; xt=(const float*)d_in[17];
    cr=(const float*)d_in[18]; ct=(const float*)d_in[19];
  } else {
    xr=(const float*)d_in[0]; xt=(const float*)d_in[1];
    cr=(const float*)d_in[2]; ct=(const float*)d_in[3];
    for (int i=0;i<8;i++){ W[i]=(const float*)d_in[4+2*i]; Bp[i]=(const float*)d_in[5+2*i]; }
  }

  float* ws = (float*)d_ws;
  long off = 0;
  auto alloc = [&](long nfl){ float* p = ws + off; off += (nfl + 63) & ~63L; return p; };
  float* featR = alloc(2L*320*9216);
  float* featT = alloc(2L*320*2304);
  float* meanb = alloc(640);
  float* rmax  = alloc(2L*9216);
  float* rsum  = alloc(2L*9216);
  float* pm    = alloc(16L*2304);
  float* ps    = alloc(16L*2304);
  float* cm    = alloc(2304);
  float* cs    = alloc(2304);
  float* scratch = alloc(9216L*2304);
  if ((size_t)(off*4) > ws_size) return;

  float* tA = scratch;                   // [2,64,96,96]
  float* tB = tA + 2L*64*9216;           // [2,64,48,48]
  float* tC = tB + 2L*64*2304;           // [2,128,48,48]
  float* tD = tC + 2L*128*2304;          // [2,128,48,48]
  float* tE = tD + 2L*128*2304;          // [2,128,24,24]
  float* tF = tE + 2L*128*576;           // [2,256,24,24]
  float* tG = tF + 2L*256*576;           // [2,256,24,24]
  float* tP = tG + 2L*256*576;           // CI-split partials (max 4*2*256*576)
  float* dist = scratch;

  auto convl = [&](const float* in, int i, float* outF, long outBSf,
                   int CI, int CO, int H, int Wd, long inBS, int cob, int S){
    int tiles = ((Wd+15)/16)*((H+15)/16);
    int nci = CI/S;
    dim3 g(tiles, CO/cob, 2*S);
    float* outArg; long sStr, oBS; const float* biasArg;
    if (S==1){ outArg=outF; sStr=0; oBS=outBSf; biasArg=Bp[i]; }
    else { outArg=tP; sStr=2L*CO*H*Wd; oBS=(long)CO*H*Wd; biasArg=nullptr; }
    if (CI == 3)
      conv3x3_v3<8,3><<<g,256,0,stream>>>(in, W[i], biasArg, outArg, CI, nci, S, H, Wd, inBS, oBS, sStr);
    else if (cob == 8)
      conv3x3_v3<8,8><<<g,256,0,stream>>>(in, W[i], biasArg, outArg, CI, nci, S, H, Wd, inBS, oBS, sStr);
    else if (cob == 4)
      conv3x3_v3<4,8><<<g,256,0,stream>>>(in, W[i], biasArg, outArg, CI, nci, S, H, Wd, inBS, oBS, sStr);
    else
      conv3x3_v3<2,8><<<g,256,0,stream>>>(in, W[i], biasArg, outArg, CI, nci, S, H, Wd, inBS, oBS, sStr);
    if (S > 1){
      long tot = 2L*CO*H*Wd;
      reduce_bias_relu<<<dim3((unsigned)((tot+255)/256)),256,0,stream>>>(
          tP, Bp[i], outF, S, sStr, CO, H*Wd, outBSf);
    }
  };
  auto pooll = [&](const float* in, float* out, long NC, int Hi, int Wi){
    long total = NC*(Hi/2)*(Wi/2);
    maxpool2<<<dim3((unsigned)((total+255)/256)), 256, 0, stream>>>(in, out, NC, Hi, Wi);
  };

  // ---- reference path (96x96) ----
  convl(xr,    0, featR, 320L*9216, 3,   64, 96, 96, 3L*9216,   8, 1);
  convl(featR, 1, tA,    64L*9216,  64,  64, 96, 96, 320L*9216, 8, 1);
  pooll(tA, tB, 2L*64, 96, 96);
  convl(tB, 2, tC, 128L*2304, 64,  128, 48, 48, 64L*2304,  4, 1);
  convl(tC, 3, tD, 128L*2304, 128, 128, 48, 48, 128L*2304, 4, 2);
  pooll(tD, tE, 2L*128, 48, 48);
  convl(tE, 4, tF, 256L*576, 128, 256, 24, 24, 128L*576, 4, 2);
  convl(tF, 5, tG, 256L*576, 256, 256, 24, 24, 256L*576, 4, 4);
  convl(tG, 6, tF, 256L*576, 256, 256, 24, 24, 256L*576, 4, 4);
  convl(tF, 7, tG, 256L*576, 256, 256, 24, 24, 256L*576, 4, 4);
  bicubic_up<<<dim3(256,2), 256, 0, stream>>>(tG, featR + 64L*9216, 24,24,96,96, 256L*576, 320L*9216);

  // ---- template path (48x48) ----
  convl(xt,    0, featT, 320L*2304, 3,   64, 48, 48, 3L*2304,   8, 1);
  convl(featT, 1, tA,    64L*2304,  64,  64, 48, 48, 320L*2304, 4, 2);
  pooll(tA, tB, 2L*64, 48, 48);
  convl(tB, 2, tC, 128L*576, 64,  128, 24, 24, 64L*576,  2, 2);
  convl(tC, 3, tD, 128L*576, 128, 128, 24, 24, 128L*576, 2, 2);
  pooll(tD, tE, 2L*128, 24, 24);
  convl(tE, 4, tF, 256L*144, 128, 256, 12, 12, 128L*144, 2, 4);
  convl(tF, 5, tG, 256L*144, 256, 256, 12, 12, 256L*144, 2, 4);
  convl(tG, 6, tF, 256L*144, 256, 256, 12, 12, 256L*144, 2, 4);
  convl(tF, 7, tG, 256L*144, 256, 256, 12, 12, 256L*144, 2, 4);
  bicubic_up<<<dim3(256,2), 256, 0, stream>>>(tG, featT + 64L*2304, 12,12,48,48, 256L*144, 320L*2304);

  // ---- normalizer (std = mean bug preserved) ----
  mean_k<<<640, 256, 0, stream>>>(featR, featT, meanb);
  norm_apply<<<dim3((unsigned)((5898240L+255)/256)), 256, 0, stream>>>(featR, meanb, 9216L, 2L*320*9216);
  norm_apply<<<dim3((unsigned)((1474560L+255)/256)), 256, 0, stream>>>(featT, meanb, 2304L, 2L*320*2304);

  // ---- per-batch: dist GEMM, softmax stats, conf + top-10 ----
  for (int b=0; b<2; b++){
    const float* Ab = featR + (long)b*320*9216;
    const float* Bb = featT + (long)b*320*2304;
    gemm128<<<dim3(18,72), 256, 0, stream>>>(Ab, Bb, dist);
    row_stats<<<dim3(9216), 256, 0, stream>>>(dist, ct, rmax + (long)b*9216, rsum + (long)b*9216);
    colstat_part<<<dim3(36,16), 256, 0, stream>>>(dist, cr, pm, ps);
    colstat_merge<<<dim3(9), 256, 0, stream>>>(pm, ps, cm, cs);
    conf_topk<<<dim3(9216), 256, 0, stream>>>(dist, cr, ct,
        rmax + (long)b*9216, rsum + (long)b*9216, cm, cs, (float*)d_out + (long)b*9216);
  }
}

// Round 4
// 1732.157 us; speedup vs baseline: 2.0187x; 1.0850x over previous
//
#include <hip/hip_runtime.h>
#include <math.h>

#define CK_A (-0.75f)

__device__ __forceinline__ float cubicw(float t){
  float at = fabsf(t);
  float at2 = at*at, at3 = at2*at;
  if (at <= 1.f) return (CK_A+2.f)*at3 - (CK_A+3.f)*at2 + 1.f;
  if (at < 2.f)  return CK_A*at3 - 5.f*CK_A*at2 + 8.f*CK_A*at - 4.f*CK_A;
  return 0.f;
}

// ---------------- conv 3x3 SAME, CI-split, scalar (SMEM) weights ----------
// Weights read via block-uniform addresses -> compiler emits s_load on the
// scalar pipe: zero VALU/LDS issue cost. Input tile staged in LDS per
// CICH-channel chunk. blockIdx.z = b*S + s; S>1 writes raw partials.
template<int COB, int CICH>
__global__ __launch_bounds__(256) void conv3x3_v4(
    const float* __restrict__ in, const float* __restrict__ w, const float* __restrict__ bias,
    float* __restrict__ out, int CI, int nci, int S, int H, int W,
    long inBS, long outBS, long sStride)
{
  int tilesX = (W + 15) >> 4;
  int tx0 = (blockIdx.x % tilesX) << 4;
  int ty0 = (blockIdx.x / tilesX) << 4;
  int cob = blockIdx.y * COB;
  int s = blockIdx.z % S, b = blockIdx.z / S;
  int ci0 = s * nci;
  int lx = threadIdx.x & 15, ly = threadIdx.x >> 4;
  __shared__ float tile[CICH][18][20];
  float acc[COB];
  #pragma unroll
  for (int j=0;j<COB;j++) acc[j]=0.f;
  const float* inb = in + (long)b*inBS;
  int ox = tx0+lx, oy = ty0+ly;

  for (int c0=ci0; c0<ci0+nci; c0+=CICH){
    for (int idx = threadIdx.x; idx < CICH*324; idx += 256){
      int cl = idx/324, rem = idx - cl*324;
      int r = rem/18, c = rem - r*18;
      int gy = ty0 + r - 1, gx = tx0 + c - 1;
      const float* ic = inb + (long)(c0+cl)*H*W;
      tile[cl][r][c] = (gy>=0 && gy<H && gx>=0 && gx<W) ? ic[(long)gy*W+gx] : 0.f;
    }
    __syncthreads();
    #pragma unroll
    for (int cl=0; cl<CICH; cl++){
      float t00=tile[cl][ly+0][lx+0], t01=tile[cl][ly+0][lx+1], t02=tile[cl][ly+0][lx+2];
      float t10=tile[cl][ly+1][lx+0], t11=tile[cl][ly+1][lx+1], t12=tile[cl][ly+1][lx+2];
      float t20=tile[cl][ly+2][lx+0], t21=tile[cl][ly+2][lx+1], t22=tile[cl][ly+2][lx+2];
      #pragma unroll
      for (int j=0;j<COB;j++){
        const float* wp = w + ((long)(cob+j)*CI + (c0+cl))*9;   // block-uniform -> s_load
        float a = acc[j];
        a = fmaf(t00, wp[0], a); a = fmaf(t01, wp[1], a); a = fmaf(t02, wp[2], a);
        a = fmaf(t10, wp[3], a); a = fmaf(t11, wp[4], a); a = fmaf(t12, wp[5], a);
        a = fmaf(t20, wp[6], a); a = fmaf(t21, wp[7], a); a = fmaf(t22, wp[8], a);
        acc[j] = a;
      }
    }
    __syncthreads();
  }
  if (ox < W && oy < H){
    float* outp = out + (long)s*sStride + (long)b*outBS;
    #pragma unroll
    for (int j=0;j<COB;j++){
      float v = acc[j];
      if (bias) v = fmaxf(v + bias[cob+j], 0.f);
      outp[(long)(cob+j)*H*W + (long)oy*W + ox] = v;
    }
  }
}

// ---------------- partial reduce + bias + relu ----------------
__global__ void reduce_bias_relu(const float* __restrict__ part, const float* __restrict__ bias,
                                 float* __restrict__ out, int S, long sStride,
                                 int CO, int HW, long outBS){
  long tot = 2L*CO*HW;
  long e = (long)blockIdx.x*256 + threadIdx.x;
  if (e >= tot) return;
  long b = e / ((long)CO*HW);
  long r = e - b*(long)CO*HW;
  float v = 0.f;
  for (int s=0;s<S;s++) v += part[(long)s*sStride + e];
  int co = (int)(r / HW);
  out[b*outBS + r] = fmaxf(v + bias[co], 0.f);
}

// ---------------- maxpool 2x2 stride 2 ----------------
__global__ void maxpool2(const float* __restrict__ in, float* __restrict__ out, long NC, int Hi, int Wi){
  int Ho = Hi>>1, Wo = Wi>>1;
  long total = NC * Ho * Wo;
  long idx = (long)blockIdx.x*256 + threadIdx.x;
  if (idx >= total) return;
  int x = (int)(idx % Wo); long t = idx / Wo; int y = (int)(t % Ho); long nc = t / Ho;
  const float* p = in + (nc*Hi + 2*y)*(long)Wi + 2*x;
  float v = fmaxf(fmaxf(p[0], p[1]), fmaxf(p[Wi], p[Wi+1]));
  out[idx] = v;
}

// ---------------- bicubic upsample (align_corners=True) ----------------
__global__ __launch_bounds__(256) void bicubic_up(
    const float* __restrict__ in, float* __restrict__ out,
    int Hin, int Win, int Hout, int Wout, long inBStride, long outBStride)
{
  int c = blockIdx.x, b = blockIdx.y;
  __shared__ float s[576];
  const float* ip = in + (long)b*inBStride + (long)c*Hin*Win;
  float* op = out + (long)b*outBStride + (long)c*Hout*Wout;
  int n = Hin*Win;
  for (int i = threadIdx.x; i < n; i += 256) s[i] = ip[i];
  __syncthreads();
  float scy = (float)((double)(Hin-1)/(double)(Hout-1));
  float scx = (float)((double)(Win-1)/(double)(Wout-1));
  int total = Hout*Wout;
  for (int idx = threadIdx.x; idx < total; idx += 256){
    int ox = idx % Wout, oy = idx / Wout;
    float py = oy * scy, px = ox * scx;
    float iy0f = floorf(py), ix0f = floorf(px);
    int iy0 = (int)iy0f, ix0 = (int)ix0f;
    float fy = py - iy0f, fx = px - ix0f;
    float wy[4], wx[4]; int xs[4], ys[4];
    #pragma unroll
    for (int t=0;t<4;t++){
      wy[t] = cubicw(fy - (float)(t-1));
      wx[t] = cubicw(fx - (float)(t-1));
      ys[t] = min(max(iy0 + t - 1, 0), Hin-1);
      xs[t] = min(max(ix0 + t - 1, 0), Win-1);
    }
    float acc = 0.f;
    #pragma unroll
    for (int i=0;i<4;i++){
      const float* row = &s[ys[i]*Win];
      float rs = wx[0]*row[xs[0]] + wx[1]*row[xs[1]] + wx[2]*row[xs[2]] + wx[3]*row[xs[3]];
      acc = fmaf(wy[i], rs, acc);
    }
    op[idx] = acc;
  }
}

// ---------------- normalizer ----------------
__global__ __launch_bounds__(256) void mean_k(const float* __restrict__ fR, const float* __restrict__ fT, float* __restrict__ mean){
  int c = blockIdx.x % 320, b = blockIdx.x / 320;
  const float* a = fR + ((long)b*320+c)*9216L;
  const float* t = fT + ((long)b*320+c)*2304L;
  float s = 0.f;
  for (int i=threadIdx.x;i<9216;i+=256) s += a[i];
  for (int i=threadIdx.x;i<2304;i+=256) s += t[i];
  __shared__ float sm[4];
  for (int o=32;o;o>>=1) s += __shfl_down(s,o);
  int lane = threadIdx.x & 63, wv = threadIdx.x >> 6;
  if (lane==0) sm[wv] = s;
  __syncthreads();
  if (threadIdx.x==0) mean[b*320+c] = (sm[0]+sm[1]+sm[2]+sm[3]) * (1.f/11520.f);
}

__global__ void norm_apply(float* __restrict__ f, const float* __restrict__ mean, long perChan, long total){
  long idx = (long)blockIdx.x*256 + threadIdx.x;
  if (idx >= total) return;
  long c = (idx / perChan) % 320;
  long b = idx / (perChan*320);
  float m = mean[b*320+c];
  f[idx] = (f[idx] - m) / (m + 1e-8f);
}

// ---------------- dist GEMM: D[m][n] = sum_k A[k][m]*B[k][n] ----------------
#define FMA4(ac, s, b) { ac.x=fmaf(s,b.x,ac.x); ac.y=fmaf(s,b.y,ac.y); ac.z=fmaf(s,b.z,ac.z); ac.w=fmaf(s,b.w,ac.w); }

__global__ __launch_bounds__(256) void gemm128(const float* __restrict__ A, const float* __restrict__ Bv, float* __restrict__ D){
  const int M=9216, N=2304, K=320;
  int n0 = blockIdx.x*128, m0 = blockIdx.y*128;
  const float* Ab = A + m0;
  const float* Bb = Bv + n0;
  __shared__ float As[8][128], Bs[8][128];
  int tid = threadIdx.x;
  int tn = tid & 15, tm = tid >> 4;
  float4 acc[8][2];
  #pragma unroll
  for (int i=0;i<8;i++){
    acc[i][0] = make_float4(0.f,0.f,0.f,0.f);
    acc[i][1] = make_float4(0.f,0.f,0.f,0.f);
  }
  int la = tid*4; int lk = la >> 7; int lm = la & 127;
  for (int k0=0;k0<K;k0+=8){
    *(float4*)&As[lk][lm] = *(const float4*)&Ab[(long)(k0+lk)*M + lm];
    *(float4*)&Bs[lk][lm] = *(const float4*)&Bb[(long)(k0+lk)*N + lm];
    __syncthreads();
    #pragma unroll
    for (int kk=0;kk<8;kk++){
      float4 A0 = *(float4*)&As[kk][tm*4];
      float4 A1 = *(float4*)&As[kk][64+tm*4];
      float4 B0 = *(float4*)&Bs[kk][tn*4];
      float4 B1 = *(float4*)&Bs[kk][64+tn*4];
      FMA4(acc[0][0], A0.x, B0); FMA4(acc[0][1], A0.x, B1);
      FMA4(acc[1][0], A0.y, B0); FMA4(acc[1][1], A0.y, B1);
      FMA4(acc[2][0], A0.z, B0); FMA4(acc[2][1], A0.z, B1);
      FMA4(acc[3][0], A0.w, B0); FMA4(acc[3][1], A0.w, B1);
      FMA4(acc[4][0], A1.x, B0); FMA4(acc[4][1], A1.x, B1);
      FMA4(acc[5][0], A1.y, B0); FMA4(acc[5][1], A1.y, B1);
      FMA4(acc[6][0], A1.z, B0); FMA4(acc[6][1], A1.z, B1);
      FMA4(acc[7][0], A1.w, B0); FMA4(acc[7][1], A1.w, B1);
    }
    __syncthreads();
  }
  float* Db = D + (long)m0*N + n0;
  #pragma unroll
  for (int i=0;i<8;i++){
    int mr = (i<4) ? (tm*4+i) : (64+tm*4+(i-4));
    *(float4*)&Db[(long)mr*N + tn*4] = acc[i][0];
    *(float4*)&Db[(long)mr*N + 64 + tn*4] = acc[i][1];
  }
}

// ---------------- row softmax stats (axis=-1, coef_tmp) ----------------
__global__ __launch_bounds__(256) void row_stats(const float* __restrict__ D, const float* __restrict__ coeft,
                                                 float* __restrict__ rmax, float* __restrict__ rsum){
  int m = blockIdx.x;
  const float* drow = D + (long)m*2304;
  float ct = *coeft;
  float v[9];
  float mx = -INFINITY;
  #pragma unroll
  for (int i=0;i<9;i++){ v[i] = ct * drow[threadIdx.x + i*256]; mx = fmaxf(mx, v[i]); }
  __shared__ float sm[4];
  for (int o=32;o;o>>=1) mx = fmaxf(mx, __shfl_down(mx,o));
  int lane = threadIdx.x & 63, wv = threadIdx.x>>6;
  if (lane==0) sm[wv]=mx;
  __syncthreads();
  mx = fmaxf(fmaxf(sm[0],sm[1]),fmaxf(sm[2],sm[3]));
  __syncthreads();
  float s=0.f;
  #pragma unroll
  for (int i=0;i<9;i++) s += expf(v[i]-mx);
  for (int o=32;o;o>>=1) s += __shfl_down(s,o);
  if (lane==0) sm[wv]=s;
  __syncthreads();
  if (threadIdx.x==0){ rmax[m]=mx; rsum[m]=sm[0]+sm[1]+sm[2]+sm[3]; }
}

// ---------------- column softmax stats (axis=-2, coef_ref) ----------------
__device__ __forceinline__ void merge_ms(float& m, float& s, float m2, float s2){
  float M = fmaxf(m, m2);
  s = s*expf(m - M) + s2*expf(m2 - M);
  m = M;
}

__global__ __launch_bounds__(256) void colstat_part(const float* __restrict__ D, const float* __restrict__ coefr,
                                                    float* __restrict__ pm, float* __restrict__ ps){
  int tx = threadIdx.x & 63, ty = threadIdx.x >> 6;
  int n = blockIdx.x*64 + tx;
  float cr = *coefr;
  float m = -INFINITY, s = 0.f;
  int r0 = blockIdx.y * 576;
  for (int r = r0 + ty; r < r0 + 576; r += 4){
    float v = cr * D[(long)r*2304 + n];
    if (v > m){ s = s*expf(m - v) + 1.f; m = v; }
    else s += expf(v - m);
  }
  __shared__ float smm[4][64], sms[4][64];
  smm[ty][tx]=m; sms[ty][tx]=s;
  __syncthreads();
  if (ty==0){
    #pragma unroll
    for (int k=1;k<4;k++) merge_ms(m, s, smm[k][tx], sms[k][tx]);
    pm[(long)blockIdx.y*2304 + n] = m;
    ps[(long)blockIdx.y*2304 + n] = s;
  }
}

__global__ void colstat_merge(const float* __restrict__ pm, const float* __restrict__ ps,
                              float* __restrict__ cm, float* __restrict__ cs){
  int idx = blockIdx.x*256 + threadIdx.x;
  if (idx >= 2304) return;
  float m=-INFINITY, s=0.f;
  for (int k=0;k<16;k++){
    merge_ms(m, s, pm[(long)k*2304+idx], ps[(long)k*2304+idx]);
  }
  cm[idx]=m; cs[idx]=s;
}

// ---------------- confidence + top-10 mean ----------------
__global__ __launch_bounds__(256) void conf_topk(const float* __restrict__ D,
    const float* __restrict__ coefr, const float* __restrict__ coeft,
    const float* __restrict__ rmax, const float* __restrict__ rsum,
    const float* __restrict__ cmax, const float* __restrict__ csum,
    float* __restrict__ outp){
  int m = blockIdx.x;
  const float* drow = D + (long)m*2304;
  float cr = *coefr, ct = *coeft;
  float rm = rmax[m], rs = rsum[m];
  float vals[9];
  #pragma unroll
  for (int i=0;i<9;i++){
    int n = threadIdx.x + i*256;
    float d = drow[n];
    float e = expf(0.5f*((cr+ct)*d - cmax[n] - rm));
    vals[i] = e / sqrtf(csum[n]*rs);
  }
  __shared__ float smv[4]; __shared__ int smi[4];
  float total = 0.f;
  for (int t=0;t<10;t++){
    float lv = -1.f; int li = 0;
    #pragma unroll
    for (int i=0;i<9;i++) if (vals[i] > lv){ lv = vals[i]; li = i; }
    float v = lv; int idx = li*256 + threadIdx.x;
    for (int o=32;o;o>>=1){
      float v2 = __shfl_down(v,o); int i2 = __shfl_down(idx,o);
      if (v2 > v || (v2 == v && i2 < idx)){ v=v2; idx=i2; }
    }
    int lane = threadIdx.x&63, wv = threadIdx.x>>6;
    if (lane==0){ smv[wv]=v; smi[wv]=idx; }
    __syncthreads();
    float bv = smv[0]; int bi = smi[0];
    #pragma unroll
    for (int k=1;k<4;k++){ float v2=smv[k]; int i2=smi[k]; if (v2>bv || (v2==bv && i2<bi)){bv=v2;bi=i2;} }
    total += bv;
    if ((bi & 255) == threadIdx.x) vals[bi>>8] = -2.f;
    __syncthreads();
  }
  if (threadIdx.x==0) outp[m] = total*0.1f;
}

// ---------------- host ----------------
extern "C" void kernel_launch(void* const* d_in, const int* in_sizes, int n_in,
                              void* d_out, int out_size, void* d_ws, size_t ws_size,
                              hipStream_t stream) {
  const float *W[8], *Bp[8], *xr, *xt, *cr, *ct;
  if (in_sizes[0] == 1728){
    for (int i=0;i<8;i++){ W[i]=(const float*)d_in[2*i]; Bp[i]=(const float*)d_in[2*i+1]; }
    xr=(const float*)d_in[16]; xt=(const float*)d_in[17];
    cr=(const float*)d_in[18]; ct=(const float*)d_in[19];
  } else {
    xr=(const float*)d_in[0]; xt=(const float*)d_in[1];
    cr=(const float*)d_in[2]; ct=(const float*)d_in[3];
    for (int i=0;i<8;i++){ W[i]=(const float*)d_in[4+2*i]; Bp[i]=(const float*)d_in[5+2*i]; }
  }

  float* ws = (float*)d_ws;
  long off = 0;
  auto alloc = [&](long nfl){ float* p = ws + off; off += (nfl + 63) & ~63L; return p; };
  float* featR = alloc(2L*320*9216);
  float* featT = alloc(2L*320*2304);
  float* meanb = alloc(640);
  float* rmax  = alloc(2L*9216);
  float* rsum  = alloc(2L*9216);
  float* pm    = alloc(16L*2304);
  float* ps    = alloc(16L*2304);
  float* cm    = alloc(2304);
  float* cs    = alloc(2304);
  float* scratch = alloc(9216L*2304);
  if ((size_t)(off*4) > ws_size) return;

  float* tA = scratch;                   // [2,64,96,96]
  float* tB = tA + 2L*64*9216;           // [2,64,48,48]
  float* tC = tB + 2L*64*2304;           // [2,128,48,48]
  float* tD = tC + 2L*128*2304;          // [2,128,48,48]
  float* tE = tD + 2L*128*2304;          // [2,128,24,24]
  float* tF = tE + 2L*128*576;           // [2,256,24,24]
  float* tG = tF + 2L*256*576;           // [2,256,24,24]
  float* tP = tG + 2L*256*576;           // CI-split partials (max ~2.4M floats)
  float* dist = scratch;

  auto convl = [&](const float* in, int i, float* outF, long outBSf,
                   int CI, int CO, int H, int Wd, long inBS, int cob, int S){
    int tiles = ((Wd+15)/16)*((H+15)/16);
    int nci = CI/S;
    dim3 g(tiles, CO/cob, 2*S);
    float* outArg; long sStr, oBS; const float* biasArg;
    if (S==1){ outArg=outF; sStr=0; oBS=outBSf; biasArg=Bp[i]; }
    else { outArg=tP; sStr=2L*CO*H*Wd; oBS=(long)CO*H*Wd; biasArg=nullptr; }
    if (CI == 3)
      conv3x3_v4<8,3><<<g,256,0,stream>>>(in, W[i], biasArg, outArg, CI, nci, S, H, Wd, inBS, oBS, sStr);
    else if (cob == 8)
      conv3x3_v4<8,8><<<g,256,0,stream>>>(in, W[i], biasArg, outArg, CI, nci, S, H, Wd, inBS, oBS, sStr);
    else
      conv3x3_v4<4,8><<<g,256,0,stream>>>(in, W[i], biasArg, outArg, CI, nci, S, H, Wd, inBS, oBS, sStr);
    if (S > 1){
      long tot = 2L*CO*H*Wd;
      reduce_bias_relu<<<dim3((unsigned)((tot+255)/256)),256,0,stream>>>(
          tP, Bp[i], outF, S, sStr, CO, H*Wd, outBSf);
    }
  };
  auto pooll = [&](const float* in, float* out, long NC, int Hi, int Wi){
    long total = NC*(Hi/2)*(Wi/2);
    maxpool2<<<dim3((unsigned)((total+255)/256)), 256, 0, stream>>>(in, out, NC, Hi, Wi);
  };

  // ---- reference path (96x96) ----
  convl(xr,    0, featR, 320L*9216, 3,   64, 96, 96, 3L*9216,   8, 1);  // 576 blocks
  convl(featR, 1, tA,    64L*9216,  64,  64, 96, 96, 320L*9216, 8, 2);  // 1152
  pooll(tA, tB, 2L*64, 96, 96);
  convl(tB, 2, tC, 128L*2304, 64,  128, 48, 48, 64L*2304,  8, 2);       // 576
  convl(tC, 3, tD, 128L*2304, 128, 128, 48, 48, 128L*2304, 8, 2);       // 576
  pooll(tD, tE, 2L*128, 48, 48);
  convl(tE, 4, tF, 256L*576, 128, 256, 24, 24, 128L*576, 8, 2);         // 512
  convl(tF, 5, tG, 256L*576, 256, 256, 24, 24, 256L*576, 8, 4);         // 1024
  convl(tG, 6, tF, 256L*576, 256, 256, 24, 24, 256L*576, 8, 4);
  convl(tF, 7, tG, 256L*576, 256, 256, 24, 24, 256L*576, 8, 4);
  bicubic_up<<<dim3(256,2), 256, 0, stream>>>(tG, featR + 64L*9216, 24,24,96,96, 256L*576, 320L*9216);

  // ---- template path (48x48) ----
  convl(xt,    0, featT, 320L*2304, 3,   64, 48, 48, 3L*2304,   8, 1);  // 144
  convl(featT, 1, tA,    64L*2304,  64,  64, 48, 48, 320L*2304, 4, 2);  // 576
  pooll(tA, tB, 2L*64, 48, 48);
  convl(tB, 2, tC, 128L*576, 64,  128, 24, 24, 64L*576,  4, 2);         // 512
  convl(tC, 3, tD, 128L*576, 128, 128, 24, 24, 128L*576, 4, 2);         // 512
  pooll(tD, tE, 2L*128, 24, 24);
  convl(tE, 4, tF, 256L*144, 128, 256, 12, 12, 128L*144, 4, 4);         // 512
  convl(tF, 5, tG, 256L*144, 256, 256, 12, 12, 256L*144, 4, 4);
  convl(tG, 6, tF, 256L*144, 256, 256, 12, 12, 256L*144, 4, 4);
  convl(tF, 7, tG, 256L*144, 256, 256, 12, 12, 256L*144, 4, 4);
  bicubic_up<<<dim3(256,2), 256, 0, stream>>>(tG, featT + 64L*2304, 12,12,48,48, 256L*144, 320L*2304);

  // ---- normalizer (std = mean bug preserved) ----
  mean_k<<<640, 256, 0, stream>>>(featR, featT, meanb);
  norm_apply<<<dim3((unsigned)((5898240L+255)/256)), 256, 0, stream>>>(featR, meanb, 9216L, 2L*320*9216);
  norm_apply<<<dim3((unsigned)((1474560L+255)/256)), 256, 0, stream>>>(featT, meanb, 2304L, 2L*320*2304);

  // ---- per-batch: dist GEMM, softmax stats, conf + top-10 ----
  for (int b=0; b<2; b++){
    const float* Ab = featR + (long)b*320*9216;
    const float* Bb = featT + (long)b*320*2304;
    gemm128<<<dim3(18,72), 256, 0, stream>>>(Ab, Bb, dist);
    row_stats<<<dim3(9216), 256, 0, stream>>>(dist, ct, rmax + (long)b*9216, rsum + (long)b*9216);
    colstat_part<<<dim3(36,16), 256, 0, stream>>>(dist, cr, pm, ps);
    colstat_merge<<<dim3(9), 256, 0, stream>>>(pm, ps, cm, cs);
    conf_topk<<<dim3(9216), 256, 0, stream>>>(dist, cr, ct,
        rmax + (long)b*9216, rsum + (long)b*9216, cm, cs, (float*)d_out + (long)b*9216);
  }
}

// Round 5
// 1524.782 us; speedup vs baseline: 2.2932x; 1.1360x over previous
//
#include <hip/hip_runtime.h>
#include <math.h>

#define CK_A (-0.75f)

typedef __attribute__((ext_vector_type(8))) short bf16x8;
typedef __attribute__((ext_vector_type(4))) float f32x4;

__device__ __forceinline__ float cubicw(float t){
  float at = fabsf(t);
  float at2 = at*at, at3 = at2*at;
  if (at <= 1.f) return (CK_A+2.f)*at3 - (CK_A+3.f)*at2 + 1.f;
  if (at < 2.f)  return CK_A*at3 - 5.f*CK_A*at2 + 8.f*CK_A*at - 4.f*CK_A;
  return 0.f;
}

__device__ __forceinline__ unsigned short f2bf_rne(float f){
  unsigned int u = __float_as_uint(f);
  unsigned int r = (u + 0x7fffu + ((u>>16)&1u)) >> 16;
  return (unsigned short)r;
}
__device__ __forceinline__ float bf2f(unsigned short h){
  return __uint_as_float(((unsigned int)h)<<16);
}

// ---------------- conv 3x3 SAME, CI-split, scalar (SMEM) weights ----------
template<int COB, int CICH>
__global__ __launch_bounds__(256) void conv3x3_v4(
    const float* __restrict__ in, const float* __restrict__ w, const float* __restrict__ bias,
    float* __restrict__ out, int CI, int nci, int S, int H, int W,
    long inBS, long outBS, long sStride)
{
  int tilesX = (W + 15) >> 4;
  int tx0 = (blockIdx.x % tilesX) << 4;
  int ty0 = (blockIdx.x / tilesX) << 4;
  int cob = blockIdx.y * COB;
  int s = blockIdx.z % S, b = blockIdx.z / S;
  int ci0 = s * nci;
  int lx = threadIdx.x & 15, ly = threadIdx.x >> 4;
  __shared__ float tile[CICH][18][20];
  float acc[COB];
  #pragma unroll
  for (int j=0;j<COB;j++) acc[j]=0.f;
  const float* inb = in + (long)b*inBS;
  int ox = tx0+lx, oy = ty0+ly;

  for (int c0=ci0; c0<ci0+nci; c0+=CICH){
    for (int idx = threadIdx.x; idx < CICH*324; idx += 256){
      int cl = idx/324, rem = idx - cl*324;
      int r = rem/18, c = rem - r*18;
      int gy = ty0 + r - 1, gx = tx0 + c - 1;
      const float* ic = inb + (long)(c0+cl)*H*W;
      tile[cl][r][c] = (gy>=0 && gy<H && gx>=0 && gx<W) ? ic[(long)gy*W+gx] : 0.f;
    }
    __syncthreads();
    #pragma unroll
    for (int cl=0; cl<CICH; cl++){
      float t00=tile[cl][ly+0][lx+0], t01=tile[cl][ly+0][lx+1], t02=tile[cl][ly+0][lx+2];
      float t10=tile[cl][ly+1][lx+0], t11=tile[cl][ly+1][lx+1], t12=tile[cl][ly+1][lx+2];
      float t20=tile[cl][ly+2][lx+0], t21=tile[cl][ly+2][lx+1], t22=tile[cl][ly+2][lx+2];
      #pragma unroll
      for (int j=0;j<COB;j++){
        const float* wp = w + ((long)(cob+j)*CI + (c0+cl))*9;   // block-uniform -> s_load
        float a = acc[j];
        a = fmaf(t00, wp[0], a); a = fmaf(t01, wp[1], a); a = fmaf(t02, wp[2], a);
        a = fmaf(t10, wp[3], a); a = fmaf(t11, wp[4], a); a = fmaf(t12, wp[5], a);
        a = fmaf(t20, wp[6], a); a = fmaf(t21, wp[7], a); a = fmaf(t22, wp[8], a);
        acc[j] = a;
      }
    }
    __syncthreads();
  }
  if (ox < W && oy < H){
    float* outp = out + (long)s*sStride + (long)b*outBS;
    #pragma unroll
    for (int j=0;j<COB;j++){
      float v = acc[j];
      if (bias) v = fmaxf(v + bias[cob+j], 0.f);
      outp[(long)(cob+j)*H*W + (long)oy*W + ox] = v;
    }
  }
}

// ---------------- partial reduce + bias + relu ----------------
__global__ void reduce_bias_relu(const float* __restrict__ part, const float* __restrict__ bias,
                                 float* __restrict__ out, int S, long sStride,
                                 int CO, int HW, long outBS){
  long tot = 2L*CO*HW;
  long e = (long)blockIdx.x*256 + threadIdx.x;
  if (e >= tot) return;
  long b = e / ((long)CO*HW);
  long r = e - b*(long)CO*HW;
  float v = 0.f;
  for (int s=0;s<S;s++) v += part[(long)s*sStride + e];
  int co = (int)(r / HW);
  out[b*outBS + r] = fmaxf(v + bias[co], 0.f);
}

// ---------------- maxpool 2x2 stride 2 ----------------
__global__ void maxpool2(const float* __restrict__ in, float* __restrict__ out, long NC, int Hi, int Wi){
  int Ho = Hi>>1, Wo = Wi>>1;
  long total = NC * Ho * Wo;
  long idx = (long)blockIdx.x*256 + threadIdx.x;
  if (idx >= total) return;
  int x = (int)(idx % Wo); long t = idx / Wo; int y = (int)(t % Ho); long nc = t / Ho;
  const float* p = in + (nc*Hi + 2*y)*(long)Wi + 2*x;
  float v = fmaxf(fmaxf(p[0], p[1]), fmaxf(p[Wi], p[Wi+1]));
  out[idx] = v;
}

// ---------------- bicubic upsample (align_corners=True) ----------------
__global__ __launch_bounds__(256) void bicubic_up(
    const float* __restrict__ in, float* __restrict__ out,
    int Hin, int Win, int Hout, int Wout, long inBStride, long outBStride)
{
  int c = blockIdx.x, b = blockIdx.y;
  __shared__ float s[576];
  const float* ip = in + (long)b*inBStride + (long)c*Hin*Win;
  float* op = out + (long)b*outBStride + (long)c*Hout*Wout;
  int n = Hin*Win;
  for (int i = threadIdx.x; i < n; i += 256) s[i] = ip[i];
  __syncthreads();
  float scy = (float)((double)(Hin-1)/(double)(Hout-1));
  float scx = (float)((double)(Win-1)/(double)(Wout-1));
  int total = Hout*Wout;
  for (int idx = threadIdx.x; idx < total; idx += 256){
    int ox = idx % Wout, oy = idx / Wout;
    float py = oy * scy, px = ox * scx;
    float iy0f = floorf(py), ix0f = floorf(px);
    int iy0 = (int)iy0f, ix0 = (int)ix0f;
    float fy = py - iy0f, fx = px - ix0f;
    float wy[4], wx[4]; int xs[4], ys[4];
    #pragma unroll
    for (int t=0;t<4;t++){
      wy[t] = cubicw(fy - (float)(t-1));
      wx[t] = cubicw(fx - (float)(t-1));
      ys[t] = min(max(iy0 + t - 1, 0), Hin-1);
      xs[t] = min(max(ix0 + t - 1, 0), Win-1);
    }
    float acc = 0.f;
    #pragma unroll
    for (int i=0;i<4;i++){
      const float* row = &s[ys[i]*Win];
      float rs = wx[0]*row[xs[0]] + wx[1]*row[xs[1]] + wx[2]*row[xs[2]] + wx[3]*row[xs[3]];
      acc = fmaf(wy[i], rs, acc);
    }
    op[idx] = acc;
  }
}

// ---------------- normalizer ----------------
__global__ __launch_bounds__(256) void mean_k(const float* __restrict__ fR, const float* __restrict__ fT, float* __restrict__ mean){
  int c = blockIdx.x % 320, b = blockIdx.x / 320;
  const float* a = fR + ((long)b*320+c)*9216L;
  const float* t = fT + ((long)b*320+c)*2304L;
  float s = 0.f;
  for (int i=threadIdx.x;i<9216;i+=256) s += a[i];
  for (int i=threadIdx.x;i<2304;i+=256) s += t[i];
  __shared__ float sm[4];
  for (int o=32;o;o>>=1) s += __shfl_down(s,o);
  int lane = threadIdx.x & 63, wv = threadIdx.x >> 6;
  if (lane==0) sm[wv] = s;
  __syncthreads();
  if (threadIdx.x==0) mean[b*320+c] = (sm[0]+sm[1]+sm[2]+sm[3]) * (1.f/11520.f);
}

__global__ void norm_apply(float* __restrict__ f, const float* __restrict__ mean, long perChan, long total){
  long idx = (long)blockIdx.x*256 + threadIdx.x;
  if (idx >= total) return;
  long c = (idx / perChan) % 320;
  long b = idx / (perChan*320);
  float m = mean[b*320+c];
  f[idx] = (f[idx] - m) / (m + 1e-8f);
}

// ---------------- split+transpose: feat [2][320][P] fp32 -> hi/lo [2][P][320] bf16
__global__ __launch_bounds__(256) void split_bf16(const float* __restrict__ feat,
    unsigned short* __restrict__ oh, unsigned short* __restrict__ ol, int P){
  int b = blockIdx.y; int m0 = blockIdx.x*32;
  __shared__ unsigned int t[32][321];
  int ml = threadIdx.x & 31, kq = threadIdx.x >> 5;
  const float* fp = feat + (long)b*320*P + m0 + ml;
  for (int k = kq*40; k < kq*40+40; k++){
    float v = fp[(long)k*P];
    unsigned short h = f2bf_rne(v);
    unsigned short l = f2bf_rne(v - bf2f(h));
    t[ml][k] = ((unsigned int)h<<16) | l;
  }
  __syncthreads();
  long base = ((long)b*P + m0)*320;
  for (int idx = threadIdx.x; idx < 32*320; idx += 256){
    int m = idx/320, k = idx - m*320;
    unsigned int p = t[m][k];
    oh[base + (long)m*320 + k] = (unsigned short)(p>>16);
    ol[base + (long)m*320 + k] = (unsigned short)(p & 0xffffu);
  }
}

// ---------------- split-bf16 MFMA GEMM: D[m][n] = sum_k A[m][k]*B[n][k] ----
// A (hi/lo) [9216][320] bf16, B (hi/lo) [2304][320] bf16, D [9216][2304] fp32.
// 128x128 tile, 4 waves (2x2), 16x16x32 MFMA, 4x4 frags/wave,
// D ~= Ah*Bh + Ah*Bl + Al*Bh (Al*Bl dropped, ~2^-16 relative).
union FragU { bf16x8 v; uint2 u[2]; };

__global__ __launch_bounds__(256) void gemm_mfma(
    const unsigned short* __restrict__ Ah, const unsigned short* __restrict__ Al,
    const unsigned short* __restrict__ Bh, const unsigned short* __restrict__ Bl,
    float* __restrict__ D){
  const int N = 2304, K = 320;
  int n0 = blockIdx.x*128, m0 = blockIdx.y*128;
  __shared__ unsigned short As[2][128][36], Bs[2][128][36];  // 36-pad: <=2-way banks
  int tid = threadIdx.x, lane = tid & 63, wid = tid >> 6;
  int wm = wid >> 1, wn = wid & 1;
  f32x4 acc[4][4];
  #pragma unroll
  for (int i=0;i<4;i++)
    #pragma unroll
    for (int j=0;j<4;j++) acc[i][j] = (f32x4){0.f,0.f,0.f,0.f};

  for (int k0=0; k0<K; k0+=32){
    #pragma unroll
    for (int q=0;q<2;q++){
      int flat = q*256 + tid;
      int row = flat >> 2, seg = flat & 3;
      long ga = (long)(m0+row)*K + k0 + seg*8;
      long gb = (long)(n0+row)*K + k0 + seg*8;
      uint4 va = *(const uint4*)(Ah + ga);
      *(uint2*)&As[0][row][seg*8]   = make_uint2(va.x, va.y);
      *(uint2*)&As[0][row][seg*8+4] = make_uint2(va.z, va.w);
      uint4 vb = *(const uint4*)(Al + ga);
      *(uint2*)&As[1][row][seg*8]   = make_uint2(vb.x, vb.y);
      *(uint2*)&As[1][row][seg*8+4] = make_uint2(vb.z, vb.w);
      uint4 vc = *(const uint4*)(Bh + gb);
      *(uint2*)&Bs[0][row][seg*8]   = make_uint2(vc.x, vc.y);
      *(uint2*)&Bs[0][row][seg*8+4] = make_uint2(vc.z, vc.w);
      uint4 vd = *(const uint4*)(Bl + gb);
      *(uint2*)&Bs[1][row][seg*8]   = make_uint2(vd.x, vd.y);
      *(uint2*)&Bs[1][row][seg*8+4] = make_uint2(vd.z, vd.w);
    }
    __syncthreads();

    FragU af[2][4], bf[2][4];
    #pragma unroll
    for (int g=0; g<4; g++){
      const unsigned short* pa0 = &As[0][wm*64 + g*16 + (lane&15)][(lane>>4)*4];
      const unsigned short* pa1 = &As[1][wm*64 + g*16 + (lane&15)][(lane>>4)*4];
      const unsigned short* pb0 = &Bs[0][wn*64 + g*16 + (lane&15)][(lane>>4)*4];
      const unsigned short* pb1 = &Bs[1][wn*64 + g*16 + (lane&15)][(lane>>4)*4];
      af[0][g].u[0] = *(const uint2*)pa0; af[0][g].u[1] = *(const uint2*)(pa0 + 16);
      af[1][g].u[0] = *(const uint2*)pa1; af[1][g].u[1] = *(const uint2*)(pa1 + 16);
      bf[0][g].u[0] = *(const uint2*)pb0; bf[0][g].u[1] = *(const uint2*)(pb0 + 16);
      bf[1][g].u[0] = *(const uint2*)pb1; bf[1][g].u[1] = *(const uint2*)(pb1 + 16);
    }
    #pragma unroll
    for (int mg=0; mg<4; mg++)
      #pragma unroll
      for (int ng=0; ng<4; ng++){
        acc[mg][ng] = __builtin_amdgcn_mfma_f32_16x16x32_bf16(af[0][mg].v, bf[1][ng].v, acc[mg][ng], 0,0,0);
        acc[mg][ng] = __builtin_amdgcn_mfma_f32_16x16x32_bf16(af[1][mg].v, bf[0][ng].v, acc[mg][ng], 0,0,0);
        acc[mg][ng] = __builtin_amdgcn_mfma_f32_16x16x32_bf16(af[0][mg].v, bf[0][ng].v, acc[mg][ng], 0,0,0);
      }
    __syncthreads();
  }
  // C/D layout: col = lane&15, row = (lane>>4)*4 + reg   [m89/m91 verified]
  #pragma unroll
  for (int mg=0; mg<4; mg++)
    #pragma unroll
    for (int ng=0; ng<4; ng++){
      int col = n0 + wn*64 + ng*16 + (lane & 15);
      #pragma unroll
      for (int r=0;r<4;r++){
        int rowv = m0 + wm*64 + mg*16 + (lane>>4)*4 + r;
        D[(long)rowv*N + col] = acc[mg][ng][r];
      }
    }
}

// ---------------- fp32 fallback GEMM (ws too small) ----------------
#define FMA4(ac, s, b) { ac.x=fmaf(s,b.x,ac.x); ac.y=fmaf(s,b.y,ac.y); ac.z=fmaf(s,b.z,ac.z); ac.w=fmaf(s,b.w,ac.w); }

__global__ __launch_bounds__(256) void gemm128(const float* __restrict__ A, const float* __restrict__ Bv, float* __restrict__ D){
  const int M=9216, N=2304, K=320;
  int n0 = blockIdx.x*128, m0 = blockIdx.y*128;
  const float* Ab = A + m0;
  const float* Bb = Bv + n0;
  __shared__ float As[8][128], Bs[8][128];
  int tid = threadIdx.x;
  int tn = tid & 15, tm = tid >> 4;
  float4 acc[8][2];
  #pragma unroll
  for (int i=0;i<8;i++){
    acc[i][0] = make_float4(0.f,0.f,0.f,0.f);
    acc[i][1] = make_float4(0.f,0.f,0.f,0.f);
  }
  int la = tid*4; int lk = la >> 7; int lm = la & 127;
  for (int k0=0;k0<K;k0+=8){
    *(float4*)&As[lk][lm] = *(const float4*)&Ab[(long)(k0+lk)*M + lm];
    *(float4*)&Bs[lk][lm] = *(const float4*)&Bb[(long)(k0+lk)*N + lm];
    __syncthreads();
    #pragma unroll
    for (int kk=0;kk<8;kk++){
      float4 A0 = *(float4*)&As[kk][tm*4];
      float4 A1 = *(float4*)&As[kk][64+tm*4];
      float4 B0 = *(float4*)&Bs[kk][tn*4];
      float4 B1 = *(float4*)&Bs[kk][64+tn*4];
      FMA4(acc[0][0], A0.x, B0); FMA4(acc[0][1], A0.x, B1);
      FMA4(acc[1][0], A0.y, B0); FMA4(acc[1][1], A0.y, B1);
      FMA4(acc[2][0], A0.z, B0); FMA4(acc[2][1], A0.z, B1);
      FMA4(acc[3][0], A0.w, B0); FMA4(acc[3][1], A0.w, B1);
      FMA4(acc[4][0], A1.x, B0); FMA4(acc[4][1], A1.x, B1);
      FMA4(acc[5][0], A1.y, B0); FMA4(acc[5][1], A1.y, B1);
      FMA4(acc[6][0], A1.z, B0); FMA4(acc[6][1], A1.z, B1);
      FMA4(acc[7][0], A1.w, B0); FMA4(acc[7][1], A1.w, B1);
    }
    __syncthreads();
  }
  float* Db = D + (long)m0*N + n0;
  #pragma unroll
  for (int i=0;i<8;i++){
    int mr = (i<4) ? (tm*4+i) : (64+tm*4+(i-4));
    *(float4*)&Db[(long)mr*N + tn*4] = acc[i][0];
    *(float4*)&Db[(long)mr*N + 64 + tn*4] = acc[i][1];
  }
}

// ---------------- row softmax stats (axis=-1, coef_tmp) ----------------
__global__ __launch_bounds__(256) void row_stats(const float* __restrict__ D, const float* __restrict__ coeft,
                                                 float* __restrict__ rmax, float* __restrict__ rsum){
  int m = blockIdx.x;
  const float* drow = D + (long)m*2304;
  float ct = *coeft;
  float v[9];
  float mx = -INFINITY;
  #pragma unroll
  for (int i=0;i<9;i++){ v[i] = ct * drow[threadIdx.x + i*256]; mx = fmaxf(mx, v[i]); }
  __shared__ float sm[4];
  for (int o=32;o;o>>=1) mx = fmaxf(mx, __shfl_down(mx,o));
  int lane = threadIdx.x & 63, wv = threadIdx.x>>6;
  if (lane==0) sm[wv]=mx;
  __syncthreads();
  mx = fmaxf(fmaxf(sm[0],sm[1]),fmaxf(sm[2],sm[3]));
  __syncthreads();
  float s=0.f;
  #pragma unroll
  for (int i=0;i<9;i++) s += expf(v[i]-mx);
  for (int o=32;o;o>>=1) s += __shfl_down(s,o);
  if (lane==0) sm[wv]=s;
  __syncthreads();
  if (threadIdx.x==0){ rmax[m]=mx; rsum[m]=sm[0]+sm[1]+sm[2]+sm[3]; }
}

// ---------------- column softmax stats (axis=-2, coef_ref) ----------------
__device__ __forceinline__ void merge_ms(float& m, float& s, float m2, float s2){
  float M = fmaxf(m, m2);
  s = s*expf(m - M) + s2*expf(m2 - M);
  m = M;
}

__global__ __launch_bounds__(256) void colstat_part(const float* __restrict__ D, const float* __restrict__ coefr,
                                                    float* __restrict__ pm, float* __restrict__ ps){
  int tx = threadIdx.x & 63, ty = threadIdx.x >> 6;
  int n = blockIdx.x*64 + tx;
  float cr = *coefr;
  float m = -INFINITY, s = 0.f;
  int r0 = blockIdx.y * 576;
  for (int r = r0 + ty; r < r0 + 576; r += 4){
    float v = cr * D[(long)r*2304 + n];
    if (v > m){ s = s*expf(m - v) + 1.f; m = v; }
    else s += expf(v - m);
  }
  __shared__ float smm[4][64], sms[4][64];
  smm[ty][tx]=m; sms[ty][tx]=s;
  __syncthreads();
  if (ty==0){
    #pragma unroll
    for (int k=1;k<4;k++) merge_ms(m, s, smm[k][tx], sms[k][tx]);
    pm[(long)blockIdx.y*2304 + n] = m;
    ps[(long)blockIdx.y*2304 + n] = s;
  }
}

__global__ void colstat_merge(const float* __restrict__ pm, const float* __restrict__ ps,
                              float* __restrict__ cm, float* __restrict__ cs){
  int idx = blockIdx.x*256 + threadIdx.x;
  if (idx >= 2304) return;
  float m=-INFINITY, s=0.f;
  for (int k=0;k<16;k++){
    merge_ms(m, s, pm[(long)k*2304+idx], ps[(long)k*2304+idx]);
  }
  cm[idx]=m; cs[idx]=s;
}

// ---------------- confidence + top-10 mean ----------------
__global__ __launch_bounds__(256) void conf_topk(const float* __restrict__ D,
    const float* __restrict__ coefr, const float* __restrict__ coeft,
    const float* __restrict__ rmax, const float* __restrict__ rsum,
    const float* __restrict__ cmax, const float* __restrict__ csum,
    float* __restrict__ outp){
  int m = blockIdx.x;
  const float* drow = D + (long)m*2304;
  float cr = *coefr, ct = *coeft;
  float rm = rmax[m], rs = rsum[m];
  float vals[9];
  #pragma unroll
  for (int i=0;i<9;i++){
    int n = threadIdx.x + i*256;
    float d = drow[n];
    float e = expf(0.5f*((cr+ct)*d - cmax[n] - rm));
    vals[i] = e / sqrtf(csum[n]*rs);
  }
  __shared__ float smv[4]; __shared__ int smi[4];
  float total = 0.f;
  for (int t=0;t<10;t++){
    float lv = -1.f; int li = 0;
    #pragma unroll
    for (int i=0;i<9;i++) if (vals[i] > lv){ lv = vals[i]; li = i; }
    float v = lv; int idx = li*256 + threadIdx.x;
    for (int o=32;o;o>>=1){
      float v2 = __shfl_down(v,o); int i2 = __shfl_down(idx,o);
      if (v2 > v || (v2 == v && i2 < idx)){ v=v2; idx=i2; }
    }
    int lane = threadIdx.x&63, wv = threadIdx.x>>6;
    if (lane==0){ smv[wv]=v; smi[wv]=idx; }
    __syncthreads();
    float bv = smv[0]; int bi = smi[0];
    #pragma unroll
    for (int k=1;k<4;k++){ float v2=smv[k]; int i2=smi[k]; if (v2>bv || (v2==bv && i2<bi)){bv=v2;bi=i2;} }
    total += bv;
    if ((bi & 255) == threadIdx.x) vals[bi>>8] = -2.f;
    __syncthreads();
  }
  if (threadIdx.x==0) outp[m] = total*0.1f;
}

// ---------------- host ----------------
extern "C" void kernel_launch(void* const* d_in, const int* in_sizes, int n_in,
                              void* d_out, int out_size, void* d_ws, size_t ws_size,
                              hipStream_t stream) {
  const float *W[8], *Bp[8], *xr, *xt, *cr, *ct;
  if (in_sizes[0] == 1728){
    for (int i=0;i<8;i++){ W[i]=(const float*)d_in[2*i]; Bp[i]=(const float*)d_in[2*i+1]; }
    xr=(const float*)d_in[16]; xt=(const float*)d_in[17];
    cr=(const float*)d_in[18]; ct=(const float*)d_in[19];
  } else {
    xr=(const float*)d_in[0]; xt=(const float*)d_in[1];
    cr=(const float*)d_in[2]; ct=(const float*)d_in[3];
    for (int i=0;i<8;i++){ W[i]=(const float*)d_in[4+2*i]; Bp[i]=(const float*)d_in[5+2*i]; }
  }

  float* ws = (float*)d_ws;
  long off = 0;
  auto alloc = [&](long nfl){ float* p = ws + off; off += (nfl + 63) & ~63L; return p; };
  float* featR = alloc(2L*320*9216);
  float* featT = alloc(2L*320*2304);
  float* meanb = alloc(640);
  float* rmax  = alloc(2L*9216);
  float* rsum  = alloc(2L*9216);
  float* pm    = alloc(16L*2304);
  float* ps    = alloc(16L*2304);
  float* cm    = alloc(2304);
  float* cs    = alloc(2304);
  float* scratch = alloc(9216L*2304);
  long offBase = off;
  if ((size_t)(offBase*4) > ws_size) return;

  // split-bf16 buffers (fp16-range-safe bf16 hi/lo, transposed to [P][320])
  unsigned short* AhR = (unsigned short*)alloc((2L*9216*320 + 1)/2);
  unsigned short* AlR = (unsigned short*)alloc((2L*9216*320 + 1)/2);
  unsigned short* BhT = (unsigned short*)alloc((2L*2304*320 + 1)/2);
  unsigned short* BlT = (unsigned short*)alloc((2L*2304*320 + 1)/2);
  bool useMfma = ((size_t)(off*4) <= ws_size);

  float* tA = scratch;                   // [2,64,96,96]
  float* tB = tA + 2L*64*9216;           // [2,64,48,48]
  float* tC = tB + 2L*64*2304;           // [2,128,48,48]
  float* tD = tC + 2L*128*2304;          // [2,128,48,48]
  float* tE = tD + 2L*128*2304;          // [2,128,24,24]
  float* tF = tE + 2L*128*576;           // [2,256,24,24]
  float* tG = tF + 2L*256*576;           // [2,256,24,24]
  float* tP = tG + 2L*256*576;           // CI-split partials
  float* dist = scratch;

  auto convl = [&](const float* in, int i, float* outF, long outBSf,
                   int CI, int CO, int H, int Wd, long inBS, int cob, int S){
    int tiles = ((Wd+15)/16)*((H+15)/16);
    int nci = CI/S;
    dim3 g(tiles, CO/cob, 2*S);
    float* outArg; long sStr, oBS; const float* biasArg;
    if (S==1){ outArg=outF; sStr=0; oBS=outBSf; biasArg=Bp[i]; }
    else { outArg=tP; sStr=2L*CO*H*Wd; oBS=(long)CO*H*Wd; biasArg=nullptr; }
    if (CI == 3)
      conv3x3_v4<8,3><<<g,256,0,stream>>>(in, W[i], biasArg, outArg, CI, nci, S, H, Wd, inBS, oBS, sStr);
    else if (cob == 8)
      conv3x3_v4<8,8><<<g,256,0,stream>>>(in, W[i], biasArg, outArg, CI, nci, S, H, Wd, inBS, oBS, sStr);
    else
      conv3x3_v4<4,8><<<g,256,0,stream>>>(in, W[i], biasArg, outArg, CI, nci, S, H, Wd, inBS, oBS, sStr);
    if (S > 1){
      long tot = 2L*CO*H*Wd;
      reduce_bias_relu<<<dim3((unsigned)((tot+255)/256)),256,0,stream>>>(
          tP, Bp[i], outF, S, sStr, CO, H*Wd, outBSf);
    }
  };
  auto pooll = [&](const float* in, float* out, long NC, int Hi, int Wi){
    long total = NC*(Hi/2)*(Wi/2);
    maxpool2<<<dim3((unsigned)((total+255)/256)), 256, 0, stream>>>(in, out, NC, Hi, Wi);
  };

  // ---- reference path (96x96) ----
  convl(xr,    0, featR, 320L*9216, 3,   64, 96, 96, 3L*9216,   8, 1);
  convl(featR, 1, tA,    64L*9216,  64,  64, 96, 96, 320L*9216, 8, 2);
  pooll(tA, tB, 2L*64, 96, 96);
  convl(tB, 2, tC, 128L*2304, 64,  128, 48, 48, 64L*2304,  8, 2);
  convl(tC, 3, tD, 128L*2304, 128, 128, 48, 48, 128L*2304, 8, 2);
  pooll(tD, tE, 2L*128, 48, 48);
  convl(tE, 4, tF, 256L*576, 128, 256, 24, 24, 128L*576, 8, 2);
  convl(tF, 5, tG, 256L*576, 256, 256, 24, 24, 256L*576, 8, 4);
  convl(tG, 6, tF, 256L*576, 256, 256, 24, 24, 256L*576, 8, 4);
  convl(tF, 7, tG, 256L*576, 256, 256, 24, 24, 256L*576, 8, 4);
  bicubic_up<<<dim3(256,2), 256, 0, stream>>>(tG, featR + 64L*9216, 24,24,96,96, 256L*576, 320L*9216);

  // ---- template path (48x48) ----
  convl(xt,    0, featT, 320L*2304, 3,   64, 48, 48, 3L*2304,   8, 1);
  convl(featT, 1, tA,    64L*2304,  64,  64, 48, 48, 320L*2304, 4, 2);
  pooll(tA, tB, 2L*64, 48, 48);
  convl(tB, 2, tC, 128L*576, 64,  128, 24, 24, 64L*576,  4, 2);
  convl(tC, 3, tD, 128L*576, 128, 128, 24, 24, 128L*576, 4, 2);
  pooll(tD, tE, 2L*128, 24, 24);
  convl(tE, 4, tF, 256L*144, 128, 256, 12, 12, 128L*144, 4, 4);
  convl(tF, 5, tG, 256L*144, 256, 256, 12, 12, 256L*144, 4, 4);
  convl(tG, 6, tF, 256L*144, 256, 256, 12, 12, 256L*144, 4, 4);
  convl(tF, 7, tG, 256L*144, 256, 256, 12, 12, 256L*144, 4, 4);
  bicubic_up<<<dim3(256,2), 256, 0, stream>>>(tG, featT + 64L*2304, 12,12,48,48, 256L*144, 320L*2304);

  // ---- normalizer (std = mean bug preserved) ----
  mean_k<<<640, 256, 0, stream>>>(featR, featT, meanb);
  norm_apply<<<dim3((unsigned)((5898240L+255)/256)), 256, 0, stream>>>(featR, meanb, 9216L, 2L*320*9216);
  norm_apply<<<dim3((unsigned)((1474560L+255)/256)), 256, 0, stream>>>(featT, meanb, 2304L, 2L*320*2304);

  if (useMfma){
    split_bf16<<<dim3(288,2), 256, 0, stream>>>(featR, AhR, AlR, 9216);
    split_bf16<<<dim3(72,2),  256, 0, stream>>>(featT, BhT, BlT, 2304);
  }

  // ---- per-batch: dist GEMM, softmax stats, conf + top-10 ----
  for (int b=0; b<2; b++){
    if (useMfma){
      gemm_mfma<<<dim3(18,72), 256, 0, stream>>>(
          AhR + (long)b*9216*320, AlR + (long)b*9216*320,
          BhT + (long)b*2304*320, BlT + (long)b*2304*320, dist);
    } else {
      gemm128<<<dim3(18,72), 256, 0, stream>>>(
          featR + (long)b*320*9216, featT + (long)b*320*2304, dist);
    }
    row_stats<<<dim3(9216), 256, 0, stream>>>(dist, ct, rmax + (long)b*9216, rsum + (long)b*9216);
    colstat_part<<<dim3(36,16), 256, 0, stream>>>(dist, cr, pm, ps);
    colstat_merge<<<dim3(9), 256, 0, stream>>>(pm, ps, cm, cs);
    conf_topk<<<dim3(9216), 256, 0, stream>>>(dist, cr, ct,
        rmax + (long)b*9216, rsum + (long)b*9216, cm, cs, (float*)d_out + (long)b*9216);
  }
}

// Round 6
// 857.281 us; speedup vs baseline: 4.0788x; 1.7786x over previous
//
#include <hip/hip_runtime.h>
#include <math.h>

#define CK_A (-0.75f)

typedef __attribute__((ext_vector_type(8))) short bf16x8;
typedef __attribute__((ext_vector_type(4))) float f32x4;

__device__ __forceinline__ float cubicw(float t){
  float at = fabsf(t);
  float at2 = at*at, at3 = at2*at;
  if (at <= 1.f) return (CK_A+2.f)*at3 - (CK_A+3.f)*at2 + 1.f;
  if (at < 2.f)  return CK_A*at3 - 5.f*CK_A*at2 + 8.f*CK_A*at - 4.f*CK_A;
  return 0.f;
}

__device__ __forceinline__ unsigned short f2bf_rne(float f){
  unsigned int u = __float_as_uint(f);
  unsigned int r = (u + 0x7fffu + ((u>>16)&1u)) >> 16;
  return (unsigned short)r;
}
__device__ __forceinline__ float bf2f(unsigned short h){
  return __uint_as_float(((unsigned int)h)<<16);
}

// ---------------- direct conv (layer 0 only, CI=3) ----------------
template<int COB, int CICH>
__global__ __launch_bounds__(256) void conv3x3_v4(
    const float* __restrict__ in, const float* __restrict__ w, const float* __restrict__ bias,
    float* __restrict__ out, int CI, int nci, int S, int H, int W,
    long inBS, long outBS, long sStride)
{
  int tilesX = (W + 15) >> 4;
  int tx0 = (blockIdx.x % tilesX) << 4;
  int ty0 = (blockIdx.x / tilesX) << 4;
  int cob = blockIdx.y * COB;
  int s = blockIdx.z % S, b = blockIdx.z / S;
  int ci0 = s * nci;
  int lx = threadIdx.x & 15, ly = threadIdx.x >> 4;
  __shared__ float tile[CICH][18][20];
  float acc[COB];
  #pragma unroll
  for (int j=0;j<COB;j++) acc[j]=0.f;
  const float* inb = in + (long)b*inBS;
  int ox = tx0+lx, oy = ty0+ly;

  for (int c0=ci0; c0<ci0+nci; c0+=CICH){
    for (int idx = threadIdx.x; idx < CICH*324; idx += 256){
      int cl = idx/324, rem = idx - cl*324;
      int r = rem/18, c = rem - r*18;
      int gy = ty0 + r - 1, gx = tx0 + c - 1;
      const float* ic = inb + (long)(c0+cl)*H*W;
      tile[cl][r][c] = (gy>=0 && gy<H && gx>=0 && gx<W) ? ic[(long)gy*W+gx] : 0.f;
    }
    __syncthreads();
    #pragma unroll
    for (int cl=0; cl<CICH; cl++){
      float t00=tile[cl][ly+0][lx+0], t01=tile[cl][ly+0][lx+1], t02=tile[cl][ly+0][lx+2];
      float t10=tile[cl][ly+1][lx+0], t11=tile[cl][ly+1][lx+1], t12=tile[cl][ly+1][lx+2];
      float t20=tile[cl][ly+2][lx+0], t21=tile[cl][ly+2][lx+1], t22=tile[cl][ly+2][lx+2];
      #pragma unroll
      for (int j=0;j<COB;j++){
        const float* wp = w + ((long)(cob+j)*CI + (c0+cl))*9;
        float a = acc[j];
        a = fmaf(t00, wp[0], a); a = fmaf(t01, wp[1], a); a = fmaf(t02, wp[2], a);
        a = fmaf(t10, wp[3], a); a = fmaf(t11, wp[4], a); a = fmaf(t12, wp[5], a);
        a = fmaf(t20, wp[6], a); a = fmaf(t21, wp[7], a); a = fmaf(t22, wp[8], a);
        acc[j] = a;
      }
    }
    __syncthreads();
  }
  if (ox < W && oy < H){
    float* outp = out + (long)s*sStride + (long)b*outBS;
    #pragma unroll
    for (int j=0;j<COB;j++){
      float v = acc[j];
      if (bias) v = fmaxf(v + bias[cob+j], 0.f);
      outp[(long)(cob+j)*H*W + (long)oy*W + ox] = v;
    }
  }
}

// ---------------- weight pre-pack for MFMA conv ----------------
// Layout: [o][kc][g][h][lane][j]  (1KB hi + 1KB lo per (o,kc,g))
// co = g*16 + (lane&15); ci = kc*32 + (lane>>4)*8 + j; o = dy*3+dx.
__global__ void prep_w(const float* __restrict__ w, unsigned short* __restrict__ wp,
                       int CI, int CO, long total){
  long e = (long)blockIdx.x*256 + threadIdx.x;
  if (e >= total) return;
  int j = (int)(e & 7);
  int lane = (int)((e>>3) & 63);
  int h = (int)((e>>9) & 1);
  long rem = e >> 10;
  int G = CO >> 4, KC = CI >> 5;
  int g = (int)(rem % G); long q = rem / G;
  int kc = (int)(q % KC); int o = (int)(q / KC);
  int co = (g<<4) + (lane & 15);
  int ci = (kc<<5) + ((lane>>4)<<3) + j;
  float v = w[((long)co*CI + ci)*9 + o];
  unsigned short hi = f2bf_rne(v);
  if (h == 0) wp[e] = hi;
  else wp[e] = f2bf_rne(v - bf2f(hi));
}

// ---------------- implicit-GEMM MFMA conv (split-bf16, 3 products) -------
// Block: 64 CO x 64 px (8x8 tile). 4 waves (2co x 2px), each 32co x 32px
// = 2x2 frags of 16x16x32. Input halo tile (32ci x 10x10) staged hi/lo in
// LDS per ci-chunk, reused by all 9 taps. Weights read as pre-packed frags.
union AB { bf16x8 v; uint4 u; };
#define MFB(a,b,c) __builtin_amdgcn_mfma_f32_16x16x32_bf16(a,b,c,0,0,0)

__global__ __launch_bounds__(256) void conv_mfma(
    const float* __restrict__ in, const unsigned short* __restrict__ Wp,
    const float* __restrict__ bias, float* __restrict__ out,
    int CI, int CO, int nci, int S, int H, int W,
    long inBS, long outBS, long sStride)
{
  int HW = H*W;
  int tilesX = (W+7)>>3;
  int tx0 = (blockIdx.x % tilesX)<<3, ty0 = (blockIdx.x / tilesX)<<3;
  int cobase = blockIdx.y << 6;
  int s = blockIdx.z % S, b = blockIdx.z / S;
  int tid = threadIdx.x, lane = tid & 63, wid = tid>>6;
  int wm = wid>>1, wn = wid&1;
  int KC = CI>>5, G = CO>>4;
  __shared__ __align__(16) unsigned short Bth[4000];
  __shared__ __align__(16) unsigned short Btl[4000];
  const float* inb = in + (long)b*inBS;

  // staging precompute: e = tid + i*256 over 3200 = 32ci x 100px (px fast)
  int sofs[13]; int sla[13];
  #pragma unroll
  for (int i=0;i<13;i++){
    int e = tid + i*256;
    int cidx = e / 100, pix = e - cidx*100;
    int hy = pix/10, hx = pix - hy*10;
    int gy = ty0 - 1 + hy, gx = tx0 - 1 + hx;
    bool v = (gy>=0) && (gy<H) && (gx>=0) && (gx<W);
    sofs[i] = v ? (cidx*HW + gy*W + gx) : -1;
    sla[i] = pix*40 + cidx;
  }

  int n15 = lane & 15;
  int klane8 = (lane>>4)<<3;
  int p0 = wn*32 + n15;
  int base0 = ((p0>>3)*10 + (p0&7))*40 + klane8;
  int p1 = p0 + 16;
  int base1 = ((p1>>3)*10 + (p1&7))*40 + klane8;
  int g0 = (cobase>>4) + wm*2;

  f32x4 acc[2][2];
  #pragma unroll
  for (int i=0;i<2;i++)
    #pragma unroll
    for (int j=0;j<2;j++) acc[i][j] = (f32x4){0.f,0.f,0.f,0.f};

  int nkc = nci >> 5;
  for (int kk=0; kk<nkc; kk++){
    int ci0 = s*nci + (kk<<5);
    __syncthreads();
    #pragma unroll
    for (int i=0;i<12;i++){
      float v = (sofs[i] >= 0) ? inb[(long)ci0*HW + sofs[i]] : 0.f;
      unsigned short h = f2bf_rne(v);
      Bth[sla[i]] = h;
      Btl[sla[i]] = f2bf_rne(v - bf2f(h));
    }
    if (tid < 128){
      float v = (sofs[12] >= 0) ? inb[(long)ci0*HW + sofs[12]] : 0.f;
      unsigned short h = f2bf_rne(v);
      Bth[sla[12]] = h;
      Btl[sla[12]] = f2bf_rne(v - bf2f(h));
    }
    __syncthreads();
    int kc = ci0 >> 5;
    const unsigned short* wpb = Wp + (long)kc*G*1024 + (long)lane*8;
    #pragma unroll
    for (int o=0;o<9;o++){
      const int dy = o/3, dx = o - dy*3;
      const int sh = (dy*10+dx)*40;
      const unsigned short* wo = wpb + (long)o*KC*G*1024;
      AB a0h,a0l,a1h,a1l, b0h,b0l,b1h,b1l;
      a0h.u = *(const uint4*)(wo + (long)g0*1024);
      a0l.u = *(const uint4*)(wo + (long)g0*1024 + 512);
      a1h.u = *(const uint4*)(wo + (long)(g0+1)*1024);
      a1l.u = *(const uint4*)(wo + (long)(g0+1)*1024 + 512);
      b0h.v = *(const bf16x8*)&Bth[base0 + sh];
      b0l.v = *(const bf16x8*)&Btl[base0 + sh];
      b1h.v = *(const bf16x8*)&Bth[base1 + sh];
      b1l.v = *(const bf16x8*)&Btl[base1 + sh];
      acc[0][0] = MFB(a0h.v, b0l.v, acc[0][0]);
      acc[0][0] = MFB(a0l.v, b0h.v, acc[0][0]);
      acc[0][0] = MFB(a0h.v, b0h.v, acc[0][0]);
      acc[0][1] = MFB(a0h.v, b1l.v, acc[0][1]);
      acc[0][1] = MFB(a0l.v, b1h.v, acc[0][1]);
      acc[0][1] = MFB(a0h.v, b1h.v, acc[0][1]);
      acc[1][0] = MFB(a1h.v, b0l.v, acc[1][0]);
      acc[1][0] = MFB(a1l.v, b0h.v, acc[1][0]);
      acc[1][0] = MFB(a1h.v, b0h.v, acc[1][0]);
      acc[1][1] = MFB(a1h.v, b1l.v, acc[1][1]);
      acc[1][1] = MFB(a1l.v, b1h.v, acc[1][1]);
      acc[1][1] = MFB(a1h.v, b1h.v, acc[1][1]);
    }
  }

  // epilogue: D col = lane&15 (px), row = (lane>>4)*4 + r (co)
  float* outp = out + (long)s*sStride + (long)b*outBS;
  #pragma unroll
  for (int ng=0; ng<2; ng++){
    int p = wn*32 + ng*16 + n15;
    int gy = ty0 + (p>>3), gx = tx0 + (p&7);
    bool ok = (gy<H) && (gx<W);
    #pragma unroll
    for (int mg=0; mg<2; mg++){
      #pragma unroll
      for (int r=0;r<4;r++){
        if (ok){
          int co = cobase + wm*32 + mg*16 + ((lane>>4)<<2) + r;
          float v = acc[mg][ng][r];
          if (bias) v = fmaxf(v + bias[co], 0.f);
          outp[(long)co*HW + (long)gy*W + gx] = v;
        }
      }
    }
  }
}

// ---------------- partial reduce + bias + relu ----------------
__global__ void reduce_bias_relu(const float* __restrict__ part, const float* __restrict__ bias,
                                 float* __restrict__ out, int S, long sStride,
                                 int CO, int HW, long outBS){
  long tot = 2L*CO*HW;
  long e = (long)blockIdx.x*256 + threadIdx.x;
  if (e >= tot) return;
  long b = e / ((long)CO*HW);
  long r = e - b*(long)CO*HW;
  float v = 0.f;
  for (int s=0;s<S;s++) v += part[(long)s*sStride + e];
  int co = (int)(r / HW);
  out[b*outBS + r] = fmaxf(v + bias[co], 0.f);
}

// ---------------- maxpool 2x2 stride 2 ----------------
__global__ void maxpool2(const float* __restrict__ in, float* __restrict__ out, long NC, int Hi, int Wi){
  int Ho = Hi>>1, Wo = Wi>>1;
  long total = NC * Ho * Wo;
  long idx = (long)blockIdx.x*256 + threadIdx.x;
  if (idx >= total) return;
  int x = (int)(idx % Wo); long t = idx / Wo; int y = (int)(t % Ho); long nc = t / Ho;
  const float* p = in + (nc*Hi + 2*y)*(long)Wi + 2*x;
  float v = fmaxf(fmaxf(p[0], p[1]), fmaxf(p[Wi], p[Wi+1]));
  out[idx] = v;
}

// ---------------- bicubic upsample (align_corners=True) ----------------
__global__ __launch_bounds__(256) void bicubic_up(
    const float* __restrict__ in, float* __restrict__ out,
    int Hin, int Win, int Hout, int Wout, long inBStride, long outBStride)
{
  int c = blockIdx.x, b = blockIdx.y;
  __shared__ float s[576];
  const float* ip = in + (long)b*inBStride + (long)c*Hin*Win;
  float* op = out + (long)b*outBStride + (long)c*Hout*Wout;
  int n = Hin*Win;
  for (int i = threadIdx.x; i < n; i += 256) s[i] = ip[i];
  __syncthreads();
  float scy = (float)((double)(Hin-1)/(double)(Hout-1));
  float scx = (float)((double)(Win-1)/(double)(Wout-1));
  int total = Hout*Wout;
  for (int idx = threadIdx.x; idx < total; idx += 256){
    int ox = idx % Wout, oy = idx / Wout;
    float py = oy * scy, px = ox * scx;
    float iy0f = floorf(py), ix0f = floorf(px);
    int iy0 = (int)iy0f, ix0 = (int)ix0f;
    float fy = py - iy0f, fx = px - ix0f;
    float wy[4], wx[4]; int xs[4], ys[4];
    #pragma unroll
    for (int t=0;t<4;t++){
      wy[t] = cubicw(fy - (float)(t-1));
      wx[t] = cubicw(fx - (float)(t-1));
      ys[t] = min(max(iy0 + t - 1, 0), Hin-1);
      xs[t] = min(max(ix0 + t - 1, 0), Win-1);
    }
    float acc = 0.f;
    #pragma unroll
    for (int i=0;i<4;i++){
      const float* row = &s[ys[i]*Win];
      float rs = wx[0]*row[xs[0]] + wx[1]*row[xs[1]] + wx[2]*row[xs[2]] + wx[3]*row[xs[3]];
      acc = fmaf(wy[i], rs, acc);
    }
    op[idx] = acc;
  }
}

// ---------------- normalizer ----------------
__global__ __launch_bounds__(256) void mean_k(const float* __restrict__ fR, const float* __restrict__ fT, float* __restrict__ mean){
  int c = blockIdx.x % 320, b = blockIdx.x / 320;
  const float* a = fR + ((long)b*320+c)*9216L;
  const float* t = fT + ((long)b*320+c)*2304L;
  float s = 0.f;
  for (int i=threadIdx.x;i<9216;i+=256) s += a[i];
  for (int i=threadIdx.x;i<2304;i+=256) s += t[i];
  __shared__ float sm[4];
  for (int o=32;o;o>>=1) s += __shfl_down(s,o);
  int lane = threadIdx.x & 63, wv = threadIdx.x >> 6;
  if (lane==0) sm[wv] = s;
  __syncthreads();
  if (threadIdx.x==0) mean[b*320+c] = (sm[0]+sm[1]+sm[2]+sm[3]) * (1.f/11520.f);
}

__global__ void norm_apply(float* __restrict__ f, const float* __restrict__ mean, long perChan, long total){
  long idx = (long)blockIdx.x*256 + threadIdx.x;
  if (idx >= total) return;
  long c = (idx / perChan) % 320;
  long b = idx / (perChan*320);
  float m = mean[b*320+c];
  f[idx] = (f[idx] - m) / (m + 1e-8f);
}

// ---------------- split+transpose for dist GEMM ----------------
__global__ __launch_bounds__(256) void split_bf16(const float* __restrict__ feat,
    unsigned short* __restrict__ oh, unsigned short* __restrict__ ol, int P){
  int b = blockIdx.y; int m0 = blockIdx.x*32;
  __shared__ unsigned int t[32][321];
  int ml = threadIdx.x & 31, kq = threadIdx.x >> 5;
  const float* fp = feat + (long)b*320*P + m0 + ml;
  for (int k = kq*40; k < kq*40+40; k++){
    float v = fp[(long)k*P];
    unsigned short h = f2bf_rne(v);
    unsigned short l = f2bf_rne(v - bf2f(h));
    t[ml][k] = ((unsigned int)h<<16) | l;
  }
  __syncthreads();
  long base = ((long)b*P + m0)*320;
  for (int idx = threadIdx.x; idx < 32*320; idx += 256){
    int m = idx/320, k = idx - m*320;
    unsigned int p = t[m][k];
    oh[base + (long)m*320 + k] = (unsigned short)(p>>16);
    ol[base + (long)m*320 + k] = (unsigned short)(p & 0xffffu);
  }
}

// ---------------- split-bf16 MFMA dist GEMM ----------------
union FragU { bf16x8 v; uint2 u[2]; };

__global__ __launch_bounds__(256) void gemm_mfma(
    const unsigned short* __restrict__ Ah, const unsigned short* __restrict__ Al,
    const unsigned short* __restrict__ Bh, const unsigned short* __restrict__ Bl,
    float* __restrict__ D){
  const int N = 2304, K = 320;
  int n0 = blockIdx.x*128, m0 = blockIdx.y*128;
  __shared__ unsigned short As[2][128][36], Bs[2][128][36];
  int tid = threadIdx.x, lane = tid & 63, wid = tid >> 6;
  int wm = wid >> 1, wn = wid & 1;
  f32x4 acc[4][4];
  #pragma unroll
  for (int i=0;i<4;i++)
    #pragma unroll
    for (int j=0;j<4;j++) acc[i][j] = (f32x4){0.f,0.f,0.f,0.f};

  for (int k0=0; k0<K; k0+=32){
    #pragma unroll
    for (int q=0;q<2;q++){
      int flat = q*256 + tid;
      int row = flat >> 2, seg = flat & 3;
      long ga = (long)(m0+row)*K + k0 + seg*8;
      long gb = (long)(n0+row)*K + k0 + seg*8;
      uint4 va = *(const uint4*)(Ah + ga);
      *(uint2*)&As[0][row][seg*8]   = make_uint2(va.x, va.y);
      *(uint2*)&As[0][row][seg*8+4] = make_uint2(va.z, va.w);
      uint4 vb = *(const uint4*)(Al + ga);
      *(uint2*)&As[1][row][seg*8]   = make_uint2(vb.x, vb.y);
      *(uint2*)&As[1][row][seg*8+4] = make_uint2(vb.z, vb.w);
      uint4 vc = *(const uint4*)(Bh + gb);
      *(uint2*)&Bs[0][row][seg*8]   = make_uint2(vc.x, vc.y);
      *(uint2*)&Bs[0][row][seg*8+4] = make_uint2(vc.z, vc.w);
      uint4 vd = *(const uint4*)(Bl + gb);
      *(uint2*)&Bs[1][row][seg*8]   = make_uint2(vd.x, vd.y);
      *(uint2*)&Bs[1][row][seg*8+4] = make_uint2(vd.z, vd.w);
    }
    __syncthreads();

    FragU af[2][4], bf[2][4];
    #pragma unroll
    for (int g=0; g<4; g++){
      const unsigned short* pa0 = &As[0][wm*64 + g*16 + (lane&15)][(lane>>4)*4];
      const unsigned short* pa1 = &As[1][wm*64 + g*16 + (lane&15)][(lane>>4)*4];
      const unsigned short* pb0 = &Bs[0][wn*64 + g*16 + (lane&15)][(lane>>4)*4];
      const unsigned short* pb1 = &Bs[1][wn*64 + g*16 + (lane&15)][(lane>>4)*4];
      af[0][g].u[0] = *(const uint2*)pa0; af[0][g].u[1] = *(const uint2*)(pa0 + 16);
      af[1][g].u[0] = *(const uint2*)pa1; af[1][g].u[1] = *(const uint2*)(pa1 + 16);
      bf[0][g].u[0] = *(const uint2*)pb0; bf[0][g].u[1] = *(const uint2*)(pb0 + 16);
      bf[1][g].u[0] = *(const uint2*)pb1; bf[1][g].u[1] = *(const uint2*)(pb1 + 16);
    }
    #pragma unroll
    for (int mg=0; mg<4; mg++)
      #pragma unroll
      for (int ng=0; ng<4; ng++){
        acc[mg][ng] = MFB(af[0][mg].v, bf[1][ng].v, acc[mg][ng]);
        acc[mg][ng] = MFB(af[1][mg].v, bf[0][ng].v, acc[mg][ng]);
        acc[mg][ng] = MFB(af[0][mg].v, bf[0][ng].v, acc[mg][ng]);
      }
    __syncthreads();
  }
  #pragma unroll
  for (int mg=0; mg<4; mg++)
    #pragma unroll
    for (int ng=0; ng<4; ng++){
      int col = n0 + wn*64 + ng*16 + (lane & 15);
      #pragma unroll
      for (int r=0;r<4;r++){
        int rowv = m0 + wm*64 + mg*16 + (lane>>4)*4 + r;
        D[(long)rowv*N + col] = acc[mg][ng][r];
      }
    }
}

// ---------------- row softmax stats ----------------
__global__ __launch_bounds__(256) void row_stats(const float* __restrict__ D, const float* __restrict__ coeft,
                                                 float* __restrict__ rmax, float* __restrict__ rsum){
  int m = blockIdx.x;
  const float* drow = D + (long)m*2304;
  float ct = *coeft;
  float v[9];
  float mx = -INFINITY;
  #pragma unroll
  for (int i=0;i<9;i++){ v[i] = ct * drow[threadIdx.x + i*256]; mx = fmaxf(mx, v[i]); }
  __shared__ float sm[4];
  for (int o=32;o;o>>=1) mx = fmaxf(mx, __shfl_down(mx,o));
  int lane = threadIdx.x & 63, wv = threadIdx.x>>6;
  if (lane==0) sm[wv]=mx;
  __syncthreads();
  mx = fmaxf(fmaxf(sm[0],sm[1]),fmaxf(sm[2],sm[3]));
  __syncthreads();
  float s=0.f;
  #pragma unroll
  for (int i=0;i<9;i++) s += expf(v[i]-mx);
  for (int o=32;o;o>>=1) s += __shfl_down(s,o);
  if (lane==0) sm[wv]=s;
  __syncthreads();
  if (threadIdx.x==0){ rmax[m]=mx; rsum[m]=sm[0]+sm[1]+sm[2]+sm[3]; }
}

// ---------------- column softmax stats ----------------
__device__ __forceinline__ void merge_ms(float& m, float& s, float m2, float s2){
  float M = fmaxf(m, m2);
  s = s*expf(m - M) + s2*expf(m2 - M);
  m = M;
}

__global__ __launch_bounds__(256) void colstat_part(const float* __restrict__ D, const float* __restrict__ coefr,
                                                    float* __restrict__ pm, float* __restrict__ ps){
  int tx = threadIdx.x & 63, ty = threadIdx.x >> 6;
  int n = blockIdx.x*64 + tx;
  float cr = *coefr;
  float m = -INFINITY, s = 0.f;
  int r0 = blockIdx.y * 576;
  for (int r = r0 + ty; r < r0 + 576; r += 4){
    float v = cr * D[(long)r*2304 + n];
    if (v > m){ s = s*expf(m - v) + 1.f; m = v; }
    else s += expf(v - m);
  }
  __shared__ float smm[4][64], sms[4][64];
  smm[ty][tx]=m; sms[ty][tx]=s;
  __syncthreads();
  if (ty==0){
    #pragma unroll
    for (int k=1;k<4;k++) merge_ms(m, s, smm[k][tx], sms[k][tx]);
    pm[(long)blockIdx.y*2304 + n] = m;
    ps[(long)blockIdx.y*2304 + n] = s;
  }
}

__global__ void colstat_merge(const float* __restrict__ pm, const float* __restrict__ ps,
                              float* __restrict__ cm, float* __restrict__ cs){
  int idx = blockIdx.x*256 + threadIdx.x;
  if (idx >= 2304) return;
  float m=-INFINITY, s=0.f;
  for (int k=0;k<16;k++){
    merge_ms(m, s, pm[(long)k*2304+idx], ps[(long)k*2304+idx]);
  }
  cm[idx]=m; cs[idx]=s;
}

// ---------------- confidence + top-10 mean ----------------
__global__ __launch_bounds__(256) void conf_topk(const float* __restrict__ D,
    const float* __restrict__ coefr, const float* __restrict__ coeft,
    const float* __restrict__ rmax, const float* __restrict__ rsum,
    const float* __restrict__ cmax, const float* __restrict__ csum,
    float* __restrict__ outp){
  int m = blockIdx.x;
  const float* drow = D + (long)m*2304;
  float cr = *coefr, ct = *coeft;
  float rm = rmax[m], rs = rsum[m];
  float vals[9];
  #pragma unroll
  for (int i=0;i<9;i++){
    int n = threadIdx.x + i*256;
    float d = drow[n];
    float e = expf(0.5f*((cr+ct)*d - cmax[n] - rm));
    vals[i] = e / sqrtf(csum[n]*rs);
  }
  __shared__ float smv[4]; __shared__ int smi[4];
  float total = 0.f;
  for (int t=0;t<10;t++){
    float lv = -1.f; int li = 0;
    #pragma unroll
    for (int i=0;i<9;i++) if (vals[i] > lv){ lv = vals[i]; li = i; }
    float v = lv; int idx = li*256 + threadIdx.x;
    for (int o=32;o;o>>=1){
      float v2 = __shfl_down(v,o); int i2 = __shfl_down(idx,o);
      if (v2 > v || (v2 == v && i2 < idx)){ v=v2; idx=i2; }
    }
    int lane = threadIdx.x&63, wv = threadIdx.x>>6;
    if (lane==0){ smv[wv]=v; smi[wv]=idx; }
    __syncthreads();
    float bv = smv[0]; int bi = smi[0];
    #pragma unroll
    for (int k=1;k<4;k++){ float v2=smv[k]; int i2=smi[k]; if (v2>bv || (v2==bv && i2<bi)){bv=v2;bi=i2;} }
    total += bv;
    if ((bi & 255) == threadIdx.x) vals[bi>>8] = -2.f;
    __syncthreads();
  }
  if (threadIdx.x==0) outp[m] = total*0.1f;
}

// ---------------- host ----------------
extern "C" void kernel_launch(void* const* d_in, const int* in_sizes, int n_in,
                              void* d_out, int out_size, void* d_ws, size_t ws_size,
                              hipStream_t stream) {
  const float *W[8], *Bp[8], *xr, *xt, *cr, *ct;
  if (in_sizes[0] == 1728){
    for (int i=0;i<8;i++){ W[i]=(const float*)d_in[2*i]; Bp[i]=(const float*)d_in[2*i+1]; }
    xr=(const float*)d_in[16]; xt=(const float*)d_in[17];
    cr=(const float*)d_in[18]; ct=(const float*)d_in[19];
  } else {
    xr=(const float*)d_in[0]; xt=(const float*)d_in[1];
    cr=(const float*)d_in[2]; ct=(const float*)d_in[3];
    for (int i=0;i<8;i++){ W[i]=(const float*)d_in[4+2*i]; Bp[i]=(const float*)d_in[5+2*i]; }
  }

  const int convCI[8] = {3,64,64,128,128,256,256,256};
  const int convCO[8] = {64,64,128,128,256,256,256,256};
  long wpoff[8]; long wtot = 0;
  for (int l=1;l<8;l++){ wpoff[l] = wtot; wtot += 9L*convCI[l]*convCO[l]*2; }

  float* ws = (float*)d_ws;
  long off = 0;
  auto alloc = [&](long nfl){ float* p = ws + off; off += (nfl + 63) & ~63L; return p; };
  float* featR = alloc(2L*320*9216);
  float* featT = alloc(2L*320*2304);
  float* meanb = alloc(640);
  float* rmax  = alloc(2L*9216);
  float* rsum  = alloc(2L*9216);
  float* pm    = alloc(16L*2304);
  float* ps    = alloc(16L*2304);
  float* cm    = alloc(2304);
  float* cs    = alloc(2304);
  unsigned short* wp = (unsigned short*)alloc((wtot+1)/2);
  float* scratch = alloc(9216L*2304);
  if ((size_t)(off*4) > ws_size) return;

  unsigned short* AhR = (unsigned short*)alloc((2L*9216*320 + 1)/2);
  unsigned short* AlR = (unsigned short*)alloc((2L*9216*320 + 1)/2);
  unsigned short* BhT = (unsigned short*)alloc((2L*2304*320 + 1)/2);
  unsigned short* BlT = (unsigned short*)alloc((2L*2304*320 + 1)/2);
  bool useMfma = ((size_t)(off*4) <= ws_size);

  float* tA = scratch;                   // [2,64,96,96]
  float* tB = tA + 2L*64*9216;           // [2,64,48,48]
  float* tC = tB + 2L*64*2304;           // [2,128,48,48]
  float* tD = tC + 2L*128*2304;          // [2,128,48,48]
  float* tE = tD + 2L*128*2304;          // [2,128,24,24]
  float* tF = tE + 2L*128*576;           // [2,256,24,24]
  float* tG = tF + 2L*256*576;           // [2,256,24,24]
  float* tP = tG + 2L*256*576;           // CI-split partials
  float* dist = scratch;

  // pre-pack weights for MFMA conv (layers 1..7)
  for (int l=1;l<8;l++){
    long tot = 9L*convCI[l]*convCO[l]*2;
    prep_w<<<dim3((unsigned)((tot+255)/256)),256,0,stream>>>(W[l], wp+wpoff[l], convCI[l], convCO[l], tot);
  }

  auto convM = [&](const float* inp, int l, float* outF, long outBSf,
                   int H, int Wd, long inBS_, int S){
    int CI_=convCI[l], CO_=convCO[l];
    int tiles = ((Wd+7)/8)*((H+7)/8);
    dim3 g(tiles, CO_/64, 2*S);
    int nci = CI_/S;
    if (S==1){
      conv_mfma<<<g,256,0,stream>>>(inp, wp+wpoff[l], Bp[l], outF, CI_, CO_, nci, 1, H, Wd, inBS_, outBSf, 0);
    } else {
      conv_mfma<<<g,256,0,stream>>>(inp, wp+wpoff[l], nullptr, tP, CI_, CO_, nci, S, H, Wd, inBS_, (long)CO_*H*Wd, 2L*CO_*H*Wd);
      long tot = 2L*CO_*H*Wd;
      reduce_bias_relu<<<dim3((unsigned)((tot+255)/256)),256,0,stream>>>(
          tP, Bp[l], outF, S, 2L*CO_*H*Wd, CO_, H*Wd, outBSf);
    }
  };
  auto pooll = [&](const float* in, float* out, long NC, int Hi, int Wi){
    long total = NC*(Hi/2)*(Wi/2);
    maxpool2<<<dim3((unsigned)((total+255)/256)), 256, 0, stream>>>(in, out, NC, Hi, Wi);
  };
  auto conv0 = [&](const float* in, float* outF, long outBSf, int H, int Wd, long inBS_){
    int tiles = ((Wd+15)/16)*((H+15)/16);
    dim3 g(tiles, 16, 2);
    conv3x3_v4<4,3><<<g,256,0,stream>>>(in, W[0], Bp[0], outF, 3, 3, 1, H, Wd, inBS_, outBSf, 0);
  };

  // ---- reference path (96x96) ----
  conv0(xr, featR, 320L*9216, 96, 96, 3L*9216);
  convM(featR, 1, tA, 64L*9216, 96, 96, 320L*9216, 1);
  pooll(tA, tB, 2L*64, 96, 96);
  convM(tB, 2, tC, 128L*2304, 48, 48, 64L*2304, 1);
  convM(tC, 3, tD, 128L*2304, 48, 48, 128L*2304, 2);
  pooll(tD, tE, 2L*128, 48, 48);
  convM(tE, 4, tF, 256L*576, 24, 24, 128L*576, 2);
  convM(tF, 5, tG, 256L*576, 24, 24, 256L*576, 4);
  convM(tG, 6, tF, 256L*576, 24, 24, 256L*576, 4);
  convM(tF, 7, tG, 256L*576, 24, 24, 256L*576, 4);
  bicubic_up<<<dim3(256,2), 256, 0, stream>>>(tG, featR + 64L*9216, 24,24,96,96, 256L*576, 320L*9216);

  // ---- template path (48x48) ----
  conv0(xt, featT, 320L*2304, 48, 48, 3L*2304);
  convM(featT, 1, tA, 64L*2304, 48, 48, 320L*2304, 1);
  pooll(tA, tB, 2L*64, 48, 48);
  convM(tB, 2, tC, 128L*576, 24, 24, 64L*576, 2);
  convM(tC, 3, tD, 128L*576, 24, 24, 128L*576, 2);
  pooll(tD, tE, 2L*128, 24, 24);
  convM(tE, 4, tF, 256L*144, 12, 12, 128L*144, 2);
  convM(tF, 5, tG, 256L*144, 12, 12, 256L*144, 4);
  convM(tG, 6, tF, 256L*144, 12, 12, 256L*144, 4);
  convM(tF, 7, tG, 256L*144, 12, 12, 256L*144, 4);
  bicubic_up<<<dim3(256,2), 256, 0, stream>>>(tG, featT + 64L*2304, 12,12,48,48, 256L*144, 320L*2304);

  // ---- normalizer (std = mean bug preserved) ----
  mean_k<<<640, 256, 0, stream>>>(featR, featT, meanb);
  norm_apply<<<dim3((unsigned)((5898240L+255)/256)), 256, 0, stream>>>(featR, meanb, 9216L, 2L*320*9216);
  norm_apply<<<dim3((unsigned)((1474560L+255)/256)), 256, 0, stream>>>(featT, meanb, 2304L, 2L*320*2304);

  if (useMfma){
    split_bf16<<<dim3(288,2), 256, 0, stream>>>(featR, AhR, AlR, 9216);
    split_bf16<<<dim3(72,2),  256, 0, stream>>>(featT, BhT, BlT, 2304);
  }

  // ---- per-batch: dist GEMM, softmax stats, conf + top-10 ----
  for (int b=0; b<2; b++){
    if (useMfma){
      gemm_mfma<<<dim3(18,72), 256, 0, stream>>>(
          AhR + (long)b*9216*320, AlR + (long)b*9216*320,
          BhT + (long)b*2304*320, BlT + (long)b*2304*320, dist);
    } else {
      return; // should not happen given prior rounds' ws_size
    }
    row_stats<<<dim3(9216), 256, 0, stream>>>(dist, ct, rmax + (long)b*9216, rsum + (long)b*9216);
    colstat_part<<<dim3(36,16), 256, 0, stream>>>(dist, cr, pm, ps);
    colstat_merge<<<dim3(9), 256, 0, stream>>>(pm, ps, cm, cs);
    conf_topk<<<dim3(9216), 256, 0, stream>>>(dist, cr, ct,
        rmax + (long)b*9216, rsum + (long)b*9216, cm, cs, (float*)d_out + (long)b*9216);
  }
}

// Round 7
// 762.658 us; speedup vs baseline: 4.5849x; 1.1241x over previous
//
#include <hip/hip_runtime.h>
#include <math.h>

#define CK_A (-0.75f)

typedef __attribute__((ext_vector_type(8))) short bf16x8;
typedef __attribute__((ext_vector_type(4))) float f32x4;

__device__ __forceinline__ float cubicw(float t){
  float at = fabsf(t);
  float at2 = at*at, at3 = at2*at;
  if (at <= 1.f) return (CK_A+2.f)*at3 - (CK_A+3.f)*at2 + 1.f;
  if (at < 2.f)  return CK_A*at3 - 5.f*CK_A*at2 + 8.f*CK_A*at - 4.f*CK_A;
  return 0.f;
}

__device__ __forceinline__ unsigned short f2bf_rne(float f){
  unsigned int u = __float_as_uint(f);
  unsigned int r = (u + 0x7fffu + ((u>>16)&1u)) >> 16;
  return (unsigned short)r;
}
__device__ __forceinline__ float bf2f(unsigned short h){
  return __uint_as_float(((unsigned int)h)<<16);
}

// ---------------- direct conv (layer 0 only, CI=3) ----------------
template<int COB, int CICH>
__global__ __launch_bounds__(256) void conv3x3_v4(
    const float* __restrict__ in, const float* __restrict__ w, const float* __restrict__ bias,
    float* __restrict__ out, int CI, int nci, int S, int H, int W,
    long inBS, long outBS, long sStride)
{
  int tilesX = (W + 15) >> 4;
  int tx0 = (blockIdx.x % tilesX) << 4;
  int ty0 = (blockIdx.x / tilesX) << 4;
  int cob = blockIdx.y * COB;
  int s = blockIdx.z % S, b = blockIdx.z / S;
  int ci0 = s * nci;
  int lx = threadIdx.x & 15, ly = threadIdx.x >> 4;
  __shared__ float tile[CICH][18][20];
  float acc[COB];
  #pragma unroll
  for (int j=0;j<COB;j++) acc[j]=0.f;
  const float* inb = in + (long)b*inBS;
  int ox = tx0+lx, oy = ty0+ly;

  for (int c0=ci0; c0<ci0+nci; c0+=CICH){
    for (int idx = threadIdx.x; idx < CICH*324; idx += 256){
      int cl = idx/324, rem = idx - cl*324;
      int r = rem/18, c = rem - r*18;
      int gy = ty0 + r - 1, gx = tx0 + c - 1;
      const float* ic = inb + (long)(c0+cl)*H*W;
      tile[cl][r][c] = (gy>=0 && gy<H && gx>=0 && gx<W) ? ic[(long)gy*W+gx] : 0.f;
    }
    __syncthreads();
    #pragma unroll
    for (int cl=0; cl<CICH; cl++){
      float t00=tile[cl][ly+0][lx+0], t01=tile[cl][ly+0][lx+1], t02=tile[cl][ly+0][lx+2];
      float t10=tile[cl][ly+1][lx+0], t11=tile[cl][ly+1][lx+1], t12=tile[cl][ly+1][lx+2];
      float t20=tile[cl][ly+2][lx+0], t21=tile[cl][ly+2][lx+1], t22=tile[cl][ly+2][lx+2];
      #pragma unroll
      for (int j=0;j<COB;j++){
        const float* wp = w + ((long)(cob+j)*CI + (c0+cl))*9;
        float a = acc[j];
        a = fmaf(t00, wp[0], a); a = fmaf(t01, wp[1], a); a = fmaf(t02, wp[2], a);
        a = fmaf(t10, wp[3], a); a = fmaf(t11, wp[4], a); a = fmaf(t12, wp[5], a);
        a = fmaf(t20, wp[6], a); a = fmaf(t21, wp[7], a); a = fmaf(t22, wp[8], a);
        acc[j] = a;
      }
    }
    __syncthreads();
  }
  if (ox < W && oy < H){
    float* outp = out + (long)s*sStride + (long)b*outBS;
    #pragma unroll
    for (int j=0;j<COB;j++){
      float v = acc[j];
      if (bias) v = fmaxf(v + bias[cob+j], 0.f);
      outp[(long)(cob+j)*H*W + (long)oy*W + ox] = v;
    }
  }
}

// ---------------- weight pre-pack for MFMA conv ----------------
__global__ void prep_w(const float* __restrict__ w, unsigned short* __restrict__ wp,
                       int CI, int CO, long total){
  long e = (long)blockIdx.x*256 + threadIdx.x;
  if (e >= total) return;
  int j = (int)(e & 7);
  int lane = (int)((e>>3) & 63);
  int h = (int)((e>>9) & 1);
  long rem = e >> 10;
  int G = CO >> 4, KC = CI >> 5;
  int g = (int)(rem % G); long q = rem / G;
  int kc = (int)(q % KC); int o = (int)(q / KC);
  int co = (g<<4) + (lane & 15);
  int ci = (kc<<5) + ((lane>>4)<<3) + j;
  float v = w[((long)co*CI + ci)*9 + o];
  unsigned short hi = f2bf_rne(v);
  if (h == 0) wp[e] = hi;
  else wp[e] = f2bf_rne(v - bf2f(hi));
}

// ---------------- implicit-GEMM MFMA conv (split-bf16, 3 products) -------
union AB { bf16x8 v; uint4 u; };
#define MFB(a,b,c) __builtin_amdgcn_mfma_f32_16x16x32_bf16(a,b,c,0,0,0)

__global__ __launch_bounds__(256) void conv_mfma(
    const float* __restrict__ in, const unsigned short* __restrict__ Wp,
    const float* __restrict__ bias, float* __restrict__ out,
    int CI, int CO, int nci, int S, int H, int W,
    long inBS, long outBS, long sStride)
{
  int HW = H*W;
  int tilesX = (W+7)>>3;
  int tx0 = (blockIdx.x % tilesX)<<3, ty0 = (blockIdx.x / tilesX)<<3;
  int cobase = blockIdx.y << 6;
  int s = blockIdx.z % S, b = blockIdx.z / S;
  int tid = threadIdx.x, lane = tid & 63, wid = tid>>6;
  int wm = wid>>1, wn = wid&1;
  int KC = CI>>5, G = CO>>4;
  __shared__ __align__(16) unsigned short Bth[4000];
  __shared__ __align__(16) unsigned short Btl[4000];
  const float* inb = in + (long)b*inBS;

  int sofs[13]; int sla[13];
  #pragma unroll
  for (int i=0;i<13;i++){
    int e = tid + i*256;
    int cidx = e / 100, pix = e - cidx*100;
    int hy = pix/10, hx = pix - hy*10;
    int gy = ty0 - 1 + hy, gx = tx0 - 1 + hx;
    bool v = (gy>=0) && (gy<H) && (gx>=0) && (gx<W);
    sofs[i] = v ? (cidx*HW + gy*W + gx) : -1;
    sla[i] = pix*40 + cidx;
  }

  int n15 = lane & 15;
  int klane8 = (lane>>4)<<3;
  int p0 = wn*32 + n15;
  int base0 = ((p0>>3)*10 + (p0&7))*40 + klane8;
  int p1 = p0 + 16;
  int base1 = ((p1>>3)*10 + (p1&7))*40 + klane8;
  int g0 = (cobase>>4) + wm*2;

  f32x4 acc[2][2];
  #pragma unroll
  for (int i=0;i<2;i++)
    #pragma unroll
    for (int j=0;j<2;j++) acc[i][j] = (f32x4){0.f,0.f,0.f,0.f};

  int nkc = nci >> 5;
  for (int kk=0; kk<nkc; kk++){
    int ci0 = s*nci + (kk<<5);
    __syncthreads();
    #pragma unroll
    for (int i=0;i<12;i++){
      float v = (sofs[i] >= 0) ? inb[(long)ci0*HW + sofs[i]] : 0.f;
      unsigned short h = f2bf_rne(v);
      Bth[sla[i]] = h;
      Btl[sla[i]] = f2bf_rne(v - bf2f(h));
    }
    if (tid < 128){
      float v = (sofs[12] >= 0) ? inb[(long)ci0*HW + sofs[12]] : 0.f;
      unsigned short h = f2bf_rne(v);
      Bth[sla[12]] = h;
      Btl[sla[12]] = f2bf_rne(v - bf2f(h));
    }
    __syncthreads();
    int kc = ci0 >> 5;
    const unsigned short* wpb = Wp + (long)kc*G*1024 + (long)lane*8;
    #pragma unroll
    for (int o=0;o<9;o++){
      const int dy = o/3, dx = o - dy*3;
      const int sh = (dy*10+dx)*40;
      const unsigned short* wo = wpb + (long)o*KC*G*1024;
      AB a0h,a0l,a1h,a1l, b0h,b0l,b1h,b1l;
      a0h.u = *(const uint4*)(wo + (long)g0*1024);
      a0l.u = *(const uint4*)(wo + (long)g0*1024 + 512);
      a1h.u = *(const uint4*)(wo + (long)(g0+1)*1024);
      a1l.u = *(const uint4*)(wo + (long)(g0+1)*1024 + 512);
      b0h.v = *(const bf16x8*)&Bth[base0 + sh];
      b0l.v = *(const bf16x8*)&Btl[base0 + sh];
      b1h.v = *(const bf16x8*)&Bth[base1 + sh];
      b1l.v = *(const bf16x8*)&Btl[base1 + sh];
      acc[0][0] = MFB(a0h.v, b0l.v, acc[0][0]);
      acc[0][0] = MFB(a0l.v, b0h.v, acc[0][0]);
      acc[0][0] = MFB(a0h.v, b0h.v, acc[0][0]);
      acc[0][1] = MFB(a0h.v, b1l.v, acc[0][1]);
      acc[0][1] = MFB(a0l.v, b1h.v, acc[0][1]);
      acc[0][1] = MFB(a0h.v, b1h.v, acc[0][1]);
      acc[1][0] = MFB(a1h.v, b0l.v, acc[1][0]);
      acc[1][0] = MFB(a1l.v, b0h.v, acc[1][0]);
      acc[1][0] = MFB(a1h.v, b0h.v, acc[1][0]);
      acc[1][1] = MFB(a1h.v, b1l.v, acc[1][1]);
      acc[1][1] = MFB(a1l.v, b1h.v, acc[1][1]);
      acc[1][1] = MFB(a1h.v, b1h.v, acc[1][1]);
    }
  }

  float* outp = out + (long)s*sStride + (long)b*outBS;
  #pragma unroll
  for (int ng=0; ng<2; ng++){
    int p = wn*32 + ng*16 + n15;
    int gy = ty0 + (p>>3), gx = tx0 + (p&7);
    bool ok = (gy<H) && (gx<W);
    #pragma unroll
    for (int mg=0; mg<2; mg++){
      #pragma unroll
      for (int r=0;r<4;r++){
        if (ok){
          int co = cobase + wm*32 + mg*16 + ((lane>>4)<<2) + r;
          float v = acc[mg][ng][r];
          if (bias) v = fmaxf(v + bias[co], 0.f);
          outp[(long)co*HW + (long)gy*W + gx] = v;
        }
      }
    }
  }
}

// ---------------- partial reduce + bias + relu ----------------
__global__ void reduce_bias_relu(const float* __restrict__ part, const float* __restrict__ bias,
                                 float* __restrict__ out, int S, long sStride,
                                 int CO, int HW, long outBS){
  long tot = 2L*CO*HW;
  long e = (long)blockIdx.x*256 + threadIdx.x;
  if (e >= tot) return;
  long b = e / ((long)CO*HW);
  long r = e - b*(long)CO*HW;
  float v = 0.f;
  for (int s=0;s<S;s++) v += part[(long)s*sStride + e];
  int co = (int)(r / HW);
  out[b*outBS + r] = fmaxf(v + bias[co], 0.f);
}

// ---------------- maxpool 2x2 stride 2 ----------------
__global__ void maxpool2(const float* __restrict__ in, float* __restrict__ out, long NC, int Hi, int Wi){
  int Ho = Hi>>1, Wo = Wi>>1;
  long total = NC * Ho * Wo;
  long idx = (long)blockIdx.x*256 + threadIdx.x;
  if (idx >= total) return;
  int x = (int)(idx % Wo); long t = idx / Wo; int y = (int)(t % Ho); long nc = t / Ho;
  const float* p = in + (nc*Hi + 2*y)*(long)Wi + 2*x;
  float v = fmaxf(fmaxf(p[0], p[1]), fmaxf(p[Wi], p[Wi+1]));
  out[idx] = v;
}

// ---------------- bicubic upsample (align_corners=True) ----------------
__global__ __launch_bounds__(256) void bicubic_up(
    const float* __restrict__ in, float* __restrict__ out,
    int Hin, int Win, int Hout, int Wout, long inBStride, long outBStride)
{
  int c = blockIdx.x, b = blockIdx.y;
  __shared__ float s[576];
  const float* ip = in + (long)b*inBStride + (long)c*Hin*Win;
  float* op = out + (long)b*outBStride + (long)c*Hout*Wout;
  int n = Hin*Win;
  for (int i = threadIdx.x; i < n; i += 256) s[i] = ip[i];
  __syncthreads();
  float scy = (float)((double)(Hin-1)/(double)(Hout-1));
  float scx = (float)((double)(Win-1)/(double)(Wout-1));
  int total = Hout*Wout;
  for (int idx = threadIdx.x; idx < total; idx += 256){
    int ox = idx % Wout, oy = idx / Wout;
    float py = oy * scy, px = ox * scx;
    float iy0f = floorf(py), ix0f = floorf(px);
    int iy0 = (int)iy0f, ix0 = (int)ix0f;
    float fy = py - iy0f, fx = px - ix0f;
    float wy[4], wx[4]; int xs[4], ys[4];
    #pragma unroll
    for (int t=0;t<4;t++){
      wy[t] = cubicw(fy - (float)(t-1));
      wx[t] = cubicw(fx - (float)(t-1));
      ys[t] = min(max(iy0 + t - 1, 0), Hin-1);
      xs[t] = min(max(ix0 + t - 1, 0), Win-1);
    }
    float acc = 0.f;
    #pragma unroll
    for (int i=0;i<4;i++){
      const float* row = &s[ys[i]*Win];
      float rs = wx[0]*row[xs[0]] + wx[1]*row[xs[1]] + wx[2]*row[xs[2]] + wx[3]*row[xs[3]];
      acc = fmaf(wy[i], rs, acc);
    }
    op[idx] = acc;
  }
}

// ---------------- normalizer ----------------
__global__ __launch_bounds__(256) void mean_k(const float* __restrict__ fR, const float* __restrict__ fT, float* __restrict__ mean){
  int c = blockIdx.x % 320, b = blockIdx.x / 320;
  const float* a = fR + ((long)b*320+c)*9216L;
  const float* t = fT + ((long)b*320+c)*2304L;
  float s = 0.f;
  for (int i=threadIdx.x;i<9216;i+=256) s += a[i];
  for (int i=threadIdx.x;i<2304;i+=256) s += t[i];
  __shared__ float sm[4];
  for (int o=32;o;o>>=1) s += __shfl_down(s,o);
  int lane = threadIdx.x & 63, wv = threadIdx.x >> 6;
  if (lane==0) sm[wv] = s;
  __syncthreads();
  if (threadIdx.x==0) mean[b*320+c] = (sm[0]+sm[1]+sm[2]+sm[3]) * (1.f/11520.f);
}

__global__ void norm_apply(float* __restrict__ f, const float* __restrict__ mean, long perChan, long total){
  long idx = (long)blockIdx.x*256 + threadIdx.x;
  if (idx >= total) return;
  long c = (idx / perChan) % 320;
  long b = idx / (perChan*320);
  float m = mean[b*320+c];
  f[idx] = (f[idx] - m) / (m + 1e-8f);
}

// ---------------- split+transpose for dist GEMM ----------------
__global__ __launch_bounds__(256) void split_bf16(const float* __restrict__ feat,
    unsigned short* __restrict__ oh, unsigned short* __restrict__ ol, int P){
  int b = blockIdx.y; int m0 = blockIdx.x*32;
  __shared__ unsigned int t[32][321];
  int ml = threadIdx.x & 31, kq = threadIdx.x >> 5;
  const float* fp = feat + (long)b*320*P + m0 + ml;
  for (int k = kq*40; k < kq*40+40; k++){
    float v = fp[(long)k*P];
    unsigned short h = f2bf_rne(v);
    unsigned short l = f2bf_rne(v - bf2f(h));
    t[ml][k] = ((unsigned int)h<<16) | l;
  }
  __syncthreads();
  long base = ((long)b*P + m0)*320;
  for (int idx = threadIdx.x; idx < 32*320; idx += 256){
    int m = idx/320, k = idx - m*320;
    unsigned int p = t[m][k];
    oh[base + (long)m*320 + k] = (unsigned short)(p>>16);
    ol[base + (long)m*320 + k] = (unsigned short)(p & 0xffffu);
  }
}

// ---------------- split-bf16 MFMA dist GEMM ----------------
union FragU { bf16x8 v; uint2 u[2]; };

__global__ __launch_bounds__(256) void gemm_mfma(
    const unsigned short* __restrict__ Ah, const unsigned short* __restrict__ Al,
    const unsigned short* __restrict__ Bh, const unsigned short* __restrict__ Bl,
    float* __restrict__ D){
  const int N = 2304, K = 320;
  int n0 = blockIdx.x*128, m0 = blockIdx.y*128;
  __shared__ unsigned short As[2][128][36], Bs[2][128][36];
  int tid = threadIdx.x, lane = tid & 63, wid = tid >> 6;
  int wm = wid >> 1, wn = wid & 1;
  f32x4 acc[4][4];
  #pragma unroll
  for (int i=0;i<4;i++)
    #pragma unroll
    for (int j=0;j<4;j++) acc[i][j] = (f32x4){0.f,0.f,0.f,0.f};

  for (int k0=0; k0<K; k0+=32){
    #pragma unroll
    for (int q=0;q<2;q++){
      int flat = q*256 + tid;
      int row = flat >> 2, seg = flat & 3;
      long ga = (long)(m0+row)*K + k0 + seg*8;
      long gb = (long)(n0+row)*K + k0 + seg*8;
      uint4 va = *(const uint4*)(Ah + ga);
      *(uint2*)&As[0][row][seg*8]   = make_uint2(va.x, va.y);
      *(uint2*)&As[0][row][seg*8+4] = make_uint2(va.z, va.w);
      uint4 vb = *(const uint4*)(Al + ga);
      *(uint2*)&As[1][row][seg*8]   = make_uint2(vb.x, vb.y);
      *(uint2*)&As[1][row][seg*8+4] = make_uint2(vb.z, vb.w);
      uint4 vc = *(const uint4*)(Bh + gb);
      *(uint2*)&Bs[0][row][seg*8]   = make_uint2(vc.x, vc.y);
      *(uint2*)&Bs[0][row][seg*8+4] = make_uint2(vc.z, vc.w);
      uint4 vd = *(const uint4*)(Bl + gb);
      *(uint2*)&Bs[1][row][seg*8]   = make_uint2(vd.x, vd.y);
      *(uint2*)&Bs[1][row][seg*8+4] = make_uint2(vd.z, vd.w);
    }
    __syncthreads();

    FragU af[2][4], bf[2][4];
    #pragma unroll
    for (int g=0; g<4; g++){
      const unsigned short* pa0 = &As[0][wm*64 + g*16 + (lane&15)][(lane>>4)*4];
      const unsigned short* pa1 = &As[1][wm*64 + g*16 + (lane&15)][(lane>>4)*4];
      const unsigned short* pb0 = &Bs[0][wn*64 + g*16 + (lane&15)][(lane>>4)*4];
      const unsigned short* pb1 = &Bs[1][wn*64 + g*16 + (lane&15)][(lane>>4)*4];
      af[0][g].u[0] = *(const uint2*)pa0; af[0][g].u[1] = *(const uint2*)(pa0 + 16);
      af[1][g].u[0] = *(const uint2*)pa1; af[1][g].u[1] = *(const uint2*)(pa1 + 16);
      bf[0][g].u[0] = *(const uint2*)pb0; bf[0][g].u[1] = *(const uint2*)(pb0 + 16);
      bf[1][g].u[0] = *(const uint2*)pb1; bf[1][g].u[1] = *(const uint2*)(pb1 + 16);
    }
    #pragma unroll
    for (int mg=0; mg<4; mg++)
      #pragma unroll
      for (int ng=0; ng<4; ng++){
        acc[mg][ng] = MFB(af[0][mg].v, bf[1][ng].v, acc[mg][ng]);
        acc[mg][ng] = MFB(af[1][mg].v, bf[0][ng].v, acc[mg][ng]);
        acc[mg][ng] = MFB(af[0][mg].v, bf[0][ng].v, acc[mg][ng]);
      }
    __syncthreads();
  }
  #pragma unroll
  for (int mg=0; mg<4; mg++)
    #pragma unroll
    for (int ng=0; ng<4; ng++){
      int col = n0 + wn*64 + ng*16 + (lane & 15);
      #pragma unroll
      for (int r=0;r<4;r++){
        int rowv = m0 + wm*64 + mg*16 + (lane>>4)*4 + r;
        D[(long)rowv*N + col] = acc[mg][ng][r];
      }
    }
}

// ---------------- column softmax stats ----------------
__device__ __forceinline__ void merge_ms(float& m, float& s, float m2, float s2){
  float M = fmaxf(m, m2);
  s = s*expf(m - M) + s2*expf(m2 - M);
  m = M;
}

__global__ __launch_bounds__(256) void colstat_part(const float* __restrict__ D, const float* __restrict__ coefr,
                                                    float* __restrict__ pm, float* __restrict__ ps){
  int tx = threadIdx.x & 63, ty = threadIdx.x >> 6;
  int n = blockIdx.x*64 + tx;
  float cr = *coefr;
  float m = -INFINITY, s = 0.f;
  int r0 = blockIdx.y * 576;
  for (int r = r0 + ty; r < r0 + 576; r += 4){
    float v = cr * D[(long)r*2304 + n];
    if (v > m){ s = s*expf(m - v) + 1.f; m = v; }
    else s += expf(v - m);
  }
  __shared__ float smm[4][64], sms[4][64];
  smm[ty][tx]=m; sms[ty][tx]=s;
  __syncthreads();
  if (ty==0){
    #pragma unroll
    for (int k=1;k<4;k++) merge_ms(m, s, smm[k][tx], sms[k][tx]);
    pm[(long)blockIdx.y*2304 + n] = m;
    ps[(long)blockIdx.y*2304 + n] = s;
  }
}

// merge 16 partials and emit q[n] = 0.5*cmax[n] + 0.5*log(csum[n])
__global__ void colstat_merge(const float* __restrict__ pm, const float* __restrict__ ps,
                              float* __restrict__ qcol){
  int idx = blockIdx.x*256 + threadIdx.x;
  if (idx >= 2304) return;
  float m=-INFINITY, s=0.f;
  for (int k=0;k<16;k++){
    merge_ms(m, s, pm[(long)k*2304+idx], ps[(long)k*2304+idx]);
  }
  qcol[idx] = 0.5f*m + 0.5f*logf(s);
}

// ---------------- fused row-stats + confidence + top-10 mean -------------
// conf(m,n) = exp(t(n) - rho(m)), t = 0.5*(cr+ct)*d - qcol[n],
// rho = 0.5*rmax + 0.5*log(rsum). Selection on order-preserving uint keys
// with idx in low 12 bits (exact values recomputed for the 10 winners).
__global__ __launch_bounds__(256) void conf_topk_f(const float* __restrict__ D,
    const float* __restrict__ coefr, const float* __restrict__ coeft,
    const float* __restrict__ qcol, float* __restrict__ outp){
  int m = blockIdx.x;
  const float* drow = D + (long)m*2304;
  int tid = threadIdx.x, lane = tid & 63, wv = tid >> 6;
  float ct = *coeft, cr = *coefr;
  float v[9], tv[9];
  #pragma unroll
  for (int i=0;i<9;i++){ v[i] = drow[tid + i*256]; tv[i] = ct * v[i]; }

  __shared__ float sred[8];
  __shared__ unsigned int cand[40];

  // row max of ct*d
  float mx = tv[0];
  #pragma unroll
  for (int i=1;i<9;i++) mx = fmaxf(mx, tv[i]);
  #pragma unroll
  for (int o=1;o<64;o<<=1) mx = fmaxf(mx, __shfl_xor(mx, o));
  if (lane==0) sred[wv] = mx;
  __syncthreads();
  mx = fmaxf(fmaxf(sred[0],sred[1]), fmaxf(sred[2],sred[3]));
  // row sum of exp
  float s = 0.f;
  #pragma unroll
  for (int i=0;i<9;i++) s += expf(tv[i]-mx);
  #pragma unroll
  for (int o=1;o<64;o<<=1) s += __shfl_xor(s, o);
  if (lane==0) sred[4+wv] = s;
  __syncthreads();
  float rs = sred[4]+sred[5]+sred[6]+sred[7];
  float rho = 0.5f*mx + 0.5f*logf(rs);
  float hc = 0.5f*(cr+ct);

  // selection keys: monotone uint map of t, low 12 bits = element index
  unsigned int key[9];
  #pragma unroll
  for (int i=0;i<9;i++){
    int n = i*256 + tid;
    float t = fmaf(hc, v[i], -qcol[n]);
    unsigned int b = __float_as_uint(t);
    b ^= (b >> 31) ? 0xFFFFFFFFu : 0x80000000u;
    key[i] = (b & 0xFFFFF000u) | (unsigned)n;
  }

  // per-wave top-10 (barrier-free)
  for (int t10=0; t10<10; t10++){
    unsigned int lb = key[0];
    #pragma unroll
    for (int i=1;i<9;i++) lb = lb > key[i] ? lb : key[i];
    unsigned int wb = lb;
    #pragma unroll
    for (int o=1;o<64;o<<=1){
      unsigned int x = (unsigned int)__shfl_xor((int)wb, o);
      wb = wb > x ? wb : x;
    }
    if (lane==0) cand[wv*10 + t10] = wb;
    #pragma unroll
    for (int i=0;i<9;i++) if (key[i]==wb) key[i]=0;
  }
  __syncthreads();

  // wave 0 merges 40 candidates, recomputes exact conf for the winners
  if (wv == 0){
    unsigned int k = (lane < 40) ? cand[lane] : 0u;
    int sel = -1;
    for (int t10=0; t10<10; t10++){
      unsigned int wb = k;
      #pragma unroll
      for (int o=1;o<64;o<<=1){
        unsigned int x = (unsigned int)__shfl_xor((int)wb, o);
        wb = wb > x ? wb : x;
      }
      if (k == wb) k = 0;
      if (lane == t10) sel = (int)(wb & 0xFFFu);
    }
    float c = 0.f;
    if (sel >= 0){
      float t = fmaf(hc, drow[sel], -qcol[sel]);
      c = expf(t - rho);
    }
    #pragma unroll
    for (int o=1;o<64;o<<=1) c += __shfl_xor(c, o);
    if (lane == 0) outp[m] = c * 0.1f;
  }
}

// ---------------- host ----------------
extern "C" void kernel_launch(void* const* d_in, const int* in_sizes, int n_in,
                              void* d_out, int out_size, void* d_ws, size_t ws_size,
                              hipStream_t stream) {
  const float *W[8], *Bp[8], *xr, *xt, *cr, *ct;
  if (in_sizes[0] == 1728){
    for (int i=0;i<8;i++){ W[i]=(const float*)d_in[2*i]; Bp[i]=(const float*)d_in[2*i+1]; }
    xr=(const float*)d_in[16]; xt=(const float*)d_in[17];
    cr=(const float*)d_in[18]; ct=(const float*)d_in[19];
  } else {
    xr=(const float*)d_in[0]; xt=(const float*)d_in[1];
    cr=(const float*)d_in[2]; ct=(const float*)d_in[3];
    for (int i=0;i<8;i++){ W[i]=(const float*)d_in[4+2*i]; Bp[i]=(const float*)d_in[5+2*i]; }
  }

  const int convCI[8] = {3,64,64,128,128,256,256,256};
  const int convCO[8] = {64,64,128,128,256,256,256,256};
  long wpoff[8]; long wtot = 0;
  for (int l=1;l<8;l++){ wpoff[l] = wtot; wtot += 9L*convCI[l]*convCO[l]*2; }

  float* ws = (float*)d_ws;
  long off = 0;
  auto alloc = [&](long nfl){ float* p = ws + off; off += (nfl + 63) & ~63L; return p; };
  float* featR = alloc(2L*320*9216);
  float* featT = alloc(2L*320*2304);
  float* meanb = alloc(640);
  float* pm    = alloc(16L*2304);
  float* ps    = alloc(16L*2304);
  float* qcol  = alloc(2304);
  unsigned short* wp = (unsigned short*)alloc((wtot+1)/2);
  float* scratch = alloc(9216L*2304);
  if ((size_t)(off*4) > ws_size) return;

  unsigned short* AhR = (unsigned short*)alloc((2L*9216*320 + 1)/2);
  unsigned short* AlR = (unsigned short*)alloc((2L*9216*320 + 1)/2);
  unsigned short* BhT = (unsigned short*)alloc((2L*2304*320 + 1)/2);
  unsigned short* BlT = (unsigned short*)alloc((2L*2304*320 + 1)/2);
  if ((size_t)(off*4) > ws_size) return;

  float* tA = scratch;                   // [2,64,96,96]
  float* tB = tA + 2L*64*9216;           // [2,64,48,48]
  float* tC = tB + 2L*64*2304;           // [2,128,48,48]
  float* tD = tC + 2L*128*2304;          // [2,128,48,48]
  float* tE = tD + 2L*128*2304;          // [2,128,24,24]
  float* tF = tE + 2L*128*576;           // [2,256,24,24]
  float* tG = tF + 2L*256*576;           // [2,256,24,24]
  float* tP = tG + 2L*256*576;           // CI-split partials
  float* dist = scratch;

  for (int l=1;l<8;l++){
    long tot = 9L*convCI[l]*convCO[l]*2;
    prep_w<<<dim3((unsigned)((tot+255)/256)),256,0,stream>>>(W[l], wp+wpoff[l], convCI[l], convCO[l], tot);
  }

  auto convM = [&](const float* inp, int l, float* outF, long outBSf,
                   int H, int Wd, long inBS_, int S){
    int CI_=convCI[l], CO_=convCO[l];
    int tiles = ((Wd+7)/8)*((H+7)/8);
    dim3 g(tiles, CO_/64, 2*S);
    int nci = CI_/S;
    if (S==1){
      conv_mfma<<<g,256,0,stream>>>(inp, wp+wpoff[l], Bp[l], outF, CI_, CO_, nci, 1, H, Wd, inBS_, outBSf, 0);
    } else {
      conv_mfma<<<g,256,0,stream>>>(inp, wp+wpoff[l], nullptr, tP, CI_, CO_, nci, S, H, Wd, inBS_, (long)CO_*H*Wd, 2L*CO_*H*Wd);
      long tot = 2L*CO_*H*Wd;
      reduce_bias_relu<<<dim3((unsigned)((tot+255)/256)),256,0,stream>>>(
          tP, Bp[l], outF, S, 2L*CO_*H*Wd, CO_, H*Wd, outBSf);
    }
  };
  auto pooll = [&](const float* in, float* out, long NC, int Hi, int Wi){
    long total = NC*(Hi/2)*(Wi/2);
    maxpool2<<<dim3((unsigned)((total+255)/256)), 256, 0, stream>>>(in, out, NC, Hi, Wi);
  };
  auto conv0 = [&](const float* in, float* outF, long outBSf, int H, int Wd, long inBS_){
    int tiles = ((Wd+15)/16)*((H+15)/16);
    dim3 g(tiles, 16, 2);
    conv3x3_v4<4,3><<<g,256,0,stream>>>(in, W[0], Bp[0], outF, 3, 3, 1, H, Wd, inBS_, outBSf, 0);
  };

  // ---- reference path (96x96) ----
  conv0(xr, featR, 320L*9216, 96, 96, 3L*9216);
  convM(featR, 1, tA, 64L*9216, 96, 96, 320L*9216, 1);
  pooll(tA, tB, 2L*64, 96, 96);
  convM(tB, 2, tC, 128L*2304, 48, 48, 64L*2304, 1);
  convM(tC, 3, tD, 128L*2304, 48, 48, 128L*2304, 2);
  pooll(tD, tE, 2L*128, 48, 48);
  convM(tE, 4, tF, 256L*576, 24, 24, 128L*576, 2);
  convM(tF, 5, tG, 256L*576, 24, 24, 256L*576, 4);
  convM(tG, 6, tF, 256L*576, 24, 24, 256L*576, 4);
  convM(tF, 7, tG, 256L*576, 24, 24, 256L*576, 4);
  bicubic_up<<<dim3(256,2), 256, 0, stream>>>(tG, featR + 64L*9216, 24,24,96,96, 256L*576, 320L*9216);

  // ---- template path (48x48) ----
  conv0(xt, featT, 320L*2304, 48, 48, 3L*2304);
  convM(featT, 1, tA, 64L*2304, 48, 48, 320L*2304, 1);
  pooll(tA, tB, 2L*64, 48, 48);
  convM(tB, 2, tC, 128L*576, 24, 24, 64L*576, 2);
  convM(tC, 3, tD, 128L*576, 24, 24, 128L*576, 2);
  pooll(tD, tE, 2L*128, 24, 24);
  convM(tE, 4, tF, 256L*144, 12, 12, 128L*144, 2);
  convM(tF, 5, tG, 256L*144, 12, 12, 256L*144, 4);
  convM(tG, 6, tF, 256L*144, 12, 12, 256L*144, 4);
  convM(tF, 7, tG, 256L*144, 12, 12, 256L*144, 4);
  bicubic_up<<<dim3(256,2), 256, 0, stream>>>(tG, featT + 64L*2304, 12,12,48,48, 256L*144, 320L*2304);

  // ---- normalizer (std = mean bug preserved) ----
  mean_k<<<640, 256, 0, stream>>>(featR, featT, meanb);
  norm_apply<<<dim3((unsigned)((5898240L+255)/256)), 256, 0, stream>>>(featR, meanb, 9216L, 2L*320*9216);
  norm_apply<<<dim3((unsigned)((1474560L+255)/256)), 256, 0, stream>>>(featT, meanb, 2304L, 2L*320*2304);

  split_bf16<<<dim3(288,2), 256, 0, stream>>>(featR, AhR, AlR, 9216);
  split_bf16<<<dim3(72,2),  256, 0, stream>>>(featT, BhT, BlT, 2304);

  // ---- per-batch: dist GEMM, column stats, fused conf + top-10 ----
  for (int b=0; b<2; b++){
    gemm_mfma<<<dim3(18,72), 256, 0, stream>>>(
        AhR + (long)b*9216*320, AlR + (long)b*9216*320,
        BhT + (long)b*2304*320, BlT + (long)b*2304*320, dist);
    colstat_part<<<dim3(36,16), 256, 0, stream>>>(dist, cr, pm, ps);
    colstat_merge<<<dim3(9), 256, 0, stream>>>(pm, ps, qcol);
    conf_topk_f<<<dim3(9216), 256, 0, stream>>>(dist, cr, ct, qcol, (float*)d_out + (long)b*9216);
  }
}

// Round 8
// 499.867 us; speedup vs baseline: 6.9952x; 1.5257x over previous
//
#include <hip/hip_runtime.h>
#include <math.h>

#define CK_A (-0.75f)

typedef __attribute__((ext_vector_type(8))) short bf16x8;
typedef __attribute__((ext_vector_type(4))) float f32x4;

struct CImg { const float* in; float* out; int H, W, tiles; long inBS, outBS, sStride; };

__device__ __forceinline__ float cubicw(float t){
  float at = fabsf(t);
  float at2 = at*at, at3 = at2*at;
  if (at <= 1.f) return (CK_A+2.f)*at3 - (CK_A+3.f)*at2 + 1.f;
  if (at < 2.f)  return CK_A*at3 - 5.f*CK_A*at2 + 8.f*CK_A*at - 4.f*CK_A;
  return 0.f;
}

__device__ __forceinline__ unsigned short f2bf_rne(float f){
  unsigned int u = __float_as_uint(f);
  unsigned int r = (u + 0x7fffu + ((u>>16)&1u)) >> 16;
  return (unsigned short)r;
}
__device__ __forceinline__ float bf2f(unsigned short h){
  return __uint_as_float(((unsigned int)h)<<16);
}

__device__ __forceinline__ void merge_ms(float& m, float& s, float m2, float s2){
  float M = fmaxf(m, m2);
  s = s*expf(m - M) + s2*expf(m2 - M);
  m = M;
}

#define MFB(a,b,c) __builtin_amdgcn_mfma_f32_16x16x32_bf16(a,b,c,0,0,0)

// ---------------- conv0 (CI=3 direct), both images in one launch ----------
__global__ __launch_bounds__(256) void conv0_d(CImg A, CImg B,
    const float* __restrict__ w, const float* __restrict__ bias){
  bool isA = (int)blockIdx.x < A.tiles;
  const float* in = isA ? A.in : B.in;
  float* out = isA ? A.out : B.out;
  int H = isA ? A.H : B.H, W = isA ? A.W : B.W;
  long inBS = isA ? A.inBS : B.inBS, outBS = isA ? A.outBS : B.outBS;
  int tile = isA ? blockIdx.x : blockIdx.x - A.tiles;
  int tilesX = (W + 15) >> 4;
  int tx0 = (tile % tilesX) << 4, ty0 = (tile / tilesX) << 4;
  int cob = blockIdx.y * 4;
  int b = blockIdx.z;
  int lx = threadIdx.x & 15, ly = threadIdx.x >> 4;
  __shared__ float tile_s[3][18][20];
  float acc[4] = {0.f,0.f,0.f,0.f};
  const float* inb = in + (long)b*inBS;
  int ox = tx0+lx, oy = ty0+ly;

  for (int idx = threadIdx.x; idx < 3*324; idx += 256){
    int cl = idx/324, rem = idx - cl*324;
    int r = rem/18, c = rem - r*18;
    int gy = ty0 + r - 1, gx = tx0 + c - 1;
    const float* ic = inb + (long)cl*H*W;
    tile_s[cl][r][c] = (gy>=0 && gy<H && gx>=0 && gx<W) ? ic[(long)gy*W+gx] : 0.f;
  }
  __syncthreads();
  #pragma unroll
  for (int cl=0; cl<3; cl++){
    float t00=tile_s[cl][ly+0][lx+0], t01=tile_s[cl][ly+0][lx+1], t02=tile_s[cl][ly+0][lx+2];
    float t10=tile_s[cl][ly+1][lx+0], t11=tile_s[cl][ly+1][lx+1], t12=tile_s[cl][ly+1][lx+2];
    float t20=tile_s[cl][ly+2][lx+0], t21=tile_s[cl][ly+2][lx+1], t22=tile_s[cl][ly+2][lx+2];
    #pragma unroll
    for (int j=0;j<4;j++){
      const float* wp = w + ((long)(cob+j)*3 + cl)*9;
      float a = acc[j];
      a = fmaf(t00, wp[0], a); a = fmaf(t01, wp[1], a); a = fmaf(t02, wp[2], a);
      a = fmaf(t10, wp[3], a); a = fmaf(t11, wp[4], a); a = fmaf(t12, wp[5], a);
      a = fmaf(t20, wp[6], a); a = fmaf(t21, wp[7], a); a = fmaf(t22, wp[8], a);
      acc[j] = a;
    }
  }
  if (ox < W && oy < H){
    #pragma unroll
    for (int j=0;j<4;j++){
      float v = fmaxf(acc[j] + bias[cob+j], 0.f);
      out[(long)b*outBS + (long)(cob+j)*H*W + (long)oy*W + ox] = v;
    }
  }
}

// ---------------- weight pre-pack, all layers one launch ----------------
__global__ void prep_w_all(const float* __restrict__ w1, const float* __restrict__ w2,
                           const float* __restrict__ w3, const float* __restrict__ w4,
                           const float* __restrict__ w5, const float* __restrict__ w6,
                           const float* __restrict__ w7, unsigned short* __restrict__ wp){
  const int ciT[7] = {64,64,128,128,256,256,256};
  const int coT[7] = {64,128,128,256,256,256,256};
  int l = blockIdx.y;
  const float* w = l==0?w1: l==1?w2: l==2?w3: l==3?w4: l==4?w5: l==5?w6: w7;
  long offv = 0;
  for (int i=0;i<7;i++){ if (i<l) offv += 9L*ciT[i]*coT[i]*2; }
  long total = 9L*ciT[l]*coT[l]*2;
  long e = (long)blockIdx.x*256 + threadIdx.x;
  if (e >= total) return;
  int CI = ciT[l], CO = coT[l];
  int j = (int)(e & 7);
  int lane = (int)((e>>3) & 63);
  int h = (int)((e>>9) & 1);
  long rem = e >> 10;
  int G = CO >> 4, KC = CI >> 5;
  int g = (int)(rem % G); long q = rem / G;
  int kc = (int)(q % KC); int o = (int)(q / KC);
  int co = (g<<4) + (lane & 15);
  int ci = (kc<<5) + ((lane>>4)<<3) + j;
  float v = w[((long)co*CI + ci)*9 + o];
  unsigned short hi = f2bf_rne(v);
  wp[offv + e] = (h==0) ? hi : f2bf_rne(v - bf2f(hi));
}

// ---------------- implicit-GEMM MFMA conv, both images one launch --------
union AB { bf16x8 v; uint4 u; };

__global__ __launch_bounds__(256) void conv_mfma_d(
    CImg A, CImg B, const unsigned short* __restrict__ Wp,
    const float* __restrict__ bias, int CI, int CO, int nci, int S)
{
  bool isA = (int)blockIdx.x < A.tiles;
  const float* in = isA ? A.in : B.in;
  float* out = isA ? A.out : B.out;
  int H = isA ? A.H : B.H, W = isA ? A.W : B.W;
  long inBS = isA ? A.inBS : B.inBS, outBS = isA ? A.outBS : B.outBS;
  long sStride = isA ? A.sStride : B.sStride;
  int tile = isA ? blockIdx.x : blockIdx.x - A.tiles;

  int HW = H*W;
  int tilesX = (W+7)>>3;
  int tx0 = (tile % tilesX)<<3, ty0 = (tile / tilesX)<<3;
  int cobase = blockIdx.y << 6;
  int s = blockIdx.z % S, b = blockIdx.z / S;
  int tid = threadIdx.x, lane = tid & 63, wid = tid>>6;
  int wm = wid>>1, wn = wid&1;
  int KC = CI>>5, G = CO>>4;
  __shared__ __align__(16) unsigned short Bth[4000];
  __shared__ __align__(16) unsigned short Btl[4000];
  const float* inb = in + (long)b*inBS;

  int sofs[13]; int sla[13];
  #pragma unroll
  for (int i=0;i<13;i++){
    int e = tid + i*256;
    int cidx = e / 100, pix = e - cidx*100;
    int hy = pix/10, hx = pix - hy*10;
    int gy = ty0 - 1 + hy, gx = tx0 - 1 + hx;
    bool v = (gy>=0) && (gy<H) && (gx>=0) && (gx<W);
    sofs[i] = v ? (cidx*HW + gy*W + gx) : -1;
    sla[i] = pix*40 + cidx;
  }

  int n15 = lane & 15;
  int klane8 = (lane>>4)<<3;
  int p0 = wn*32 + n15;
  int base0 = ((p0>>3)*10 + (p0&7))*40 + klane8;
  int p1 = p0 + 16;
  int base1 = ((p1>>3)*10 + (p1&7))*40 + klane8;
  int g0 = (cobase>>4) + wm*2;

  f32x4 acc[2][2];
  #pragma unroll
  for (int i=0;i<2;i++)
    #pragma unroll
    for (int j=0;j<2;j++) acc[i][j] = (f32x4){0.f,0.f,0.f,0.f};

  int nkc = nci >> 5;
  for (int kk=0; kk<nkc; kk++){
    int ci0 = s*nci + (kk<<5);
    __syncthreads();
    #pragma unroll
    for (int i=0;i<12;i++){
      float v = (sofs[i] >= 0) ? inb[(long)ci0*HW + sofs[i]] : 0.f;
      unsigned short h = f2bf_rne(v);
      Bth[sla[i]] = h;
      Btl[sla[i]] = f2bf_rne(v - bf2f(h));
    }
    if (tid < 128){
      float v = (sofs[12] >= 0) ? inb[(long)ci0*HW + sofs[12]] : 0.f;
      unsigned short h = f2bf_rne(v);
      Bth[sla[12]] = h;
      Btl[sla[12]] = f2bf_rne(v - bf2f(h));
    }
    __syncthreads();
    int kc = ci0 >> 5;
    const unsigned short* wpb = Wp + (long)kc*G*1024 + (long)lane*8;
    #pragma unroll
    for (int o=0;o<9;o++){
      const int dy = o/3, dx = o - dy*3;
      const int sh = (dy*10+dx)*40;
      const unsigned short* wo = wpb + (long)o*KC*G*1024;
      AB a0h,a0l,a1h,a1l, b0h,b0l,b1h,b1l;
      a0h.u = *(const uint4*)(wo + (long)g0*1024);
      a0l.u = *(const uint4*)(wo + (long)g0*1024 + 512);
      a1h.u = *(const uint4*)(wo + (long)(g0+1)*1024);
      a1l.u = *(const uint4*)(wo + (long)(g0+1)*1024 + 512);
      b0h.v = *(const bf16x8*)&Bth[base0 + sh];
      b0l.v = *(const bf16x8*)&Btl[base0 + sh];
      b1h.v = *(const bf16x8*)&Bth[base1 + sh];
      b1l.v = *(const bf16x8*)&Btl[base1 + sh];
      acc[0][0] = MFB(a0h.v, b0l.v, acc[0][0]);
      acc[0][0] = MFB(a0l.v, b0h.v, acc[0][0]);
      acc[0][0] = MFB(a0h.v, b0h.v, acc[0][0]);
      acc[0][1] = MFB(a0h.v, b1l.v, acc[0][1]);
      acc[0][1] = MFB(a0l.v, b1h.v, acc[0][1]);
      acc[0][1] = MFB(a0h.v, b1h.v, acc[0][1]);
      acc[1][0] = MFB(a1h.v, b0l.v, acc[1][0]);
      acc[1][0] = MFB(a1l.v, b0h.v, acc[1][0]);
      acc[1][0] = MFB(a1h.v, b0h.v, acc[1][0]);
      acc[1][1] = MFB(a1h.v, b1l.v, acc[1][1]);
      acc[1][1] = MFB(a1l.v, b1h.v, acc[1][1]);
      acc[1][1] = MFB(a1h.v, b1h.v, acc[1][1]);
    }
  }

  float* outp = out + (long)s*sStride + (long)b*outBS;
  #pragma unroll
  for (int ng=0; ng<2; ng++){
    int p = wn*32 + ng*16 + n15;
    int gy = ty0 + (p>>3), gx = tx0 + (p&7);
    bool ok = (gy<H) && (gx<W);
    #pragma unroll
    for (int mg=0; mg<2; mg++){
      #pragma unroll
      for (int r=0;r<4;r++){
        if (ok){
          int co = cobase + wm*32 + mg*16 + ((lane>>4)<<2) + r;
          float v = acc[mg][ng][r];
          if (bias) v = fmaxf(v + bias[co], 0.f);
          outp[(long)co*HW + (long)gy*W + gx] = v;
        }
      }
    }
  }
}

// ---------------- partial reduce + bias + relu, both images -------------
__global__ void reduce_d(const float* __restrict__ pA, const float* __restrict__ pB,
                         const float* __restrict__ bias,
                         float* __restrict__ oA, float* __restrict__ oB,
                         int S, long sStrA, long sStrB, int CO, int HWa, int HWb,
                         long oBSa, long oBSb){
  int img = blockIdx.y;
  const float* part = img ? pB : pA;
  float* out = img ? oB : oA;
  int HW = img ? HWb : HWa;
  long sStride = img ? sStrB : sStrA;
  long outBS = img ? oBSb : oBSa;
  long tot = 2L*CO*HW;
  long e = (long)blockIdx.x*256 + threadIdx.x;
  if (e >= tot) return;
  long b = e / ((long)CO*HW);
  long r = e - b*(long)CO*HW;
  float v = 0.f;
  for (int s=0;s<S;s++) v += part[(long)s*sStride + e];
  int co = (int)(r / HW);
  out[b*outBS + r] = fmaxf(v + bias[co], 0.f);
}

// ---------------- maxpool 2x2, both images ----------------
__global__ void maxpool2_d(const float* __restrict__ inA, float* __restrict__ outA, long NCa, int HiA, int WiA,
                           const float* __restrict__ inB, float* __restrict__ outB, long NCb, int HiB, int WiB){
  const float* in = blockIdx.y ? inB : inA;
  float* out = blockIdx.y ? outB : outA;
  long NC = blockIdx.y ? NCb : NCa;
  int Hi = blockIdx.y ? HiB : HiA, Wi = blockIdx.y ? WiB : WiA;
  int Ho = Hi>>1, Wo = Wi>>1;
  long total = NC * Ho * Wo;
  long idx = (long)blockIdx.x*256 + threadIdx.x;
  if (idx >= total) return;
  int x = (int)(idx % Wo); long t = idx / Wo; int y = (int)(t % Ho); long nc = t / Ho;
  const float* p = in + (nc*Hi + 2*y)*(long)Wi + 2*x;
  out[idx] = fmaxf(fmaxf(p[0], p[1]), fmaxf(p[Wi], p[Wi+1]));
}

// ---------------- bicubic upsample, both images ----------------
__global__ __launch_bounds__(256) void bicubic_d(
    const float* __restrict__ inA, float* __restrict__ outA,
    const float* __restrict__ inB, float* __restrict__ outB){
  int c = blockIdx.x;
  int img = blockIdx.y >> 1, b = blockIdx.y & 1;
  const float* in = img ? inB : inA;
  float* out = img ? outB : outA;
  int Hin = img ? 12 : 24, Win = Hin, Hout = img ? 48 : 96, Wout = Hout;
  long inBS = img ? 256L*144 : 256L*576;
  long outBS = img ? 320L*2304 : 320L*9216;
  __shared__ float s[576];
  const float* ip = in + (long)b*inBS + (long)c*Hin*Win;
  float* op = out + (long)b*outBS + (long)c*Hout*Wout;
  int n = Hin*Win;
  for (int i = threadIdx.x; i < n; i += 256) s[i] = ip[i];
  __syncthreads();
  float scy = (float)((double)(Hin-1)/(double)(Hout-1));
  float scx = scy;
  int total = Hout*Wout;
  for (int idx = threadIdx.x; idx < total; idx += 256){
    int ox = idx % Wout, oy = idx / Wout;
    float py = oy * scy, px = ox * scx;
    float iy0f = floorf(py), ix0f = floorf(px);
    int iy0 = (int)iy0f, ix0 = (int)ix0f;
    float fy = py - iy0f, fx = px - ix0f;
    float wy[4], wx[4]; int xs[4], ys[4];
    #pragma unroll
    for (int t=0;t<4;t++){
      wy[t] = cubicw(fy - (float)(t-1));
      wx[t] = cubicw(fx - (float)(t-1));
      ys[t] = min(max(iy0 + t - 1, 0), Hin-1);
      xs[t] = min(max(ix0 + t - 1, 0), Win-1);
    }
    float acc = 0.f;
    #pragma unroll
    for (int i=0;i<4;i++){
      const float* row = &s[ys[i]*Win];
      float rs = wx[0]*row[xs[0]] + wx[1]*row[xs[1]] + wx[2]*row[xs[2]] + wx[3]*row[xs[3]];
      acc = fmaf(wy[i], rs, acc);
    }
    op[idx] = acc;
  }
}

// ---------------- channel mean ----------------
__global__ __launch_bounds__(256) void mean_k(const float* __restrict__ fR, const float* __restrict__ fT, float* __restrict__ mean){
  int c = blockIdx.x % 320, b = blockIdx.x / 320;
  const float* a = fR + ((long)b*320+c)*9216L;
  const float* t = fT + ((long)b*320+c)*2304L;
  float s = 0.f;
  for (int i=threadIdx.x;i<9216;i+=256) s += a[i];
  for (int i=threadIdx.x;i<2304;i+=256) s += t[i];
  __shared__ float sm[4];
  for (int o=32;o;o>>=1) s += __shfl_down(s,o);
  int lane = threadIdx.x & 63, wv = threadIdx.x >> 6;
  if (lane==0) sm[wv] = s;
  __syncthreads();
  if (threadIdx.x==0) mean[b*320+c] = (sm[0]+sm[1]+sm[2]+sm[3]) * (1.f/11520.f);
}

// ---------------- normalize + split + transpose ----------------
__global__ __launch_bounds__(256) void split_bf16(const float* __restrict__ feat,
    const float* __restrict__ mean,
    unsigned short* __restrict__ oh, unsigned short* __restrict__ ol, int P){
  int b = blockIdx.y; int m0 = blockIdx.x*32;
  __shared__ unsigned int t[32][321];
  int ml = threadIdx.x & 31, kq = threadIdx.x >> 5;
  const float* fp = feat + (long)b*320*P + m0 + ml;
  for (int k = kq*40; k < kq*40+40; k++){
    float mu = mean[b*320+k];
    float v = (fp[(long)k*P] - mu) / (mu + 1e-8f);
    unsigned short h = f2bf_rne(v);
    unsigned short l = f2bf_rne(v - bf2f(h));
    t[ml][k] = ((unsigned int)h<<16) | l;
  }
  __syncthreads();
  long base = ((long)b*P + m0)*320;
  for (int idx = threadIdx.x; idx < 32*320; idx += 256){
    int m = idx/320, k = idx - m*320;
    unsigned int p = t[m][k];
    oh[base + (long)m*320 + k] = (unsigned short)(p>>16);
    ol[base + (long)m*320 + k] = (unsigned short)(p & 0xffffu);
  }
}

// ---------------- split-bf16 MFMA dist GEMM + fused column stats --------
union FragU { bf16x8 v; uint2 u[2]; };

__global__ __launch_bounds__(256) void gemm_mfma(
    const unsigned short* __restrict__ Ah, const unsigned short* __restrict__ Al,
    const unsigned short* __restrict__ Bh, const unsigned short* __restrict__ Bl,
    float* __restrict__ D, const float* __restrict__ coefr,
    float* __restrict__ pm, float* __restrict__ ps){
  const int N = 2304, K = 320;
  int n0 = blockIdx.x*128, m0 = blockIdx.y*128;
  __shared__ unsigned short As[2][128][36], Bs[2][128][36];
  int tid = threadIdx.x, lane = tid & 63, wid = tid >> 6;
  int wm = wid >> 1, wn = wid & 1;
  f32x4 acc[4][4];
  #pragma unroll
  for (int i=0;i<4;i++)
    #pragma unroll
    for (int j=0;j<4;j++) acc[i][j] = (f32x4){0.f,0.f,0.f,0.f};

  for (int k0=0; k0<K; k0+=32){
    #pragma unroll
    for (int q=0;q<2;q++){
      int flat = q*256 + tid;
      int row = flat >> 2, seg = flat & 3;
      long ga = (long)(m0+row)*K + k0 + seg*8;
      long gb = (long)(n0+row)*K + k0 + seg*8;
      uint4 va = *(const uint4*)(Ah + ga);
      *(uint2*)&As[0][row][seg*8]   = make_uint2(va.x, va.y);
      *(uint2*)&As[0][row][seg*8+4] = make_uint2(va.z, va.w);
      uint4 vb = *(const uint4*)(Al + ga);
      *(uint2*)&As[1][row][seg*8]   = make_uint2(vb.x, vb.y);
      *(uint2*)&As[1][row][seg*8+4] = make_uint2(vb.z, vb.w);
      uint4 vc = *(const uint4*)(Bh + gb);
      *(uint2*)&Bs[0][row][seg*8]   = make_uint2(vc.x, vc.y);
      *(uint2*)&Bs[0][row][seg*8+4] = make_uint2(vc.z, vc.w);
      uint4 vd = *(const uint4*)(Bl + gb);
      *(uint2*)&Bs[1][row][seg*8]   = make_uint2(vd.x, vd.y);
      *(uint2*)&Bs[1][row][seg*8+4] = make_uint2(vd.z, vd.w);
    }
    __syncthreads();

    FragU af[2][4], bf[2][4];
    #pragma unroll
    for (int g=0; g<4; g++){
      const unsigned short* pa0 = &As[0][wm*64 + g*16 + (lane&15)][(lane>>4)*4];
      const unsigned short* pa1 = &As[1][wm*64 + g*16 + (lane&15)][(lane>>4)*4];
      const unsigned short* pb0 = &Bs[0][wn*64 + g*16 + (lane&15)][(lane>>4)*4];
      const unsigned short* pb1 = &Bs[1][wn*64 + g*16 + (lane&15)][(lane>>4)*4];
      af[0][g].u[0] = *(const uint2*)pa0; af[0][g].u[1] = *(const uint2*)(pa0 + 16);
      af[1][g].u[0] = *(const uint2*)pa1; af[1][g].u[1] = *(const uint2*)(pa1 + 16);
      bf[0][g].u[0] = *(const uint2*)pb0; bf[0][g].u[1] = *(const uint2*)(pb0 + 16);
      bf[1][g].u[0] = *(const uint2*)pb1; bf[1][g].u[1] = *(const uint2*)(pb1 + 16);
    }
    #pragma unroll
    for (int mg=0; mg<4; mg++)
      #pragma unroll
      for (int ng=0; ng<4; ng++){
        acc[mg][ng] = MFB(af[0][mg].v, bf[1][ng].v, acc[mg][ng]);
        acc[mg][ng] = MFB(af[1][mg].v, bf[0][ng].v, acc[mg][ng]);
        acc[mg][ng] = MFB(af[0][mg].v, bf[0][ng].v, acc[mg][ng]);
      }
    __syncthreads();
  }

  // D write (layout: col = lane&15, row = (lane>>4)*4 + r)
  #pragma unroll
  for (int mg=0; mg<4; mg++)
    #pragma unroll
    for (int ng=0; ng<4; ng++){
      int col = n0 + wn*64 + ng*16 + (lane & 15);
      #pragma unroll
      for (int r=0;r<4;r++){
        int rowv = m0 + wm*64 + mg*16 + (lane>>4)*4 + r;
        D[(long)rowv*N + col] = acc[mg][ng][r];
      }
    }

  // fused column softmax partials over this block's 128 rows
  float cr = *coefr;
  float* red = (float*)&As[0][0][0];   // 512 floats, LDS reuse (post-barrier)
  float pmv[4], psv[4];
  #pragma unroll
  for (int ng=0; ng<4; ng++){
    float m = -INFINITY;
    #pragma unroll
    for (int mg=0; mg<4; mg++)
      #pragma unroll
      for (int r=0;r<4;r++) m = fmaxf(m, cr*acc[mg][ng][r]);
    float s = 0.f;
    #pragma unroll
    for (int mg=0; mg<4; mg++)
      #pragma unroll
      for (int r=0;r<4;r++) s += expf(cr*acc[mg][ng][r] - m);
    #pragma unroll
    for (int o=16;o<64;o<<=1){
      float m2 = __shfl_xor(m,o), s2 = __shfl_xor(s,o);
      merge_ms(m,s,m2,s2);
    }
    pmv[ng]=m; psv[ng]=s;
  }
  if ((lane>>4)==0){
    #pragma unroll
    for (int ng=0; ng<4; ng++){
      int cl = wn*64 + ng*16 + lane;
      red[wm*128 + cl] = pmv[ng];
      red[256 + wm*128 + cl] = psv[ng];
    }
  }
  __syncthreads();
  if (wm==0 && (lane>>4)==0){
    #pragma unroll
    for (int ng=0; ng<4; ng++){
      int cl = wn*64 + ng*16 + lane;
      float m = pmv[ng], s = psv[ng];
      merge_ms(m, s, red[128+cl], red[384+cl]);
      pm[(long)blockIdx.y*2304 + n0 + cl] = m;
      ps[(long)blockIdx.y*2304 + n0 + cl] = s;
    }
  }
}

// merge 72 partials, emit q[n] = 0.5*cmax + 0.5*log(csum)
__global__ void colstat_merge(const float* __restrict__ pm, const float* __restrict__ ps,
                              float* __restrict__ qcol){
  int idx = blockIdx.x*256 + threadIdx.x;
  if (idx >= 2304) return;
  float m=-INFINITY, s=0.f;
  for (int k=0;k<72;k++) merge_ms(m, s, pm[(long)k*2304+idx], ps[(long)k*2304+idx]);
  qcol[idx] = 0.5f*m + 0.5f*logf(s);
}

// ---------------- fused row-stats + confidence + top-10 mean -------------
__global__ __launch_bounds__(256) void conf_topk_f(const float* __restrict__ D,
    const float* __restrict__ coefr, const float* __restrict__ coeft,
    const float* __restrict__ qcol, float* __restrict__ outp){
  int m = blockIdx.x;
  const float* drow = D + (long)m*2304;
  int tid = threadIdx.x, lane = tid & 63, wv = tid >> 6;
  float ct = *coeft, cr = *coefr;
  float v[9], tv[9];
  #pragma unroll
  for (int i=0;i<9;i++){ v[i] = drow[tid + i*256]; tv[i] = ct * v[i]; }

  __shared__ float sred[8];
  __shared__ unsigned int cand[40];

  float mx = tv[0];
  #pragma unroll
  for (int i=1;i<9;i++) mx = fmaxf(mx, tv[i]);
  #pragma unroll
  for (int o=1;o<64;o<<=1) mx = fmaxf(mx, __shfl_xor(mx, o));
  if (lane==0) sred[wv] = mx;
  __syncthreads();
  mx = fmaxf(fmaxf(sred[0],sred[1]), fmaxf(sred[2],sred[3]));
  float s = 0.f;
  #pragma unroll
  for (int i=0;i<9;i++) s += expf(tv[i]-mx);
  #pragma unroll
  for (int o=1;o<64;o<<=1) s += __shfl_xor(s, o);
  if (lane==0) sred[4+wv] = s;
  __syncthreads();
  float rs = sred[4]+sred[5]+sred[6]+sred[7];
  float rho = 0.5f*mx + 0.5f*logf(rs);
  float hc = 0.5f*(cr+ct);

  unsigned int key[9];
  #pragma unroll
  for (int i=0;i<9;i++){
    int n = i*256 + tid;
    float t = fmaf(hc, v[i], -qcol[n]);
    unsigned int b = __float_as_uint(t);
    b ^= (b >> 31) ? 0xFFFFFFFFu : 0x80000000u;
    key[i] = (b & 0xFFFFF000u) | (unsigned)n;
  }

  for (int t10=0; t10<10; t10++){
    unsigned int lb = key[0];
    #pragma unroll
    for (int i=1;i<9;i++) lb = lb > key[i] ? lb : key[i];
    unsigned int wb = lb;
    #pragma unroll
    for (int o=1;o<64;o<<=1){
      unsigned int x = (unsigned int)__shfl_xor((int)wb, o);
      wb = wb > x ? wb : x;
    }
    if (lane==0) cand[wv*10 + t10] = wb;
    #pragma unroll
    for (int i=0;i<9;i++) if (key[i]==wb) key[i]=0;
  }
  __syncthreads();

  if (wv == 0){
    unsigned int k = (lane < 40) ? cand[lane] : 0u;
    int sel = -1;
    for (int t10=0; t10<10; t10++){
      unsigned int wb = k;
      #pragma unroll
      for (int o=1;o<64;o<<=1){
        unsigned int x = (unsigned int)__shfl_xor((int)wb, o);
        wb = wb > x ? wb : x;
      }
      if (k == wb) k = 0;
      if (lane == t10) sel = (int)(wb & 0xFFFu);
    }
    float c = 0.f;
    if (sel >= 0){
      float t = fmaf(hc, drow[sel], -qcol[sel]);
      c = expf(t - rho);
    }
    #pragma unroll
    for (int o=1;o<64;o<<=1) c += __shfl_xor(c, o);
    if (lane == 0) outp[m] = c * 0.1f;
  }
}

// ---------------- host ----------------
extern "C" void kernel_launch(void* const* d_in, const int* in_sizes, int n_in,
                              void* d_out, int out_size, void* d_ws, size_t ws_size,
                              hipStream_t stream) {
  const float *W[8], *Bp[8], *xr, *xt, *cr, *ct;
  if (in_sizes[0] == 1728){
    for (int i=0;i<8;i++){ W[i]=(const float*)d_in[2*i]; Bp[i]=(const float*)d_in[2*i+1]; }
    xr=(const float*)d_in[16]; xt=(const float*)d_in[17];
    cr=(const float*)d_in[18]; ct=(const float*)d_in[19];
  } else {
    xr=(const float*)d_in[0]; xt=(const float*)d_in[1];
    cr=(const float*)d_in[2]; ct=(const float*)d_in[3];
    for (int i=0;i<8;i++){ W[i]=(const float*)d_in[4+2*i]; Bp[i]=(const float*)d_in[5+2*i]; }
  }

  const int convCI[8] = {3,64,64,128,128,256,256,256};
  const int convCO[8] = {64,64,128,128,256,256,256,256};
  long wpoff[8]; long wtot = 0;
  for (int l=1;l<8;l++){ wpoff[l] = wtot; wtot += 9L*convCI[l]*convCO[l]*2; }

  float* ws = (float*)d_ws;
  long off = 0;
  auto alloc = [&](long nfl){ float* p = ws + off; off += (nfl + 63) & ~63L; return p; };
  float* featR = alloc(2L*320*9216);
  float* featT = alloc(2L*320*2304);
  float* meanb = alloc(640);
  float* pm    = alloc(72L*2304);
  float* ps    = alloc(72L*2304);
  float* qcol  = alloc(2304);
  unsigned short* wp = (unsigned short*)alloc((wtot+1)/2);
  float* scratch = alloc(9216L*2304);
  if ((size_t)(off*4) > ws_size) return;

  unsigned short* AhR = (unsigned short*)alloc((2L*9216*320 + 1)/2);
  unsigned short* AlR = (unsigned short*)alloc((2L*9216*320 + 1)/2);
  unsigned short* BhT = (unsigned short*)alloc((2L*2304*320 + 1)/2);
  unsigned short* BlT = (unsigned short*)alloc((2L*2304*320 + 1)/2);
  if ((size_t)(off*4) > ws_size) return;

  // conv temporaries inside the (later) dist region
  float* rA = scratch;            // [2,64,96,96]
  float* rB = rA + 1179648;       // [2,64,48,48]
  float* rC = rB + 294912;        // [2,128,48,48]
  float* rD = rC + 589824;        // [2,128,48,48]
  float* rE = rD + 589824;        // [2,128,24,24]
  float* rF = rE + 147456;        // [2,256,24,24]
  float* rG = rF + 294912;        // [2,256,24,24]
  float* a2 = rG + 294912;        // [2,64,48,48]
  float* b2 = a2 + 294912;        // [2,64,24,24]
  float* c2 = b2 + 73728;         // [2,128,24,24]
  float* d2 = c2 + 147456;        // [2,128,24,24]
  float* e2 = d2 + 147456;        // [2,128,12,12]
  float* f2 = e2 + 36864;         // [2,256,12,12]
  float* g2 = f2 + 73728;         // [2,256,12,12]
  float* tPR = g2 + 73728;        // R partials (max 4x2x256x576)
  float* tPT = tPR + 1179648;     // T partials
  float* dist = scratch;

  auto mkimg = [](const float* in, float* out, int H, int Wd, int tiles,
                  long inBS, long outBS, long sStr){
    CImg c; c.in=in; c.out=out; c.H=H; c.W=Wd; c.tiles=tiles;
    c.inBS=inBS; c.outBS=outBS; c.sStride=sStr; return c;
  };

  // weight pre-pack: one launch for layers 1..7
  prep_w_all<<<dim3(4608,7), 256, 0, stream>>>(W[1],W[2],W[3],W[4],W[5],W[6],W[7], wp);

  // conv0 (both images)
  {
    CImg A = mkimg(xr, featR, 96,96, 36, 3L*9216, 320L*9216, 0);
    CImg B = mkimg(xt, featT, 48,48, 9, 3L*2304, 320L*2304, 0);
    conv0_d<<<dim3(45,16,2), 256, 0, stream>>>(A, B, W[0], Bp[0]);
  }
  // L1 (S=1)
  {
    CImg A = mkimg(featR, rA, 96,96, 144, 320L*9216, 64L*9216, 0);
    CImg B = mkimg(featT, a2, 48,48, 36, 320L*2304, 64L*2304, 0);
    conv_mfma_d<<<dim3(180,1,2), 256, 0, stream>>>(A,B, wp+wpoff[1], Bp[1], 64,64,64,1);
  }
  maxpool2_d<<<dim3(1152,2), 256, 0, stream>>>(rA,rB,128,96,96, a2,b2,128,48,48);
  // L2 (S=2)
  {
    CImg A = mkimg(rB, tPR, 48,48, 36, 64L*2304, 128L*2304, 589824);
    CImg B = mkimg(b2, tPT, 24,24, 9, 64L*576, 128L*576, 147456);
    conv_mfma_d<<<dim3(45,2,4), 256, 0, stream>>>(A,B, wp+wpoff[2], nullptr, 64,128,32,2);
    reduce_d<<<dim3(2304,2), 256, 0, stream>>>(tPR,tPT,Bp[2], rC,c2, 2, 589824,147456, 128, 2304,576, 128L*2304, 128L*576);
  }
  // L3 (S=2)
  {
    CImg A = mkimg(rC, tPR, 48,48, 36, 128L*2304, 128L*2304, 589824);
    CImg B = mkimg(c2, tPT, 24,24, 9, 128L*576, 128L*576, 147456);
    conv_mfma_d<<<dim3(45,2,4), 256, 0, stream>>>(A,B, wp+wpoff[3], nullptr, 128,128,64,2);
    reduce_d<<<dim3(2304,2), 256, 0, stream>>>(tPR,tPT,Bp[3], rD,d2, 2, 589824,147456, 128, 2304,576, 128L*2304, 128L*576);
  }
  maxpool2_d<<<dim3(576,2), 256, 0, stream>>>(rD,rE,256,48,48, d2,e2,256,24,24);
  // L4 (S=4)
  {
    CImg A = mkimg(rE, tPR, 24,24, 9, 128L*576, 256L*576, 294912);
    CImg B = mkimg(e2, tPT, 12,12, 4, 128L*144, 256L*144, 73728);
    conv_mfma_d<<<dim3(13,4,8), 256, 0, stream>>>(A,B, wp+wpoff[4], nullptr, 128,256,32,4);
    reduce_d<<<dim3(1152,2), 256, 0, stream>>>(tPR,tPT,Bp[4], rF,f2, 4, 294912,73728, 256, 576,144, 256L*576, 256L*144);
  }
  // L5..L7 (S=4)
  const float* inR[3] = {rF, rG, rF};  float* outR[3] = {rG, rF, rG};
  const float* inT[3] = {f2, g2, f2};  float* outT[3] = {g2, f2, g2};
  for (int i=0;i<3;i++){
    int l = 5+i;
    CImg A = mkimg(inR[i], tPR, 24,24, 9, 256L*576, 256L*576, 294912);
    CImg B = mkimg(inT[i], tPT, 12,12, 4, 256L*144, 256L*144, 73728);
    conv_mfma_d<<<dim3(13,4,8), 256, 0, stream>>>(A,B, wp+wpoff[l], nullptr, 256,256,64,4);
    reduce_d<<<dim3(1152,2), 256, 0, stream>>>(tPR,tPT,Bp[l], outR[i],outT[i], 4, 294912,73728, 256, 576,144, 256L*576, 256L*144);
  }
  // bicubic (both images)
  bicubic_d<<<dim3(256,4), 256, 0, stream>>>(rG, featR + 64L*9216, g2, featT + 64L*2304);

  // normalizer mean + fused norm/split/transpose
  mean_k<<<640, 256, 0, stream>>>(featR, featT, meanb);
  split_bf16<<<dim3(288,2), 256, 0, stream>>>(featR, meanb, AhR, AlR, 9216);
  split_bf16<<<dim3(72,2),  256, 0, stream>>>(featT, meanb, BhT, BlT, 2304);

  // per-batch: GEMM(+colstat) -> merge -> conf/topk
  for (int b=0; b<2; b++){
    gemm_mfma<<<dim3(18,72), 256, 0, stream>>>(
        AhR + (long)b*9216*320, AlR + (long)b*9216*320,
        BhT + (long)b*2304*320, BlT + (long)b*2304*320, dist, cr, pm, ps);
    colstat_merge<<<dim3(9), 256, 0, stream>>>(pm, ps, qcol);
    conf_topk_f<<<dim3(9216), 256, 0, stream>>>(dist, cr, ct, qcol, (float*)d_out + (long)b*9216);
  }
}